// Round 18
// baseline (1687.185 us; speedup 1.0000x reference)
//
#include <hip/hip_runtime.h>
#include <math.h>

typedef unsigned short u16;
typedef __attribute__((ext_vector_type(4))) float f4;
typedef __attribute__((ext_vector_type(8))) unsigned short us8;
typedef __attribute__((ext_vector_type(8))) short bfrag;
typedef __attribute__((ext_vector_type(4))) float f32x4;

#define BB 32
#define TT 64
#define DD 512
#define G4_ 2048

__device__ __forceinline__ float sigf(float x) { return 1.0f / (1.0f + expf(-x)); }
__device__ __forceinline__ float bf2f(u16 u) {
    union { unsigned int i; float f; } v; v.i = ((unsigned int)u) << 16; return v.f;
}
__device__ __forceinline__ u16 f2bf(float f) {
    union { float f; unsigned int i; } v; v.f = f;
    unsigned int r = v.i + 0x7fffu + ((v.i >> 16) & 1u);
    return (u16)(r >> 16);
}

// ---------------------------------------------------------------------------
// mask dtype classifier: 0=u8(bool), 1=i32, 2=bf16, 3=f32. Deterministic.
// ---------------------------------------------------------------------------
__global__ void k_flag(const unsigned char* __restrict__ m, int* __restrict__ flag) {
    int tid = threadIdx.x;
    int badbyte = 0, nonz_off = 0, evenu16_nz = 0;
    for (int i = tid * 16; i < tid * 16 + 16; i++) {
        unsigned char c = m[i];
        if (c > 1) badbyte = 1;
        if ((i & 3) != 0 && c != 0) nonz_off = 1;
    }
    const u16* mu = (const u16*)m;
    for (int i = tid * 8; i < tid * 8 + 8; i++) {
        if ((i & 1) == 0 && mu[i] != 0) evenu16_nz = 1;
    }
    __shared__ int s_bad, s_noff, s_env;
    if (tid == 0) { s_bad = 0; s_noff = 0; s_env = 0; }
    __syncthreads();
    if (badbyte) atomicOr(&s_bad, 1);
    if (nonz_off) atomicOr(&s_noff, 1);
    if (evenu16_nz) atomicOr(&s_env, 1);
    __syncthreads();
    if (tid == 0) {
        int f;
        if (s_bad) f = s_env ? 2 : 3;
        else       f = s_noff ? 0 : 1;
        *flag = f;
    }
}

// ---------------------------------------------------------------------------
// init: copy initial h-states into both parity buffers.
// ---------------------------------------------------------------------------
__global__ void __launch_bounds__(256) k_init2(const float* __restrict__ hid,
                                               float* __restrict__ h0s,
                                               float* __restrict__ h1s) {
    int i = blockIdx.x * 256 + threadIdx.x;   // 0 .. 16383
    float v0 = hid[i], v1 = hid[16384 + i];
    h0s[i] = v0; h0s[16384 + i] = v0;
    h1s[i] = v1; h1s[16384 + i] = v1;
}

// ---------------------------------------------------------------------------
// convert weights to bf16 (RNE):  recurrent -> dstR, W_in -> dstIn, W_out -> dstOut
// ---------------------------------------------------------------------------
__global__ void __launch_bounds__(256) k_conv(const float* __restrict__ Wih,
                                              const float* __restrict__ Whh,
                                              const float* __restrict__ Win,
                                              const float* __restrict__ Wout,
                                              u16* __restrict__ dstR,
                                              u16* __restrict__ dstIn,
                                              u16* __restrict__ dstOut) {
    size_t e = ((size_t)blockIdx.x * 256 + threadIdx.x) * 4;
    if (e < 4194304) {
        int m = (int)(e >> 20);
        size_t off = e & 1048575;
        const float* src = (m == 0) ? Wih
                         : (m == 1) ? Whh
                         : (m == 2) ? (Wih + 1048576)
                                    : (Whh + 1048576);
        f4 v = *(const f4*)&src[off];
        dstR[e + 0] = f2bf(v[0]); dstR[e + 1] = f2bf(v[1]);
        dstR[e + 2] = f2bf(v[2]); dstR[e + 3] = f2bf(v[3]);
    } else if (e < 4718592) {
        size_t off = e - 4194304;
        f4 v = *(const f4*)&Win[off];
        dstIn[off + 0] = f2bf(v[0]); dstIn[off + 1] = f2bf(v[1]);
        dstIn[off + 2] = f2bf(v[2]); dstIn[off + 3] = f2bf(v[3]);
    } else {
        size_t off = e - 4718592;
        f4 v = *(const f4*)&Wout[off];
        dstOut[off + 0] = f2bf(v[0]); dstOut[off + 1] = f2bf(v[1]);
        dstOut[off + 2] = f2bf(v[2]); dstOut[off + 3] = f2bf(v[3]);
    }
}

// ---------------------------------------------------------------------------
// pack W_ih0 into MFMA B-fragment order (bf16).
// ---------------------------------------------------------------------------
__global__ void __launch_bounds__(256) k_packA(const float* __restrict__ Wih0,
                                               u16* __restrict__ Wp) {
    int g = blockIdx.x * 256 + threadIdx.x;   // 0 .. 131071
    int lane = g & 63, grp = g >> 6;          // grp = j16*16 + ks
    int j16 = grp >> 4, ks = grp & 15;
    const float* src = &Wih0[((size_t)(j16 * 16 + (lane & 15))) * 512 + ks * 32 + (lane >> 4) * 8];
    u16* dst = &Wp[(size_t)g * 8];
    f4 v0 = *(const f4*)&src[0];
    f4 v1 = *(const f4*)&src[4];
    dst[0] = f2bf(v0[0]); dst[1] = f2bf(v0[1]); dst[2] = f2bf(v0[2]); dst[3] = f2bf(v0[3]);
    dst[4] = f2bf(v1[0]); dst[5] = f2bf(v1[1]); dst[6] = f2bf(v1[2]); dst[7] = f2bf(v1[3]);
}

// ---------------------------------------------------------------------------
// gih0 via MFMA 16x16x32 bf16 (R14-proven).
// ---------------------------------------------------------------------------
__global__ void __launch_bounds__(256) k_gih0_mfma(const int* __restrict__ tokens,
                                                   const float* __restrict__ embed,
                                                   const u16* __restrict__ Wp,
                                                   const float* __restrict__ bih,
                                                   const float* __restrict__ bhh,
                                                   float* __restrict__ gih0) {
    const int tid = threadIdx.x;
    const int lane = tid & 63, w = tid >> 6;
    const int t = blockIdx.y;
    const int jw = blockIdx.x * 256 + w * 64;
    __shared__ u16 xs[32][520];
    __shared__ int toks[32];
    if (tid < 32) toks[tid] = tokens[tid * TT + t];
    __syncthreads();
    for (int i = tid; i < 32 * 128; i += 256) {
        int b = i >> 7, k4 = i & 127;
        f4 v = *(const f4*)&embed[(size_t)toks[b] * 512 + k4 * 4];
        u16* dst = &xs[b][k4 * 4];
        dst[0] = f2bf(v[0]); dst[1] = f2bf(v[1]); dst[2] = f2bf(v[2]); dst[3] = f2bf(v[3]);
    }
    __syncthreads();

    const int l15 = lane & 15, l4 = lane >> 4;
    f32x4 acc[2][4];
#pragma unroll
    for (int mi = 0; mi < 2; mi++)
#pragma unroll
        for (int ni = 0; ni < 4; ni++) acc[mi][ni] = (f32x4){0.f, 0.f, 0.f, 0.f};

    for (int ks = 0; ks < 16; ks++) {
        bfrag a0 = *(const bfrag*)&xs[l15][ks * 32 + l4 * 8];
        bfrag a1 = *(const bfrag*)&xs[16 + l15][ks * 32 + l4 * 8];
#pragma unroll
        for (int ni = 0; ni < 4; ni++) {
            int j16 = (jw + ni * 16) >> 4;
            bfrag bf = *(const bfrag*)&Wp[(((size_t)j16 * 16 + ks) * 64 + lane) * 8];
            acc[0][ni] = __builtin_amdgcn_mfma_f32_16x16x32_bf16(a0, bf, acc[0][ni], 0, 0, 0);
            acc[1][ni] = __builtin_amdgcn_mfma_f32_16x16x32_bf16(a1, bf, acc[1][ni], 0, 0, 0);
        }
    }

#pragma unroll
    for (int ni = 0; ni < 4; ni++) {
        int j = jw + ni * 16 + l15;
        float bv = bih[j] + bhh[j];
#pragma unroll
        for (int mi = 0; mi < 2; mi++) {
#pragma unroll
            for (int r = 0; r < 4; r++) {
                int b = mi * 16 + l4 * 4 + r;
                gih0[((size_t)(t * 32 + b)) * 2048 + j] = acc[mi][ni][r] + bv;
            }
        }
    }
}

// ---------------------------------------------------------------------------
// Fused phase kernel (512 blocks x 256 thr), merged K-chunks:
// full 512-col h staged in ONE pass (xs[32][513], 65.7 KB, 2 blocks/CU
// unchanged). stepA: 1 stage + 1 dot. stepB: 2 passes (h20, h1).
// Per-output k-order identical to R16 -> bit-exact.
// ---------------------------------------------------------------------------
__global__ void __launch_bounds__(256) k_phase(
    const int k,
    const float* __restrict__ gih0,
    const u16* __restrict__ Whh0b,
    const u16* __restrict__ Wih1b,
    const u16* __restrict__ Whh1b,
    const float* __restrict__ bih1,
    const float* __restrict__ bhh1,
    const float* __restrict__ cells,
    const float* __restrict__ h0r, float* __restrict__ h0w,
    const float* __restrict__ h20r, float* __restrict__ h20w,
    const float* __restrict__ h1r, float* __restrict__ h1w,
    float* __restrict__ H2)
{
    const int tid = threadIdx.x;
    const int b = tid & 31, u = tid >> 5;       // u = row m, 0..7
    __shared__ float xs[32][513];
    __shared__ float gbuf[8][33];

    if (blockIdx.x < 256) {                     // ======== stepA (t = k)
        if (k >= 64) return;
        const int d0 = blockIdx.x * 2;
        const int j = (u >> 1) * 512 + d0 + (u & 1);
        float a = gih0[(size_t)k * 65536 + b * 2048 + j];
        // stage all 512 cols of h0 in one pass
        for (int i = tid; i < 4096; i += 256) {
            int b2 = i >> 7, k4 = i & 127;
            *(f4*)&xs[b2][k4 * 4] = *(const f4*)&h0r[b2 * 512 + k4 * 4];
        }
        __syncthreads();
        const u16* wp = Whh0b + (size_t)j * 512;
        for (int k8 = 0; k8 < 64; k8++) {
            us8 wv = *(const us8*)&wp[k8 * 8];
            f4 x0 = *(const f4*)&xs[b][k8 * 8];
            f4 x1 = *(const f4*)&xs[b][k8 * 8 + 4];
            a += x0[0] * bf2f(wv[0]); a += x0[1] * bf2f(wv[1]);
            a += x0[2] * bf2f(wv[2]); a += x0[3] * bf2f(wv[3]);
            a += x1[0] * bf2f(wv[4]); a += x1[1] * bf2f(wv[5]);
            a += x1[2] * bf2f(wv[6]); a += x1[3] * bf2f(wv[7]);
        }
        gbuf[u][b] = a;
        __syncthreads();
        if (tid < 64) {
            int bb = tid & 31, dd = tid >> 5;   // dd 0..1
            float gi = gbuf[0 + dd][bb], gf = gbuf[2 + dd][bb];
            float gg = gbuf[4 + dd][bb], go = gbuf[6 + dd][bb];
            float cell = cells[bb * 512 + d0 + dd];
            float c2 = sigf(gf) * cell + sigf(gi) * tanhf(gg);
            float h2 = sigf(go) * tanhf(c2);
            h0w[bb * 512 + d0 + dd] = c2;       // faithful bug: carry = cell
            h20w[bb * 512 + d0 + dd] = h2;
        }
    } else {                                    // ======== stepB (t = k-1)
        if (k < 1) return;
        const int d0 = (blockIdx.x - 256) * 2;
        const int j = (u >> 1) * 512 + d0 + (u & 1);
        float a = bih1[j] + bhh1[j];
        for (int pass = 0; pass < 2; pass++) {
            const float* srcb = pass ? h1r : h20r;
            if (pass) __syncthreads();          // xs reuse guard
            for (int i = tid; i < 4096; i += 256) {
                int b2 = i >> 7, k4 = i & 127;
                *(f4*)&xs[b2][k4 * 4] = *(const f4*)&srcb[b2 * 512 + k4 * 4];
            }
            __syncthreads();
            const u16* wp = (pass ? Whh1b : Wih1b) + (size_t)j * 512;
            for (int k8 = 0; k8 < 64; k8++) {
                us8 wv = *(const us8*)&wp[k8 * 8];
                f4 x0 = *(const f4*)&xs[b][k8 * 8];
                f4 x1 = *(const f4*)&xs[b][k8 * 8 + 4];
                a += x0[0] * bf2f(wv[0]); a += x0[1] * bf2f(wv[1]);
                a += x0[2] * bf2f(wv[2]); a += x0[3] * bf2f(wv[3]);
                a += x1[0] * bf2f(wv[4]); a += x1[1] * bf2f(wv[5]);
                a += x1[2] * bf2f(wv[6]); a += x1[3] * bf2f(wv[7]);
            }
        }
        gbuf[u][b] = a;
        __syncthreads();
        if (tid < 64) {
            int bb = tid & 31, dd = tid >> 5;   // dd 0..1
            float gi = gbuf[0 + dd][bb], gf = gbuf[2 + dd][bb];
            float gg = gbuf[4 + dd][bb], go = gbuf[6 + dd][bb];
            float cell = cells[16384 + bb * 512 + d0 + dd];
            float c2 = sigf(gf) * cell + sigf(gi) * tanhf(gg);
            float h2 = sigf(go) * tanhf(c2);
            h1w[bb * 512 + d0 + dd] = c2;       // faithful bug
            H2[(size_t)(k - 1) * 16384 + bb * 512 + d0 + dd] = h2;
        }
    }
}

// ---------------------------------------------------------------------------
// XQ for TWO time-steps per block (R16-proven).
// ---------------------------------------------------------------------------
__global__ void __launch_bounds__(256) k_x2(const float* __restrict__ H2,
                                            const u16* __restrict__ Winb,
                                            const float* __restrict__ bin,
                                            float* __restrict__ XQ) {
    const int tid = threadIdx.x;
    const int j0 = blockIdx.x * 32;
    const int t0 = blockIdx.y * 2;
    const int b = tid & 31, jj = tid >> 5;
    __shared__ float xs[2][32][257];
    float acc[2][4];
#pragma unroll
    for (int tg = 0; tg < 2; tg++)
#pragma unroll
        for (int r = 0; r < 4; r++) acc[tg][r] = bin[j0 + jj * 4 + r];
    for (int c = 0; c < 2; c++) {
        for (int idx = tid; idx < 2 * 32 * 64; idx += 256) {
            int tg = idx >> 11;
            int rem = idx & 2047;
            int b2 = rem >> 6, k4 = rem & 63;
            f4 v = *(const f4*)&H2[(size_t)(t0 + tg) * 16384 + b2 * 512 + c * 256 + k4 * 4];
            float* dst = &xs[tg][b2][k4 * 4];
            dst[0] = v[0]; dst[1] = v[1]; dst[2] = v[2]; dst[3] = v[3];
        }
        __syncthreads();
        for (int k8 = 0; k8 < 32; k8++) {
            float w[4][8];
#pragma unroll
            for (int r = 0; r < 4; r++) {
                us8 wv = *(const us8*)&Winb[(size_t)(j0 + jj * 4 + r) * 512 + c * 256 + k8 * 8];
#pragma unroll
                for (int kk = 0; kk < 8; kk++) w[r][kk] = bf2f(wv[kk]);
            }
#pragma unroll
            for (int tg = 0; tg < 2; tg++) {
#pragma unroll
                for (int kk = 0; kk < 8; kk++) {
                    float xv = xs[tg][b][k8 * 8 + kk];
#pragma unroll
                    for (int r = 0; r < 4; r++) acc[tg][r] += xv * w[r][kk];
                }
            }
        }
        __syncthreads();
    }
#pragma unroll
    for (int tg = 0; tg < 2; tg++) {
        float* xrow = XQ + ((size_t)((t0 + tg) * 32 + b)) * 1024;
#pragma unroll
        for (int r = 0; r < 4; r++) xrow[j0 + jj * 4 + r] = acc[tg][r];
    }
}

// ---------------------------------------------------------------------------
// attention, 2 time-steps per block (R15-proven).
// ---------------------------------------------------------------------------
__global__ void __launch_bounds__(256) k_att2(const float* __restrict__ XQ,
                                              const float* __restrict__ enc,
                                              const unsigned char* __restrict__ mask,
                                              const int* __restrict__ flag,
                                              float* __restrict__ CTX) {
    const int tid = threadIdx.x;
    const int b = blockIdx.x, t0 = blockIdx.y * 2;
    __shared__ float xq[2][1024];
    __shared__ float ered[2][256];
    __shared__ float attn[2][128];
    __shared__ float red2[2][8];
#pragma unroll
    for (int tg = 0; tg < 2; tg++) {
        f4 v = *(const f4*)&XQ[((size_t)((t0 + tg) * 32 + b)) * 1024 + tid * 4];
        float* dst = &xq[tg][tid * 4];
        dst[0] = v[0]; dst[1] = v[1]; dst[2] = v[2]; dst[3] = v[3];
    }
    __syncthreads();
    const int s = tid >> 1, hh = tid & 1;
    float p0 = 0.f, p1 = 0.f;
    const float* erow = enc + ((size_t)(b * 128 + s)) * 1024 + hh * 512;
    const float* xqh0 = &xq[0][hh * 512];
    const float* xqh1 = &xq[1][hh * 512];
    for (int k4 = 0; k4 < 128; k4++) {
        f4 u = *(const f4*)&erow[k4 * 4];
#pragma unroll
        for (int kk = 0; kk < 4; kk++) {
            p0 += u[kk] * xqh0[k4 * 4 + kk];
            p1 += u[kk] * xqh1[k4 * 4 + kk];
        }
    }
    ered[0][tid] = p0; ered[1][tid] = p1;
    __syncthreads();
    bool msk = false;
    if (tid < 128) {
        int f = *flag;
        if (f == 0)      msk = mask[b * 128 + tid] != 0;
        else if (f == 1) msk = ((const int*)mask)[b * 128 + tid] != 0;
        else if (f == 2) msk = ((const u16*)mask)[b * 128 + tid] != 0;
        else             msk = ((const unsigned int*)mask)[b * 128 + tid] != 0;
    }
    const int wave = tid >> 6;
    float e[2];
#pragma unroll
    for (int tg = 0; tg < 2; tg++) {
        e[tg] = -INFINITY;
        if (tid < 128) {
            e[tg] = ered[tg][2 * tid] + ered[tg][2 * tid + 1];
            if (msk) e[tg] = -1e9f;
        }
        float v = e[tg];
#pragma unroll
        for (int off = 32; off >= 1; off >>= 1) v = fmaxf(v, __shfl_xor(v, off));
        if ((tid & 63) == 0) red2[tg][wave] = v;
    }
    __syncthreads();
#pragma unroll
    for (int tg = 0; tg < 2; tg++) {
        float mx = fmaxf(fmaxf(red2[tg][0], red2[tg][1]), fmaxf(red2[tg][2], red2[tg][3]));
        float p = (tid < 128) ? expf(e[tg] - mx) : 0.f;
        float su = p;
#pragma unroll
        for (int off = 32; off >= 1; off >>= 1) su += __shfl_xor(su, off);
        if ((tid & 63) == 0) red2[tg][4 + wave] = su;
        __syncthreads();
        float S = (red2[tg][4] + red2[tg][5]) + (red2[tg][6] + red2[tg][7]);
        if (tid < 128) attn[tg][tid] = p / S;
        __syncthreads();
    }
    float c0[2] = {0, 0}, c1[2] = {0, 0}, c2v[2] = {0, 0}, c3[2] = {0, 0};
    const float* eb = enc + ((size_t)b * 128) * 1024 + tid * 4;
    for (int s2 = 0; s2 < 128; s2++) {
        f4 u = *(const f4*)&eb[(size_t)s2 * 1024];
#pragma unroll
        for (int tg = 0; tg < 2; tg++) {
            float a = attn[tg][s2];
            c0[tg] += a * u[0]; c1[tg] += a * u[1]; c2v[tg] += a * u[2]; c3[tg] += a * u[3];
        }
    }
#pragma unroll
    for (int tg = 0; tg < 2; tg++) {
        float* crow = CTX + ((size_t)((t0 + tg) * 32 + b)) * 1024 + tid * 4;
        crow[0] = c0[tg]; crow[1] = c1[tg]; crow[2] = c2v[tg]; crow[3] = c3[tg];
    }
}

// ---------------------------------------------------------------------------
// out[t,b,:] = tanh([ctx, s] @ W_out^T + b_out)  -> f32 d_out
// 2 time-steps per block; W_out bf16 (R11-proven).
// ---------------------------------------------------------------------------
__global__ void __launch_bounds__(256) k_out2(const float* __restrict__ CTX,
                                              const float* __restrict__ H2,
                                              const u16* __restrict__ Woutb,
                                              const float* __restrict__ bout,
                                              float* __restrict__ out) {
    const int tid = threadIdx.x;
    const int j0 = blockIdx.x * 32;
    const int t0 = blockIdx.y * 2;
    const int b = tid & 31, jj = tid >> 5;
    __shared__ float xs[2][32][257];
    float acc[2][4];
#pragma unroll
    for (int tg = 0; tg < 2; tg++)
#pragma unroll
        for (int r = 0; r < 4; r++) acc[tg][r] = bout[j0 + jj * 4 + r];
    for (int c = 0; c < 6; c++) {
        for (int idx = tid; idx < 2 * 32 * 64; idx += 256) {
            int tg = idx >> 11;
            int rem = idx & 2047;
            int b2 = rem >> 6, k4 = rem & 63;
            int t = t0 + tg;
            const float* src = (c < 4) ? &CTX[(size_t)(t * 32 + b2) * 1024 + c * 256]
                                       : &H2[(size_t)t * 16384 + b2 * 512 + (c - 4) * 256];
            f4 v = *(const f4*)&src[k4 * 4];
            float* dst = &xs[tg][b2][k4 * 4];
            dst[0] = v[0]; dst[1] = v[1]; dst[2] = v[2]; dst[3] = v[3];
        }
        __syncthreads();
        for (int k8 = 0; k8 < 32; k8++) {
            float w[4][8];
#pragma unroll
            for (int r = 0; r < 4; r++) {
                us8 wv = *(const us8*)&Woutb[(size_t)(j0 + jj * 4 + r) * 1536 + c * 256 + k8 * 8];
#pragma unroll
                for (int kk = 0; kk < 8; kk++) w[r][kk] = bf2f(wv[kk]);
            }
#pragma unroll
            for (int tg = 0; tg < 2; tg++) {
#pragma unroll
                for (int kk = 0; kk < 8; kk++) {
                    float xv = xs[tg][b][k8 * 8 + kk];
#pragma unroll
                    for (int r = 0; r < 4; r++) acc[tg][r] += xv * w[r][kk];
                }
            }
        }
        __syncthreads();
    }
#pragma unroll
    for (int tg = 0; tg < 2; tg++) {
        float* orow = out + ((size_t)((t0 + tg) * 32 + b)) * 512;
#pragma unroll
        for (int r = 0; r < 4; r++) orow[j0 + jj * 4 + r] = tanhf(acc[tg][r]);
    }
}

// ---------------------------------------------------------------------------
extern "C" void kernel_launch(void* const* d_in, const int* in_sizes, int n_in,
                              void* d_out, int out_size, void* d_ws, size_t ws_size,
                              hipStream_t stream) {
    const int* tokens   = (const int*)d_in[0];
    const float* enc    = (const float*)d_in[1];
    const float* hidden = (const float*)d_in[2];
    const float* cells  = (const float*)d_in[3];
    const unsigned char* mask = (const unsigned char*)d_in[4];
    const float* embed  = (const float*)d_in[5];
    const float* W_ih   = (const float*)d_in[6];
    const float* W_hh   = (const float*)d_in[7];
    const float* b_ih   = (const float*)d_in[8];
    const float* b_hh   = (const float*)d_in[9];
    const float* W_in   = (const float*)d_in[10];
    const float* b_in   = (const float*)d_in[11];
    const float* W_out  = (const float*)d_in[12];
    const float* b_out  = (const float*)d_in[13];
    float* out = (float*)d_out;

    float* ws = (float*)d_ws;
    // Phase-time layout:
    float* gih0 = ws;                              // [0, 4194304) — dead after phases
    float* h0s  = ws + 4194304;                    // 32768 (2 parities)
    float* h20s = ws + 4227072;                    // 32768
    float* h1s  = ws + 4259840;                    // 32768
    float* H2   = ws + 4292608;                    // 1,048,576
    u16*   WB16 = (u16*)(ws + 5341184);            // recurrent bf16: 4 x 1048576 u16
    u16*   whh0b = WB16 + 1048576;
    u16*   wih1b = WB16 + 2097152;
    u16*   whh1b = WB16 + 3145728;
    u16*   winb  = (u16*)(ws + 7438336);           // 524288 u16
    u16*   woutb = (u16*)(ws + 7700480);           // 786432 u16
    u16*   wih0p = (u16*)(ws + 8093696);           // 1048576 u16 (MFMA-packed W_ih0)
    // Tail-time layout (gih0 region reused):
    float* XQ   = ws;                              // [0, 2097152)
    float* CTX  = ws + 2097152;                    // [2097152, 4194304)
    int*   flag = (int*)(ws + 9535488);

    const float* bih1 = b_ih + G4_;
    const float* bhh1 = b_hh + G4_;

    k_flag<<<1, 256, 0, stream>>>(mask, flag);
    k_init2<<<64, 256, 0, stream>>>(hidden, h0s, h1s);
    k_conv<<<5376, 256, 0, stream>>>(W_ih, W_hh, W_in, W_out, WB16, winb, woutb);
    k_packA<<<512, 256, 0, stream>>>(W_ih, wih0p);
    k_gih0_mfma<<<dim3(8, 64), 256, 0, stream>>>(tokens, embed, wih0p, b_ih, b_hh, gih0);

    for (int k = 0; k <= 64; k++) {
        const int r = k & 1, w = r ^ 1;
        k_phase<<<512, 256, 0, stream>>>(k, gih0, whh0b, wih1b, whh1b, bih1, bhh1, cells,
                                         h0s + r * 16384, h0s + w * 16384,
                                         h20s + r * 16384, h20s + w * 16384,
                                         h1s + r * 16384, h1s + w * 16384, H2);
    }

    k_x2<<<dim3(32, 32), 256, 0, stream>>>(H2, winb, b_in, XQ);
    k_att2<<<dim3(32, 32), 256, 0, stream>>>(XQ, enc, mask, flag, CTX);
    k_out2<<<dim3(16, 32), 256, 0, stream>>>(CTX, H2, woutb, b_out, out);
}

// Round 19
// 1318.228 us; speedup vs baseline: 1.2799x; 1.2799x over previous
//
#include <hip/hip_runtime.h>
#include <math.h>

typedef unsigned short u16;
typedef __attribute__((ext_vector_type(4))) float f4;
typedef __attribute__((ext_vector_type(8))) unsigned short us8;
typedef __attribute__((ext_vector_type(8))) short bfrag;
typedef __attribute__((ext_vector_type(4))) float f32x4;

#define BB 32
#define TT 64
#define DD 512
#define G4_ 2048

__device__ __forceinline__ float sigf(float x) { return 1.0f / (1.0f + expf(-x)); }
__device__ __forceinline__ float bf2f(u16 u) {
    union { unsigned int i; float f; } v; v.i = ((unsigned int)u) << 16; return v.f;
}
__device__ __forceinline__ u16 f2bf(float f) {
    union { float f; unsigned int i; } v; v.f = f;
    unsigned int r = v.i + 0x7fffu + ((v.i >> 16) & 1u);
    return (u16)(r >> 16);
}

// ---------------------------------------------------------------------------
// mask dtype classifier: 0=u8(bool), 1=i32, 2=bf16, 3=f32. Deterministic.
// ---------------------------------------------------------------------------
__global__ void k_flag(const unsigned char* __restrict__ m, int* __restrict__ flag) {
    int tid = threadIdx.x;
    int badbyte = 0, nonz_off = 0, evenu16_nz = 0;
    for (int i = tid * 16; i < tid * 16 + 16; i++) {
        unsigned char c = m[i];
        if (c > 1) badbyte = 1;
        if ((i & 3) != 0 && c != 0) nonz_off = 1;
    }
    const u16* mu = (const u16*)m;
    for (int i = tid * 8; i < tid * 8 + 8; i++) {
        if ((i & 1) == 0 && mu[i] != 0) evenu16_nz = 1;
    }
    __shared__ int s_bad, s_noff, s_env;
    if (tid == 0) { s_bad = 0; s_noff = 0; s_env = 0; }
    __syncthreads();
    if (badbyte) atomicOr(&s_bad, 1);
    if (nonz_off) atomicOr(&s_noff, 1);
    if (evenu16_nz) atomicOr(&s_env, 1);
    __syncthreads();
    if (tid == 0) {
        int f;
        if (s_bad) f = s_env ? 2 : 3;
        else       f = s_noff ? 0 : 1;
        *flag = f;
    }
}

// ---------------------------------------------------------------------------
// init: copy initial h-states into both parity buffers.
// ---------------------------------------------------------------------------
__global__ void __launch_bounds__(256) k_init2(const float* __restrict__ hid,
                                               float* __restrict__ h0s,
                                               float* __restrict__ h1s) {
    int i = blockIdx.x * 256 + threadIdx.x;   // 0 .. 16383
    float v0 = hid[i], v1 = hid[16384 + i];
    h0s[i] = v0; h0s[16384 + i] = v0;
    h1s[i] = v1; h1s[16384 + i] = v1;
}

// ---------------------------------------------------------------------------
// convert W_in / W_out to bf16 (RNE). (Recurrent weights now go through
// the MFMA pack instead.)
// ---------------------------------------------------------------------------
__global__ void __launch_bounds__(256) k_conv2(const float* __restrict__ Win,
                                               const float* __restrict__ Wout,
                                               u16* __restrict__ dstIn,
                                               u16* __restrict__ dstOut) {
    size_t e = ((size_t)blockIdx.x * 256 + threadIdx.x) * 4;
    if (e < 524288) {
        f4 v = *(const f4*)&Win[e];
        dstIn[e + 0] = f2bf(v[0]); dstIn[e + 1] = f2bf(v[1]);
        dstIn[e + 2] = f2bf(v[2]); dstIn[e + 3] = f2bf(v[3]);
    } else if (e < 1310720) {
        size_t off = e - 524288;
        f4 v = *(const f4*)&Wout[off];
        dstOut[off + 0] = f2bf(v[0]); dstOut[off + 1] = f2bf(v[1]);
        dstOut[off + 2] = f2bf(v[2]); dstOut[off + 3] = f2bf(v[3]);
    }
}

// ---------------------------------------------------------------------------
// pack W_ih0 into MFMA B-fragment order for k_gih0_mfma (R14-proven).
// ---------------------------------------------------------------------------
__global__ void __launch_bounds__(256) k_packA(const float* __restrict__ Wih0,
                                               u16* __restrict__ Wp) {
    int g = blockIdx.x * 256 + threadIdx.x;   // 0 .. 131071
    int lane = g & 63, grp = g >> 6;          // grp = j16*16 + ks
    int j16 = grp >> 4, ks = grp & 15;
    const float* src = &Wih0[((size_t)(j16 * 16 + (lane & 15))) * 512 + ks * 32 + (lane >> 4) * 8];
    u16* dst = &Wp[(size_t)g * 8];
    f4 v0 = *(const f4*)&src[0];
    f4 v1 = *(const f4*)&src[4];
    dst[0] = f2bf(v0[0]); dst[1] = f2bf(v0[1]); dst[2] = f2bf(v0[2]); dst[3] = f2bf(v0[3]);
    dst[4] = f2bf(v1[0]); dst[5] = f2bf(v1[1]); dst[6] = f2bf(v1[2]); dst[7] = f2bf(v1[3]);
}

// ---------------------------------------------------------------------------
// pack the 3 recurrent matrices {Whh0, Wih1, Whh1} into MFMA B-fragment
// order with gate-strided tiles: tile T = g*32+d16 covers rows
// j = g*512 + d16*16 + (0..15). Fragment (T,ks,lane,e) <-
// W[j = g*512+d16*16+(lane&15)][ks*32+(lane>>4)*8+e].   grid 1536 x 256.
// ---------------------------------------------------------------------------
__global__ void __launch_bounds__(256) k_packPh(const float* __restrict__ Wih,
                                                const float* __restrict__ Whh,
                                                u16* __restrict__ php) {
    int gidx = blockIdx.x * 256 + threadIdx.x;   // 0 .. 393215
    int m = gidx >> 17;                           // 0..2
    int rem = gidx & 131071;
    int lane = rem & 63;
    int q = rem >> 6;                             // 0..2047
    int ks = q & 15, T = q >> 4;                  // T 0..127
    int g = T >> 5, d16 = T & 31;
    int j = g * 512 + d16 * 16 + (lane & 15);
    int kcol = ks * 32 + (lane >> 4) * 8;
    const float* src = (m == 0) ? Whh
                     : (m == 1) ? (Wih + 1048576)
                                : (Whh + 1048576);
    const float* sp = &src[(size_t)j * 512 + kcol];
    u16* dst = &php[((size_t)m << 20) + (size_t)rem * 8];
    f4 v0 = *(const f4*)&sp[0];
    f4 v1 = *(const f4*)&sp[4];
    dst[0] = f2bf(v0[0]); dst[1] = f2bf(v0[1]); dst[2] = f2bf(v0[2]); dst[3] = f2bf(v0[3]);
    dst[4] = f2bf(v1[0]); dst[5] = f2bf(v1[1]); dst[6] = f2bf(v1[2]); dst[7] = f2bf(v1[3]);
}

// ---------------------------------------------------------------------------
// gih0 via MFMA 16x16x32 bf16 (R14-proven, untouched).
// ---------------------------------------------------------------------------
__global__ void __launch_bounds__(256) k_gih0_mfma(const int* __restrict__ tokens,
                                                   const float* __restrict__ embed,
                                                   const u16* __restrict__ Wp,
                                                   const float* __restrict__ bih,
                                                   const float* __restrict__ bhh,
                                                   float* __restrict__ gih0) {
    const int tid = threadIdx.x;
    const int lane = tid & 63, w = tid >> 6;
    const int t = blockIdx.y;
    const int jw = blockIdx.x * 256 + w * 64;
    __shared__ u16 xs[32][520];
    __shared__ int toks[32];
    if (tid < 32) toks[tid] = tokens[tid * TT + t];
    __syncthreads();
    for (int i = tid; i < 32 * 128; i += 256) {
        int b = i >> 7, k4 = i & 127;
        f4 v = *(const f4*)&embed[(size_t)toks[b] * 512 + k4 * 4];
        u16* dst = &xs[b][k4 * 4];
        dst[0] = f2bf(v[0]); dst[1] = f2bf(v[1]); dst[2] = f2bf(v[2]); dst[3] = f2bf(v[3]);
    }
    __syncthreads();

    const int l15 = lane & 15, l4 = lane >> 4;
    f32x4 acc[2][4];
#pragma unroll
    for (int mi = 0; mi < 2; mi++)
#pragma unroll
        for (int ni = 0; ni < 4; ni++) acc[mi][ni] = (f32x4){0.f, 0.f, 0.f, 0.f};

    for (int ks = 0; ks < 16; ks++) {
        bfrag a0 = *(const bfrag*)&xs[l15][ks * 32 + l4 * 8];
        bfrag a1 = *(const bfrag*)&xs[16 + l15][ks * 32 + l4 * 8];
#pragma unroll
        for (int ni = 0; ni < 4; ni++) {
            int j16 = (jw + ni * 16) >> 4;
            bfrag bf = *(const bfrag*)&Wp[(((size_t)j16 * 16 + ks) * 64 + lane) * 8];
            acc[0][ni] = __builtin_amdgcn_mfma_f32_16x16x32_bf16(a0, bf, acc[0][ni], 0, 0, 0);
            acc[1][ni] = __builtin_amdgcn_mfma_f32_16x16x32_bf16(a1, bf, acc[1][ni], 0, 0, 0);
        }
    }

#pragma unroll
    for (int ni = 0; ni < 4; ni++) {
        int j = jw + ni * 16 + l15;
        float bv = bih[j] + bhh[j];
#pragma unroll
        for (int mi = 0; mi < 2; mi++) {
#pragma unroll
            for (int r = 0; r < 4; r++) {
                int b = mi * 16 + l4 * 4 + r;
                gih0[((size_t)(t * 32 + b)) * 2048 + j] = acc[mi][ni][r] + bv;
            }
        }
    }
}

// ---------------------------------------------------------------------------
// MFMA phase kernel, 16 blocks x 256 thr (4 waves), launched 65x.
//  blocks 0..7 : stepA(t=k)   [k<64]  gates = gih0[k] + h0 @ Whh0^T
//  blocks 8..15: stepB(t=k-1) [k>=1]  gates = bias + h20 @ Wih1^T + h1 @ Whh1^T
// Wave w owns d-range [d16*16, d16*16+16), d16 = blk*4+w (stepA) etc.
// Thread holds all 4 gates of its (b,d) -> elementwise is thread-local.
// A: h staged f32->bf16 in LDS (layout == k_gih0_mfma). B: packed php.
// D: col=lane&15 (d-offset), row=(lane>>4)*4+reg (b). [R14-verified layouts]
// ---------------------------------------------------------------------------
__global__ void __launch_bounds__(256) k_phaseM(
    const int k,
    const float* __restrict__ gih0,
    const u16* __restrict__ whh0p,
    const u16* __restrict__ wih1p,
    const u16* __restrict__ whh1p,
    const float* __restrict__ bih1,
    const float* __restrict__ bhh1,
    const float* __restrict__ cells,
    const float* __restrict__ h0r, float* __restrict__ h0w,
    const float* __restrict__ h20r, float* __restrict__ h20w,
    const float* __restrict__ h1r, float* __restrict__ h1w,
    float* __restrict__ H2)
{
    const int tid = threadIdx.x;
    const int lane = tid & 63, w = tid >> 6;
    const int l15 = lane & 15, l4 = lane >> 4;
    __shared__ u16 xsA[32][520];
    __shared__ u16 xsB[32][520];

    if (blockIdx.x < 8) {                       // ======== stepA (t = k)
        if (k >= 64) return;
        for (int i = tid; i < 32 * 128; i += 256) {
            int b = i >> 7, k4 = i & 127;
            f4 v = *(const f4*)&h0r[b * 512 + k4 * 4];
            u16* dst = &xsA[b][k4 * 4];
            dst[0] = f2bf(v[0]); dst[1] = f2bf(v[1]); dst[2] = f2bf(v[2]); dst[3] = f2bf(v[3]);
        }
        __syncthreads();
        const int d16 = blockIdx.x * 4 + w;     // 0..31
        const int d = d16 * 16 + l15;
        f32x4 acc[2][4];
#pragma unroll
        for (int mi = 0; mi < 2; mi++)
#pragma unroll
            for (int g = 0; g < 4; g++) acc[mi][g] = (f32x4){0.f, 0.f, 0.f, 0.f};
        for (int ks = 0; ks < 16; ks++) {
            bfrag a0 = *(const bfrag*)&xsA[l15][ks * 32 + l4 * 8];
            bfrag a1 = *(const bfrag*)&xsA[16 + l15][ks * 32 + l4 * 8];
#pragma unroll
            for (int g = 0; g < 4; g++) {
                int T = g * 32 + d16;
                bfrag bf = *(const bfrag*)&whh0p[(((size_t)T * 16 + ks) * 64 + lane) * 8];
                acc[0][g] = __builtin_amdgcn_mfma_f32_16x16x32_bf16(a0, bf, acc[0][g], 0, 0, 0);
                acc[1][g] = __builtin_amdgcn_mfma_f32_16x16x32_bf16(a1, bf, acc[1][g], 0, 0, 0);
            }
        }
#pragma unroll
        for (int mi = 0; mi < 2; mi++) {
#pragma unroll
            for (int r = 0; r < 4; r++) {
                int b = mi * 16 + l4 * 4 + r;
                const float* grow = &gih0[(size_t)k * 65536 + (size_t)b * 2048];
                float gi = acc[mi][0][r] + grow[0 * 512 + d];
                float gf = acc[mi][1][r] + grow[1 * 512 + d];
                float gg = acc[mi][2][r] + grow[2 * 512 + d];
                float go = acc[mi][3][r] + grow[3 * 512 + d];
                float cell = cells[b * 512 + d];
                float c2 = sigf(gf) * cell + sigf(gi) * tanhf(gg);
                float h2 = sigf(go) * tanhf(c2);
                h0w[b * 512 + d] = c2;          // faithful bug: carry = cell
                h20w[b * 512 + d] = h2;
            }
        }
    } else {                                    // ======== stepB (t = k-1)
        if (k < 1) return;
        for (int i = tid; i < 32 * 128; i += 256) {
            int b = i >> 7, k4 = i & 127;
            f4 v0 = *(const f4*)&h20r[b * 512 + k4 * 4];
            f4 v1 = *(const f4*)&h1r[b * 512 + k4 * 4];
            u16* dA = &xsA[b][k4 * 4];
            u16* dB = &xsB[b][k4 * 4];
            dA[0] = f2bf(v0[0]); dA[1] = f2bf(v0[1]); dA[2] = f2bf(v0[2]); dA[3] = f2bf(v0[3]);
            dB[0] = f2bf(v1[0]); dB[1] = f2bf(v1[1]); dB[2] = f2bf(v1[2]); dB[3] = f2bf(v1[3]);
        }
        __syncthreads();
        const int d16 = (blockIdx.x - 8) * 4 + w;   // 0..31
        const int d = d16 * 16 + l15;
        f32x4 acc[2][4];
#pragma unroll
        for (int mi = 0; mi < 2; mi++)
#pragma unroll
            for (int g = 0; g < 4; g++) acc[mi][g] = (f32x4){0.f, 0.f, 0.f, 0.f};
        for (int ks = 0; ks < 16; ks++) {
            bfrag a0 = *(const bfrag*)&xsA[l15][ks * 32 + l4 * 8];
            bfrag a1 = *(const bfrag*)&xsA[16 + l15][ks * 32 + l4 * 8];
#pragma unroll
            for (int g = 0; g < 4; g++) {
                int T = g * 32 + d16;
                bfrag bf = *(const bfrag*)&wih1p[(((size_t)T * 16 + ks) * 64 + lane) * 8];
                acc[0][g] = __builtin_amdgcn_mfma_f32_16x16x32_bf16(a0, bf, acc[0][g], 0, 0, 0);
                acc[1][g] = __builtin_amdgcn_mfma_f32_16x16x32_bf16(a1, bf, acc[1][g], 0, 0, 0);
            }
        }
        for (int ks = 0; ks < 16; ks++) {
            bfrag a0 = *(const bfrag*)&xsB[l15][ks * 32 + l4 * 8];
            bfrag a1 = *(const bfrag*)&xsB[16 + l15][ks * 32 + l4 * 8];
#pragma unroll
            for (int g = 0; g < 4; g++) {
                int T = g * 32 + d16;
                bfrag bf = *(const bfrag*)&whh1p[(((size_t)T * 16 + ks) * 64 + lane) * 8];
                acc[0][g] = __builtin_amdgcn_mfma_f32_16x16x32_bf16(a0, bf, acc[0][g], 0, 0, 0);
                acc[1][g] = __builtin_amdgcn_mfma_f32_16x16x32_bf16(a1, bf, acc[1][g], 0, 0, 0);
            }
        }
        float bb0 = bih1[0 * 512 + d] + bhh1[0 * 512 + d];
        float bb1v = bih1[1 * 512 + d] + bhh1[1 * 512 + d];
        float bb2 = bih1[2 * 512 + d] + bhh1[2 * 512 + d];
        float bb3 = bih1[3 * 512 + d] + bhh1[3 * 512 + d];
#pragma unroll
        for (int mi = 0; mi < 2; mi++) {
#pragma unroll
            for (int r = 0; r < 4; r++) {
                int b = mi * 16 + l4 * 4 + r;
                float gi = acc[mi][0][r] + bb0;
                float gf = acc[mi][1][r] + bb1v;
                float gg = acc[mi][2][r] + bb2;
                float go = acc[mi][3][r] + bb3;
                float cell = cells[16384 + b * 512 + d];
                float c2 = sigf(gf) * cell + sigf(gi) * tanhf(gg);
                float h2 = sigf(go) * tanhf(c2);
                h1w[b * 512 + d] = c2;          // faithful bug
                H2[(size_t)(k - 1) * 16384 + b * 512 + d] = h2;
            }
        }
    }
}

// ---------------------------------------------------------------------------
// XQ for TWO time-steps per block (R16-proven).
// ---------------------------------------------------------------------------
__global__ void __launch_bounds__(256) k_x2(const float* __restrict__ H2,
                                            const u16* __restrict__ Winb,
                                            const float* __restrict__ bin,
                                            float* __restrict__ XQ) {
    const int tid = threadIdx.x;
    const int j0 = blockIdx.x * 32;
    const int t0 = blockIdx.y * 2;
    const int b = tid & 31, jj = tid >> 5;
    __shared__ float xs[2][32][257];
    float acc[2][4];
#pragma unroll
    for (int tg = 0; tg < 2; tg++)
#pragma unroll
        for (int r = 0; r < 4; r++) acc[tg][r] = bin[j0 + jj * 4 + r];
    for (int c = 0; c < 2; c++) {
        for (int idx = tid; idx < 2 * 32 * 64; idx += 256) {
            int tg = idx >> 11;
            int rem = idx & 2047;
            int b2 = rem >> 6, k4 = rem & 63;
            f4 v = *(const f4*)&H2[(size_t)(t0 + tg) * 16384 + b2 * 512 + c * 256 + k4 * 4];
            float* dst = &xs[tg][b2][k4 * 4];
            dst[0] = v[0]; dst[1] = v[1]; dst[2] = v[2]; dst[3] = v[3];
        }
        __syncthreads();
        for (int k8 = 0; k8 < 32; k8++) {
            float w[4][8];
#pragma unroll
            for (int r = 0; r < 4; r++) {
                us8 wv = *(const us8*)&Winb[(size_t)(j0 + jj * 4 + r) * 512 + c * 256 + k8 * 8];
#pragma unroll
                for (int kk = 0; kk < 8; kk++) w[r][kk] = bf2f(wv[kk]);
            }
#pragma unroll
            for (int tg = 0; tg < 2; tg++) {
#pragma unroll
                for (int kk = 0; kk < 8; kk++) {
                    float xv = xs[tg][b][k8 * 8 + kk];
#pragma unroll
                    for (int r = 0; r < 4; r++) acc[tg][r] += xv * w[r][kk];
                }
            }
        }
        __syncthreads();
    }
#pragma unroll
    for (int tg = 0; tg < 2; tg++) {
        float* xrow = XQ + ((size_t)((t0 + tg) * 32 + b)) * 1024;
#pragma unroll
        for (int r = 0; r < 4; r++) xrow[j0 + jj * 4 + r] = acc[tg][r];
    }
}

// ---------------------------------------------------------------------------
// attention, 2 time-steps per block (R15-proven).
// ---------------------------------------------------------------------------
__global__ void __launch_bounds__(256) k_att2(const float* __restrict__ XQ,
                                              const float* __restrict__ enc,
                                              const unsigned char* __restrict__ mask,
                                              const int* __restrict__ flag,
                                              float* __restrict__ CTX) {
    const int tid = threadIdx.x;
    const int b = blockIdx.x, t0 = blockIdx.y * 2;
    __shared__ float xq[2][1024];
    __shared__ float ered[2][256];
    __shared__ float attn[2][128];
    __shared__ float red2[2][8];
#pragma unroll
    for (int tg = 0; tg < 2; tg++) {
        f4 v = *(const f4*)&XQ[((size_t)((t0 + tg) * 32 + b)) * 1024 + tid * 4];
        float* dst = &xq[tg][tid * 4];
        dst[0] = v[0]; dst[1] = v[1]; dst[2] = v[2]; dst[3] = v[3];
    }
    __syncthreads();
    const int s = tid >> 1, hh = tid & 1;
    float p0 = 0.f, p1 = 0.f;
    const float* erow = enc + ((size_t)(b * 128 + s)) * 1024 + hh * 512;
    const float* xqh0 = &xq[0][hh * 512];
    const float* xqh1 = &xq[1][hh * 512];
    for (int k4 = 0; k4 < 128; k4++) {
        f4 u = *(const f4*)&erow[k4 * 4];
#pragma unroll
        for (int kk = 0; kk < 4; kk++) {
            p0 += u[kk] * xqh0[k4 * 4 + kk];
            p1 += u[kk] * xqh1[k4 * 4 + kk];
        }
    }
    ered[0][tid] = p0; ered[1][tid] = p1;
    __syncthreads();
    bool msk = false;
    if (tid < 128) {
        int f = *flag;
        if (f == 0)      msk = mask[b * 128 + tid] != 0;
        else if (f == 1) msk = ((const int*)mask)[b * 128 + tid] != 0;
        else if (f == 2) msk = ((const u16*)mask)[b * 128 + tid] != 0;
        else             msk = ((const unsigned int*)mask)[b * 128 + tid] != 0;
    }
    const int wave = tid >> 6;
    float e[2];
#pragma unroll
    for (int tg = 0; tg < 2; tg++) {
        e[tg] = -INFINITY;
        if (tid < 128) {
            e[tg] = ered[tg][2 * tid] + ered[tg][2 * tid + 1];
            if (msk) e[tg] = -1e9f;
        }
        float v = e[tg];
#pragma unroll
        for (int off = 32; off >= 1; off >>= 1) v = fmaxf(v, __shfl_xor(v, off));
        if ((tid & 63) == 0) red2[tg][wave] = v;
    }
    __syncthreads();
#pragma unroll
    for (int tg = 0; tg < 2; tg++) {
        float mx = fmaxf(fmaxf(red2[tg][0], red2[tg][1]), fmaxf(red2[tg][2], red2[tg][3]));
        float p = (tid < 128) ? expf(e[tg] - mx) : 0.f;
        float su = p;
#pragma unroll
        for (int off = 32; off >= 1; off >>= 1) su += __shfl_xor(su, off);
        if ((tid & 63) == 0) red2[tg][4 + wave] = su;
        __syncthreads();
        float S = (red2[tg][4] + red2[tg][5]) + (red2[tg][6] + red2[tg][7]);
        if (tid < 128) attn[tg][tid] = p / S;
        __syncthreads();
    }
    float c0[2] = {0, 0}, c1[2] = {0, 0}, c2v[2] = {0, 0}, c3[2] = {0, 0};
    const float* eb = enc + ((size_t)b * 128) * 1024 + tid * 4;
    for (int s2 = 0; s2 < 128; s2++) {
        f4 u = *(const f4*)&eb[(size_t)s2 * 1024];
#pragma unroll
        for (int tg = 0; tg < 2; tg++) {
            float a = attn[tg][s2];
            c0[tg] += a * u[0]; c1[tg] += a * u[1]; c2v[tg] += a * u[2]; c3[tg] += a * u[3];
        }
    }
#pragma unroll
    for (int tg = 0; tg < 2; tg++) {
        float* crow = CTX + ((size_t)((t0 + tg) * 32 + b)) * 1024 + tid * 4;
        crow[0] = c0[tg]; crow[1] = c1[tg]; crow[2] = c2v[tg]; crow[3] = c3[tg];
    }
}

// ---------------------------------------------------------------------------
// out[t,b,:] = tanh([ctx, s] @ W_out^T + b_out)  -> f32 d_out
// 2 time-steps per block; W_out bf16 (R11-proven).
// ---------------------------------------------------------------------------
__global__ void __launch_bounds__(256) k_out2(const float* __restrict__ CTX,
                                              const float* __restrict__ H2,
                                              const u16* __restrict__ Woutb,
                                              const float* __restrict__ bout,
                                              float* __restrict__ out) {
    const int tid = threadIdx.x;
    const int j0 = blockIdx.x * 32;
    const int t0 = blockIdx.y * 2;
    const int b = tid & 31, jj = tid >> 5;
    __shared__ float xs[2][32][257];
    float acc[2][4];
#pragma unroll
    for (int tg = 0; tg < 2; tg++)
#pragma unroll
        for (int r = 0; r < 4; r++) acc[tg][r] = bout[j0 + jj * 4 + r];
    for (int c = 0; c < 6; c++) {
        for (int idx = tid; idx < 2 * 32 * 64; idx += 256) {
            int tg = idx >> 11;
            int rem = idx & 2047;
            int b2 = rem >> 6, k4 = rem & 63;
            int t = t0 + tg;
            const float* src = (c < 4) ? &CTX[(size_t)(t * 32 + b2) * 1024 + c * 256]
                                       : &H2[(size_t)t * 16384 + b2 * 512 + (c - 4) * 256];
            f4 v = *(const f4*)&src[k4 * 4];
            float* dst = &xs[tg][b2][k4 * 4];
            dst[0] = v[0]; dst[1] = v[1]; dst[2] = v[2]; dst[3] = v[3];
        }
        __syncthreads();
        for (int k8 = 0; k8 < 32; k8++) {
            float w[4][8];
#pragma unroll
            for (int r = 0; r < 4; r++) {
                us8 wv = *(const us8*)&Woutb[(size_t)(j0 + jj * 4 + r) * 1536 + c * 256 + k8 * 8];
#pragma unroll
                for (int kk = 0; kk < 8; kk++) w[r][kk] = bf2f(wv[kk]);
            }
#pragma unroll
            for (int tg = 0; tg < 2; tg++) {
#pragma unroll
                for (int kk = 0; kk < 8; kk++) {
                    float xv = xs[tg][b][k8 * 8 + kk];
#pragma unroll
                    for (int r = 0; r < 4; r++) acc[tg][r] += xv * w[r][kk];
                }
            }
        }
        __syncthreads();
    }
#pragma unroll
    for (int tg = 0; tg < 2; tg++) {
        float* orow = out + ((size_t)((t0 + tg) * 32 + b)) * 512;
#pragma unroll
        for (int r = 0; r < 4; r++) orow[j0 + jj * 4 + r] = tanhf(acc[tg][r]);
    }
}

// ---------------------------------------------------------------------------
extern "C" void kernel_launch(void* const* d_in, const int* in_sizes, int n_in,
                              void* d_out, int out_size, void* d_ws, size_t ws_size,
                              hipStream_t stream) {
    const int* tokens   = (const int*)d_in[0];
    const float* enc    = (const float*)d_in[1];
    const float* hidden = (const float*)d_in[2];
    const float* cells  = (const float*)d_in[3];
    const unsigned char* mask = (const unsigned char*)d_in[4];
    const float* embed  = (const float*)d_in[5];
    const float* W_ih   = (const float*)d_in[6];
    const float* W_hh   = (const float*)d_in[7];
    const float* b_ih   = (const float*)d_in[8];
    const float* b_hh   = (const float*)d_in[9];
    const float* W_in   = (const float*)d_in[10];
    const float* b_in   = (const float*)d_in[11];
    const float* W_out  = (const float*)d_in[12];
    const float* b_out  = (const float*)d_in[13];
    float* out = (float*)d_out;

    float* ws = (float*)d_ws;
    // Phase-time layout:
    float* gih0 = ws;                              // [0, 4194304) — dead after phases
    float* h0s  = ws + 4194304;                    // 32768 (2 parities)
    float* h20s = ws + 4227072;                    // 32768
    float* h1s  = ws + 4259840;                    // 32768
    float* H2   = ws + 4292608;                    // 1,048,576 -> ends 5,341,184
    u16*   php  = (u16*)(ws + 5341184);            // 3 x 1,048,576 u16 -> ends 6,914,048
    u16*   whh0p = php;
    u16*   wih1p = php + 1048576;
    u16*   whh1p = php + 2097152;
    u16*   winb  = (u16*)(ws + 6914048);           // 524,288 u16 -> ends 7,176,192
    u16*   woutb = (u16*)(ws + 7176192);           // 786,432 u16 -> ends 7,569,408
    u16*   wih0p = (u16*)(ws + 7569408);           // 1,048,576 u16 -> ends 8,093,696
    int*   flag  = (int*)(ws + 8093696);
    // Tail-time layout (gih0 region reused):
    float* XQ   = ws;                              // [0, 2097152)
    float* CTX  = ws + 2097152;                    // [2097152, 4194304)

    const float* bih1 = b_ih + G4_;
    const float* bhh1 = b_hh + G4_;

    k_flag<<<1, 256, 0, stream>>>(mask, flag);
    k_init2<<<64, 256, 0, stream>>>(hidden, h0s, h1s);
    k_conv2<<<1280, 256, 0, stream>>>(W_in, W_out, winb, woutb);
    k_packA<<<512, 256, 0, stream>>>(W_ih, wih0p);
    k_packPh<<<1536, 256, 0, stream>>>(W_ih, W_hh, php);
    k_gih0_mfma<<<dim3(8, 64), 256, 0, stream>>>(tokens, embed, wih0p, b_ih, b_hh, gih0);

    for (int k = 0; k <= 64; k++) {
        const int r = k & 1, w = r ^ 1;
        k_phaseM<<<16, 256, 0, stream>>>(k, gih0, whh0p, wih1p, whh1p, bih1, bhh1, cells,
                                         h0s + r * 16384, h0s + w * 16384,
                                         h20s + r * 16384, h20s + w * 16384,
                                         h1s + r * 16384, h1s + w * 16384, H2);
    }

    k_x2<<<dim3(32, 32), 256, 0, stream>>>(H2, winb, b_in, XQ);
    k_att2<<<dim3(32, 32), 256, 0, stream>>>(XQ, enc, mask, flag, CTX);
    k_out2<<<dim3(16, 32), 256, 0, stream>>>(CTX, H2, woutb, b_out, out);
}

// Round 20
// 1219.137 us; speedup vs baseline: 1.3839x; 1.0813x over previous
//
#include <hip/hip_runtime.h>
#include <math.h>

typedef unsigned short u16;
typedef __attribute__((ext_vector_type(4))) float f4;
typedef __attribute__((ext_vector_type(8))) unsigned short us8;
typedef __attribute__((ext_vector_type(8))) short bfrag;
typedef __attribute__((ext_vector_type(4))) float f32x4;

#define BB 32
#define TT 64
#define DD 512
#define G4_ 2048

__device__ __forceinline__ float sigf(float x) { return 1.0f / (1.0f + expf(-x)); }
__device__ __forceinline__ float bf2f(u16 u) {
    union { unsigned int i; float f; } v; v.i = ((unsigned int)u) << 16; return v.f;
}
__device__ __forceinline__ u16 f2bf(float f) {
    union { float f; unsigned int i; } v; v.f = f;
    unsigned int r = v.i + 0x7fffu + ((v.i >> 16) & 1u);
    return (u16)(r >> 16);
}

// ---------------------------------------------------------------------------
// mask dtype classifier: 0=u8(bool), 1=i32, 2=bf16, 3=f32. Deterministic.
// ---------------------------------------------------------------------------
__global__ void k_flag(const unsigned char* __restrict__ m, int* __restrict__ flag) {
    int tid = threadIdx.x;
    int badbyte = 0, nonz_off = 0, evenu16_nz = 0;
    for (int i = tid * 16; i < tid * 16 + 16; i++) {
        unsigned char c = m[i];
        if (c > 1) badbyte = 1;
        if ((i & 3) != 0 && c != 0) nonz_off = 1;
    }
    const u16* mu = (const u16*)m;
    for (int i = tid * 8; i < tid * 8 + 8; i++) {
        if ((i & 1) == 0 && mu[i] != 0) evenu16_nz = 1;
    }
    __shared__ int s_bad, s_noff, s_env;
    if (tid == 0) { s_bad = 0; s_noff = 0; s_env = 0; }
    __syncthreads();
    if (badbyte) atomicOr(&s_bad, 1);
    if (nonz_off) atomicOr(&s_noff, 1);
    if (evenu16_nz) atomicOr(&s_env, 1);
    __syncthreads();
    if (tid == 0) {
        int f;
        if (s_bad) f = s_env ? 2 : 3;
        else       f = s_noff ? 0 : 1;
        *flag = f;
    }
}

// ---------------------------------------------------------------------------
// init: copy initial h-states into both parity buffers.
// ---------------------------------------------------------------------------
__global__ void __launch_bounds__(256) k_init2(const float* __restrict__ hid,
                                               float* __restrict__ h0s,
                                               float* __restrict__ h1s) {
    int i = blockIdx.x * 256 + threadIdx.x;   // 0 .. 16383
    float v0 = hid[i], v1 = hid[16384 + i];
    h0s[i] = v0; h0s[16384 + i] = v0;
    h1s[i] = v1; h1s[16384 + i] = v1;
}

// ---------------------------------------------------------------------------
// pack W_in into MFMA B-fragment order (1024 rows x K 512):
// Wp[((j16*16+ks)*64+lane)*8+e] = Win[(j16*16+(lane&15))*512 + ks*32+(lane>>4)*8+e]
// grid 256 x 256.
// ---------------------------------------------------------------------------
__global__ void __launch_bounds__(256) k_packIn(const float* __restrict__ Win,
                                                u16* __restrict__ Wp) {
    int g = blockIdx.x * 256 + threadIdx.x;   // 0 .. 65535
    int lane = g & 63, grp = g >> 6;          // grp = j16*16 + ks, j16 0..63
    int j16 = grp >> 4, ks = grp & 15;
    const float* src = &Win[((size_t)(j16 * 16 + (lane & 15))) * 512 + ks * 32 + (lane >> 4) * 8];
    u16* dst = &Wp[(size_t)g * 8];
    f4 v0 = *(const f4*)&src[0];
    f4 v1 = *(const f4*)&src[4];
    dst[0] = f2bf(v0[0]); dst[1] = f2bf(v0[1]); dst[2] = f2bf(v0[2]); dst[3] = f2bf(v0[3]);
    dst[4] = f2bf(v1[0]); dst[5] = f2bf(v1[1]); dst[6] = f2bf(v1[2]); dst[7] = f2bf(v1[3]);
}

// ---------------------------------------------------------------------------
// pack W_out into MFMA B-fragment order (512 rows x K 1536):
// Wp[((j16*48+ks)*64+lane)*8+e] = Wout[(j16*16+(lane&15))*1536 + ks*32+(lane>>4)*8+e]
// grid 384 x 256 (j16 0..31, ks 0..47).
// ---------------------------------------------------------------------------
__global__ void __launch_bounds__(256) k_packOut(const float* __restrict__ Wout,
                                                 u16* __restrict__ Wp) {
    int g = blockIdx.x * 256 + threadIdx.x;   // 0 .. 98303
    int lane = g & 63, grp = g >> 6;          // grp 0..1535
    int j16 = grp / 48, ks = grp % 48;
    const float* src = &Wout[((size_t)(j16 * 16 + (lane & 15))) * 1536 + ks * 32 + (lane >> 4) * 8];
    u16* dst = &Wp[(size_t)g * 8];
    f4 v0 = *(const f4*)&src[0];
    f4 v1 = *(const f4*)&src[4];
    dst[0] = f2bf(v0[0]); dst[1] = f2bf(v0[1]); dst[2] = f2bf(v0[2]); dst[3] = f2bf(v0[3]);
    dst[4] = f2bf(v1[0]); dst[5] = f2bf(v1[1]); dst[6] = f2bf(v1[2]); dst[7] = f2bf(v1[3]);
}

// ---------------------------------------------------------------------------
// pack W_ih0 into MFMA B-fragment order for k_gih0_mfma (R14-proven).
// ---------------------------------------------------------------------------
__global__ void __launch_bounds__(256) k_packA(const float* __restrict__ Wih0,
                                               u16* __restrict__ Wp) {
    int g = blockIdx.x * 256 + threadIdx.x;   // 0 .. 131071
    int lane = g & 63, grp = g >> 6;          // grp = j16*16 + ks
    int j16 = grp >> 4, ks = grp & 15;
    const float* src = &Wih0[((size_t)(j16 * 16 + (lane & 15))) * 512 + ks * 32 + (lane >> 4) * 8];
    u16* dst = &Wp[(size_t)g * 8];
    f4 v0 = *(const f4*)&src[0];
    f4 v1 = *(const f4*)&src[4];
    dst[0] = f2bf(v0[0]); dst[1] = f2bf(v0[1]); dst[2] = f2bf(v0[2]); dst[3] = f2bf(v0[3]);
    dst[4] = f2bf(v1[0]); dst[5] = f2bf(v1[1]); dst[6] = f2bf(v1[2]); dst[7] = f2bf(v1[3]);
}

// ---------------------------------------------------------------------------
// pack the 3 recurrent matrices {Whh0, Wih1, Whh1} into MFMA B-fragment
// order with gate-strided tiles (R19-proven). grid 1536 x 256.
// ---------------------------------------------------------------------------
__global__ void __launch_bounds__(256) k_packPh(const float* __restrict__ Wih,
                                                const float* __restrict__ Whh,
                                                u16* __restrict__ php) {
    int gidx = blockIdx.x * 256 + threadIdx.x;   // 0 .. 393215
    int m = gidx >> 17;                           // 0..2
    int rem = gidx & 131071;
    int lane = rem & 63;
    int q = rem >> 6;                             // 0..2047
    int ks = q & 15, T = q >> 4;                  // T 0..127
    int g = T >> 5, d16 = T & 31;
    int j = g * 512 + d16 * 16 + (lane & 15);
    int kcol = ks * 32 + (lane >> 4) * 8;
    const float* src = (m == 0) ? Whh
                     : (m == 1) ? (Wih + 1048576)
                                : (Whh + 1048576);
    const float* sp = &src[(size_t)j * 512 + kcol];
    u16* dst = &php[((size_t)m << 20) + (size_t)rem * 8];
    f4 v0 = *(const f4*)&sp[0];
    f4 v1 = *(const f4*)&sp[4];
    dst[0] = f2bf(v0[0]); dst[1] = f2bf(v0[1]); dst[2] = f2bf(v0[2]); dst[3] = f2bf(v0[3]);
    dst[4] = f2bf(v1[0]); dst[5] = f2bf(v1[1]); dst[6] = f2bf(v1[2]); dst[7] = f2bf(v1[3]);
}

// ---------------------------------------------------------------------------
// gih0 via MFMA 16x16x32 bf16 (R14-proven, untouched).
// ---------------------------------------------------------------------------
__global__ void __launch_bounds__(256) k_gih0_mfma(const int* __restrict__ tokens,
                                                   const float* __restrict__ embed,
                                                   const u16* __restrict__ Wp,
                                                   const float* __restrict__ bih,
                                                   const float* __restrict__ bhh,
                                                   float* __restrict__ gih0) {
    const int tid = threadIdx.x;
    const int lane = tid & 63, w = tid >> 6;
    const int t = blockIdx.y;
    const int jw = blockIdx.x * 256 + w * 64;
    __shared__ u16 xs[32][520];
    __shared__ int toks[32];
    if (tid < 32) toks[tid] = tokens[tid * TT + t];
    __syncthreads();
    for (int i = tid; i < 32 * 128; i += 256) {
        int b = i >> 7, k4 = i & 127;
        f4 v = *(const f4*)&embed[(size_t)toks[b] * 512 + k4 * 4];
        u16* dst = &xs[b][k4 * 4];
        dst[0] = f2bf(v[0]); dst[1] = f2bf(v[1]); dst[2] = f2bf(v[2]); dst[3] = f2bf(v[3]);
    }
    __syncthreads();

    const int l15 = lane & 15, l4 = lane >> 4;
    f32x4 acc[2][4];
#pragma unroll
    for (int mi = 0; mi < 2; mi++)
#pragma unroll
        for (int ni = 0; ni < 4; ni++) acc[mi][ni] = (f32x4){0.f, 0.f, 0.f, 0.f};

    for (int ks = 0; ks < 16; ks++) {
        bfrag a0 = *(const bfrag*)&xs[l15][ks * 32 + l4 * 8];
        bfrag a1 = *(const bfrag*)&xs[16 + l15][ks * 32 + l4 * 8];
#pragma unroll
        for (int ni = 0; ni < 4; ni++) {
            int j16 = (jw + ni * 16) >> 4;
            bfrag bf = *(const bfrag*)&Wp[(((size_t)j16 * 16 + ks) * 64 + lane) * 8];
            acc[0][ni] = __builtin_amdgcn_mfma_f32_16x16x32_bf16(a0, bf, acc[0][ni], 0, 0, 0);
            acc[1][ni] = __builtin_amdgcn_mfma_f32_16x16x32_bf16(a1, bf, acc[1][ni], 0, 0, 0);
        }
    }

#pragma unroll
    for (int ni = 0; ni < 4; ni++) {
        int j = jw + ni * 16 + l15;
        float bv = bih[j] + bhh[j];
#pragma unroll
        for (int mi = 0; mi < 2; mi++) {
#pragma unroll
            for (int r = 0; r < 4; r++) {
                int b = mi * 16 + l4 * 4 + r;
                gih0[((size_t)(t * 32 + b)) * 2048 + j] = acc[mi][ni][r] + bv;
            }
        }
    }
}

// ---------------------------------------------------------------------------
// MFMA phase kernel (R19-proven, untouched). 16 blocks x 256 thr, 65 launches.
// ---------------------------------------------------------------------------
__global__ void __launch_bounds__(256) k_phaseM(
    const int k,
    const float* __restrict__ gih0,
    const u16* __restrict__ whh0p,
    const u16* __restrict__ wih1p,
    const u16* __restrict__ whh1p,
    const float* __restrict__ bih1,
    const float* __restrict__ bhh1,
    const float* __restrict__ cells,
    const float* __restrict__ h0r, float* __restrict__ h0w,
    const float* __restrict__ h20r, float* __restrict__ h20w,
    const float* __restrict__ h1r, float* __restrict__ h1w,
    float* __restrict__ H2)
{
    const int tid = threadIdx.x;
    const int lane = tid & 63, w = tid >> 6;
    const int l15 = lane & 15, l4 = lane >> 4;
    __shared__ u16 xsA[32][520];
    __shared__ u16 xsB[32][520];

    if (blockIdx.x < 8) {                       // ======== stepA (t = k)
        if (k >= 64) return;
        for (int i = tid; i < 32 * 128; i += 256) {
            int b = i >> 7, k4 = i & 127;
            f4 v = *(const f4*)&h0r[b * 512 + k4 * 4];
            u16* dst = &xsA[b][k4 * 4];
            dst[0] = f2bf(v[0]); dst[1] = f2bf(v[1]); dst[2] = f2bf(v[2]); dst[3] = f2bf(v[3]);
        }
        __syncthreads();
        const int d16 = blockIdx.x * 4 + w;     // 0..31
        const int d = d16 * 16 + l15;
        f32x4 acc[2][4];
#pragma unroll
        for (int mi = 0; mi < 2; mi++)
#pragma unroll
            for (int g = 0; g < 4; g++) acc[mi][g] = (f32x4){0.f, 0.f, 0.f, 0.f};
        for (int ks = 0; ks < 16; ks++) {
            bfrag a0 = *(const bfrag*)&xsA[l15][ks * 32 + l4 * 8];
            bfrag a1 = *(const bfrag*)&xsA[16 + l15][ks * 32 + l4 * 8];
#pragma unroll
            for (int g = 0; g < 4; g++) {
                int T = g * 32 + d16;
                bfrag bf = *(const bfrag*)&whh0p[(((size_t)T * 16 + ks) * 64 + lane) * 8];
                acc[0][g] = __builtin_amdgcn_mfma_f32_16x16x32_bf16(a0, bf, acc[0][g], 0, 0, 0);
                acc[1][g] = __builtin_amdgcn_mfma_f32_16x16x32_bf16(a1, bf, acc[1][g], 0, 0, 0);
            }
        }
#pragma unroll
        for (int mi = 0; mi < 2; mi++) {
#pragma unroll
            for (int r = 0; r < 4; r++) {
                int b = mi * 16 + l4 * 4 + r;
                const float* grow = &gih0[(size_t)k * 65536 + (size_t)b * 2048];
                float gi = acc[mi][0][r] + grow[0 * 512 + d];
                float gf = acc[mi][1][r] + grow[1 * 512 + d];
                float gg = acc[mi][2][r] + grow[2 * 512 + d];
                float go = acc[mi][3][r] + grow[3 * 512 + d];
                float cell = cells[b * 512 + d];
                float c2 = sigf(gf) * cell + sigf(gi) * tanhf(gg);
                float h2 = sigf(go) * tanhf(c2);
                h0w[b * 512 + d] = c2;          // faithful bug: carry = cell
                h20w[b * 512 + d] = h2;
            }
        }
    } else {                                    // ======== stepB (t = k-1)
        if (k < 1) return;
        for (int i = tid; i < 32 * 128; i += 256) {
            int b = i >> 7, k4 = i & 127;
            f4 v0 = *(const f4*)&h20r[b * 512 + k4 * 4];
            f4 v1 = *(const f4*)&h1r[b * 512 + k4 * 4];
            u16* dA = &xsA[b][k4 * 4];
            u16* dB = &xsB[b][k4 * 4];
            dA[0] = f2bf(v0[0]); dA[1] = f2bf(v0[1]); dA[2] = f2bf(v0[2]); dA[3] = f2bf(v0[3]);
            dB[0] = f2bf(v1[0]); dB[1] = f2bf(v1[1]); dB[2] = f2bf(v1[2]); dB[3] = f2bf(v1[3]);
        }
        __syncthreads();
        const int d16 = (blockIdx.x - 8) * 4 + w;   // 0..31
        const int d = d16 * 16 + l15;
        f32x4 acc[2][4];
#pragma unroll
        for (int mi = 0; mi < 2; mi++)
#pragma unroll
            for (int g = 0; g < 4; g++) acc[mi][g] = (f32x4){0.f, 0.f, 0.f, 0.f};
        for (int ks = 0; ks < 16; ks++) {
            bfrag a0 = *(const bfrag*)&xsA[l15][ks * 32 + l4 * 8];
            bfrag a1 = *(const bfrag*)&xsA[16 + l15][ks * 32 + l4 * 8];
#pragma unroll
            for (int g = 0; g < 4; g++) {
                int T = g * 32 + d16;
                bfrag bf = *(const bfrag*)&wih1p[(((size_t)T * 16 + ks) * 64 + lane) * 8];
                acc[0][g] = __builtin_amdgcn_mfma_f32_16x16x32_bf16(a0, bf, acc[0][g], 0, 0, 0);
                acc[1][g] = __builtin_amdgcn_mfma_f32_16x16x32_bf16(a1, bf, acc[1][g], 0, 0, 0);
            }
        }
        for (int ks = 0; ks < 16; ks++) {
            bfrag a0 = *(const bfrag*)&xsB[l15][ks * 32 + l4 * 8];
            bfrag a1 = *(const bfrag*)&xsB[16 + l15][ks * 32 + l4 * 8];
#pragma unroll
            for (int g = 0; g < 4; g++) {
                int T = g * 32 + d16;
                bfrag bf = *(const bfrag*)&whh1p[(((size_t)T * 16 + ks) * 64 + lane) * 8];
                acc[0][g] = __builtin_amdgcn_mfma_f32_16x16x32_bf16(a0, bf, acc[0][g], 0, 0, 0);
                acc[1][g] = __builtin_amdgcn_mfma_f32_16x16x32_bf16(a1, bf, acc[1][g], 0, 0, 0);
            }
        }
        float bb0 = bih1[0 * 512 + d] + bhh1[0 * 512 + d];
        float bb1v = bih1[1 * 512 + d] + bhh1[1 * 512 + d];
        float bb2 = bih1[2 * 512 + d] + bhh1[2 * 512 + d];
        float bb3 = bih1[3 * 512 + d] + bhh1[3 * 512 + d];
#pragma unroll
        for (int mi = 0; mi < 2; mi++) {
#pragma unroll
            for (int r = 0; r < 4; r++) {
                int b = mi * 16 + l4 * 4 + r;
                float gi = acc[mi][0][r] + bb0;
                float gf = acc[mi][1][r] + bb1v;
                float gg = acc[mi][2][r] + bb2;
                float go = acc[mi][3][r] + bb3;
                float cell = cells[16384 + b * 512 + d];
                float c2 = sigf(gf) * cell + sigf(gi) * tanhf(gg);
                float h2 = sigf(go) * tanhf(c2);
                h1w[b * 512 + d] = c2;          // faithful bug
                H2[(size_t)(k - 1) * 16384 + b * 512 + d] = h2;
            }
        }
    }
}

// ---------------------------------------------------------------------------
// XQ via MFMA: M=2048 (t,b), N=1024 (j), K=512. grid (4 j-tiles, 64 t).
// ---------------------------------------------------------------------------
__global__ void __launch_bounds__(256) k_x_mfma(const float* __restrict__ H2,
                                                const u16* __restrict__ Wpin,
                                                const float* __restrict__ bin,
                                                float* __restrict__ XQ) {
    const int tid = threadIdx.x;
    const int lane = tid & 63, w = tid >> 6;
    const int t = blockIdx.y;
    const int jw = blockIdx.x * 256 + w * 64;
    __shared__ u16 xs[32][520];
    for (int i = tid; i < 32 * 128; i += 256) {
        int b = i >> 7, k4 = i & 127;
        f4 v = *(const f4*)&H2[(size_t)t * 16384 + b * 512 + k4 * 4];
        u16* dst = &xs[b][k4 * 4];
        dst[0] = f2bf(v[0]); dst[1] = f2bf(v[1]); dst[2] = f2bf(v[2]); dst[3] = f2bf(v[3]);
    }
    __syncthreads();
    const int l15 = lane & 15, l4 = lane >> 4;
    f32x4 acc[2][4];
#pragma unroll
    for (int mi = 0; mi < 2; mi++)
#pragma unroll
        for (int ni = 0; ni < 4; ni++) acc[mi][ni] = (f32x4){0.f, 0.f, 0.f, 0.f};
    for (int ks = 0; ks < 16; ks++) {
        bfrag a0 = *(const bfrag*)&xs[l15][ks * 32 + l4 * 8];
        bfrag a1 = *(const bfrag*)&xs[16 + l15][ks * 32 + l4 * 8];
#pragma unroll
        for (int ni = 0; ni < 4; ni++) {
            int j16 = (jw + ni * 16) >> 4;
            bfrag bf = *(const bfrag*)&Wpin[(((size_t)j16 * 16 + ks) * 64 + lane) * 8];
            acc[0][ni] = __builtin_amdgcn_mfma_f32_16x16x32_bf16(a0, bf, acc[0][ni], 0, 0, 0);
            acc[1][ni] = __builtin_amdgcn_mfma_f32_16x16x32_bf16(a1, bf, acc[1][ni], 0, 0, 0);
        }
    }
#pragma unroll
    for (int ni = 0; ni < 4; ni++) {
        int j = jw + ni * 16 + l15;
        float bv = bin[j];
#pragma unroll
        for (int mi = 0; mi < 2; mi++) {
#pragma unroll
            for (int r = 0; r < 4; r++) {
                int b = mi * 16 + l4 * 4 + r;
                XQ[((size_t)(t * 32 + b)) * 1024 + j] = acc[mi][ni][r] + bv;
            }
        }
    }
}

// ---------------------------------------------------------------------------
// out via MFMA: M=2048, N=512, K=1536 in 3 chunks {CTX[0:512], CTX[512:1024],
// H2}. grid (2 j-tiles, 64 t). Epilogue tanh.
// ---------------------------------------------------------------------------
__global__ void __launch_bounds__(256) k_out_mfma(const float* __restrict__ CTX,
                                                  const float* __restrict__ H2,
                                                  const u16* __restrict__ Wpout,
                                                  const float* __restrict__ bout,
                                                  float* __restrict__ out) {
    const int tid = threadIdx.x;
    const int lane = tid & 63, w = tid >> 6;
    const int t = blockIdx.y;
    const int jw = blockIdx.x * 256 + w * 64;
    __shared__ u16 xs[32][520];
    const int l15 = lane & 15, l4 = lane >> 4;
    f32x4 acc[2][4];
#pragma unroll
    for (int mi = 0; mi < 2; mi++)
#pragma unroll
        for (int ni = 0; ni < 4; ni++) acc[mi][ni] = (f32x4){0.f, 0.f, 0.f, 0.f};
    for (int c = 0; c < 3; c++) {
        if (c) __syncthreads();                 // xs reuse guard
        for (int i = tid; i < 32 * 128; i += 256) {
            int b = i >> 7, k4 = i & 127;
            f4 v = (c < 2) ? *(const f4*)&CTX[((size_t)(t * 32 + b)) * 1024 + c * 512 + k4 * 4]
                           : *(const f4*)&H2[(size_t)t * 16384 + b * 512 + k4 * 4];
            u16* dst = &xs[b][k4 * 4];
            dst[0] = f2bf(v[0]); dst[1] = f2bf(v[1]); dst[2] = f2bf(v[2]); dst[3] = f2bf(v[3]);
        }
        __syncthreads();
        for (int ks = 0; ks < 16; ks++) {
            bfrag a0 = *(const bfrag*)&xs[l15][ks * 32 + l4 * 8];
            bfrag a1 = *(const bfrag*)&xs[16 + l15][ks * 32 + l4 * 8];
#pragma unroll
            for (int ni = 0; ni < 4; ni++) {
                int j16 = (jw + ni * 16) >> 4;
                bfrag bf = *(const bfrag*)&Wpout[(((size_t)j16 * 48 + c * 16 + ks) * 64 + lane) * 8];
                acc[0][ni] = __builtin_amdgcn_mfma_f32_16x16x32_bf16(a0, bf, acc[0][ni], 0, 0, 0);
                acc[1][ni] = __builtin_amdgcn_mfma_f32_16x16x32_bf16(a1, bf, acc[1][ni], 0, 0, 0);
            }
        }
    }
#pragma unroll
    for (int ni = 0; ni < 4; ni++) {
        int j = jw + ni * 16 + l15;
        float bv = bout[j];
#pragma unroll
        for (int mi = 0; mi < 2; mi++) {
#pragma unroll
            for (int r = 0; r < 4; r++) {
                int b = mi * 16 + l4 * 4 + r;
                out[((size_t)(t * 32 + b)) * 512 + j] = tanhf(acc[mi][ni][r] + bv);
            }
        }
    }
}

// ---------------------------------------------------------------------------
// attention, 2 time-steps per block (R15-proven, untouched).
// ---------------------------------------------------------------------------
__global__ void __launch_bounds__(256) k_att2(const float* __restrict__ XQ,
                                              const float* __restrict__ enc,
                                              const unsigned char* __restrict__ mask,
                                              const int* __restrict__ flag,
                                              float* __restrict__ CTX) {
    const int tid = threadIdx.x;
    const int b = blockIdx.x, t0 = blockIdx.y * 2;
    __shared__ float xq[2][1024];
    __shared__ float ered[2][256];
    __shared__ float attn[2][128];
    __shared__ float red2[2][8];
#pragma unroll
    for (int tg = 0; tg < 2; tg++) {
        f4 v = *(const f4*)&XQ[((size_t)((t0 + tg) * 32 + b)) * 1024 + tid * 4];
        float* dst = &xq[tg][tid * 4];
        dst[0] = v[0]; dst[1] = v[1]; dst[2] = v[2]; dst[3] = v[3];
    }
    __syncthreads();
    const int s = tid >> 1, hh = tid & 1;
    float p0 = 0.f, p1 = 0.f;
    const float* erow = enc + ((size_t)(b * 128 + s)) * 1024 + hh * 512;
    const float* xqh0 = &xq[0][hh * 512];
    const float* xqh1 = &xq[1][hh * 512];
    for (int k4 = 0; k4 < 128; k4++) {
        f4 u = *(const f4*)&erow[k4 * 4];
#pragma unroll
        for (int kk = 0; kk < 4; kk++) {
            p0 += u[kk] * xqh0[k4 * 4 + kk];
            p1 += u[kk] * xqh1[k4 * 4 + kk];
        }
    }
    ered[0][tid] = p0; ered[1][tid] = p1;
    __syncthreads();
    bool msk = false;
    if (tid < 128) {
        int f = *flag;
        if (f == 0)      msk = mask[b * 128 + tid] != 0;
        else if (f == 1) msk = ((const int*)mask)[b * 128 + tid] != 0;
        else if (f == 2) msk = ((const u16*)mask)[b * 128 + tid] != 0;
        else             msk = ((const unsigned int*)mask)[b * 128 + tid] != 0;
    }
    const int wave = tid >> 6;
    float e[2];
#pragma unroll
    for (int tg = 0; tg < 2; tg++) {
        e[tg] = -INFINITY;
        if (tid < 128) {
            e[tg] = ered[tg][2 * tid] + ered[tg][2 * tid + 1];
            if (msk) e[tg] = -1e9f;
        }
        float v = e[tg];
#pragma unroll
        for (int off = 32; off >= 1; off >>= 1) v = fmaxf(v, __shfl_xor(v, off));
        if ((tid & 63) == 0) red2[tg][wave] = v;
    }
    __syncthreads();
#pragma unroll
    for (int tg = 0; tg < 2; tg++) {
        float mx = fmaxf(fmaxf(red2[tg][0], red2[tg][1]), fmaxf(red2[tg][2], red2[tg][3]));
        float p = (tid < 128) ? expf(e[tg] - mx) : 0.f;
        float su = p;
#pragma unroll
        for (int off = 32; off >= 1; off >>= 1) su += __shfl_xor(su, off);
        if ((tid & 63) == 0) red2[tg][4 + wave] = su;
        __syncthreads();
        float S = (red2[tg][4] + red2[tg][5]) + (red2[tg][6] + red2[tg][7]);
        if (tid < 128) attn[tg][tid] = p / S;
        __syncthreads();
    }
    float c0[2] = {0, 0}, c1[2] = {0, 0}, c2v[2] = {0, 0}, c3[2] = {0, 0};
    const float* eb = enc + ((size_t)b * 128) * 1024 + tid * 4;
    for (int s2 = 0; s2 < 128; s2++) {
        f4 u = *(const f4*)&eb[(size_t)s2 * 1024];
#pragma unroll
        for (int tg = 0; tg < 2; tg++) {
            float a = attn[tg][s2];
            c0[tg] += a * u[0]; c1[tg] += a * u[1]; c2v[tg] += a * u[2]; c3[tg] += a * u[3];
        }
    }
#pragma unroll
    for (int tg = 0; tg < 2; tg++) {
        float* crow = CTX + ((size_t)((t0 + tg) * 32 + b)) * 1024 + tid * 4;
        crow[0] = c0[tg]; crow[1] = c1[tg]; crow[2] = c2v[tg]; crow[3] = c3[tg];
    }
}

// ---------------------------------------------------------------------------
extern "C" void kernel_launch(void* const* d_in, const int* in_sizes, int n_in,
                              void* d_out, int out_size, void* d_ws, size_t ws_size,
                              hipStream_t stream) {
    const int* tokens   = (const int*)d_in[0];
    const float* enc    = (const float*)d_in[1];
    const float* hidden = (const float*)d_in[2];
    const float* cells  = (const float*)d_in[3];
    const unsigned char* mask = (const unsigned char*)d_in[4];
    const float* embed  = (const float*)d_in[5];
    const float* W_ih   = (const float*)d_in[6];
    const float* W_hh   = (const float*)d_in[7];
    const float* b_ih   = (const float*)d_in[8];
    const float* b_hh   = (const float*)d_in[9];
    const float* W_in   = (const float*)d_in[10];
    const float* b_in   = (const float*)d_in[11];
    const float* W_out  = (const float*)d_in[12];
    const float* b_out  = (const float*)d_in[13];
    float* out = (float*)d_out;

    float* ws = (float*)d_ws;
    // Phase-time layout:
    float* gih0 = ws;                              // [0, 4194304) — dead after phases
    float* h0s  = ws + 4194304;                    // 32768 (2 parities)
    float* h20s = ws + 4227072;                    // 32768
    float* h1s  = ws + 4259840;                    // 32768
    float* H2   = ws + 4292608;                    // 1,048,576 -> ends 5,341,184
    u16*   php  = (u16*)(ws + 5341184);            // 3 x 1,048,576 u16 -> ends 6,914,048
    u16*   whh0p = php;
    u16*   wih1p = php + 1048576;
    u16*   whh1p = php + 2097152;
    u16*   wpin  = (u16*)(ws + 6914048);           // 524,288 u16 -> ends 7,176,192
    u16*   wpout = (u16*)(ws + 7176192);           // 786,432 u16 -> ends 7,569,408
    u16*   wih0p = (u16*)(ws + 7569408);           // 1,048,576 u16 -> ends 8,093,696
    int*   flag  = (int*)(ws + 8093696);
    // Tail-time layout (gih0 region reused):
    float* XQ   = ws;                              // [0, 2097152)
    float* CTX  = ws + 2097152;                    // [2097152, 4194304)

    const float* bih1 = b_ih + G4_;
    const float* bhh1 = b_hh + G4_;

    k_flag<<<1, 256, 0, stream>>>(mask, flag);
    k_init2<<<64, 256, 0, stream>>>(hidden, h0s, h1s);
    k_packIn<<<256, 256, 0, stream>>>(W_in, wpin);
    k_packOut<<<384, 256, 0, stream>>>(W_out, wpout);
    k_packA<<<512, 256, 0, stream>>>(W_ih, wih0p);
    k_packPh<<<1536, 256, 0, stream>>>(W_ih, W_hh, php);
    k_gih0_mfma<<<dim3(8, 64), 256, 0, stream>>>(tokens, embed, wih0p, b_ih, b_hh, gih0);

    for (int k = 0; k <= 64; k++) {
        const int r = k & 1, w = r ^ 1;
        k_phaseM<<<16, 256, 0, stream>>>(k, gih0, whh0p, wih1p, whh1p, bih1, bhh1, cells,
                                         h0s + r * 16384, h0s + w * 16384,
                                         h20s + r * 16384, h20s + w * 16384,
                                         h1s + r * 16384, h1s + w * 16384, H2);
    }

    k_x_mfma<<<dim3(4, 64), 256, 0, stream>>>(H2, wpin, b_in, XQ);
    k_att2<<<dim3(32, 32), 256, 0, stream>>>(XQ, enc, mask, flag, CTX);
    k_out_mfma<<<dim3(2, 64), 256, 0, stream>>>(CTX, H2, wpout, b_out, out);
}

// Round 21
// 948.026 us; speedup vs baseline: 1.7797x; 1.2860x over previous
//
#include <hip/hip_runtime.h>
#include <math.h>

typedef unsigned short u16;
typedef __attribute__((ext_vector_type(4))) float f4;
typedef __attribute__((ext_vector_type(8))) unsigned short us8;
typedef __attribute__((ext_vector_type(8))) short bfrag;
typedef __attribute__((ext_vector_type(4))) float f32x4;

#define BB 32
#define TT 64
#define DD 512
#define G4_ 2048

__device__ __forceinline__ float sigf(float x) { return 1.0f / (1.0f + expf(-x)); }
__device__ __forceinline__ float bf2f(u16 u) {
    union { unsigned int i; float f; } v; v.i = ((unsigned int)u) << 16; return v.f;
}
__device__ __forceinline__ u16 f2bf(float f) {
    union { float f; unsigned int i; } v; v.f = f;
    unsigned int r = v.i + 0x7fffu + ((v.i >> 16) & 1u);
    return (u16)(r >> 16);
}

// ---------------------------------------------------------------------------
// mask dtype classifier: 0=u8(bool), 1=i32, 2=bf16, 3=f32. Deterministic.
// ---------------------------------------------------------------------------
__global__ void k_flag(const unsigned char* __restrict__ m, int* __restrict__ flag) {
    int tid = threadIdx.x;
    int badbyte = 0, nonz_off = 0, evenu16_nz = 0;
    for (int i = tid * 16; i < tid * 16 + 16; i++) {
        unsigned char c = m[i];
        if (c > 1) badbyte = 1;
        if ((i & 3) != 0 && c != 0) nonz_off = 1;
    }
    const u16* mu = (const u16*)m;
    for (int i = tid * 8; i < tid * 8 + 8; i++) {
        if ((i & 1) == 0 && mu[i] != 0) evenu16_nz = 1;
    }
    __shared__ int s_bad, s_noff, s_env;
    if (tid == 0) { s_bad = 0; s_noff = 0; s_env = 0; }
    __syncthreads();
    if (badbyte) atomicOr(&s_bad, 1);
    if (nonz_off) atomicOr(&s_noff, 1);
    if (evenu16_nz) atomicOr(&s_env, 1);
    __syncthreads();
    if (tid == 0) {
        int f;
        if (s_bad) f = s_env ? 2 : 3;
        else       f = s_noff ? 0 : 1;
        *flag = f;
    }
}

// ---------------------------------------------------------------------------
// init: h-states to bf16 parity buffers (both parities; k=0 reads r=0 for h0,
// k=1 reads r=1 for h1).
// ---------------------------------------------------------------------------
__global__ void __launch_bounds__(256) k_init2(const float* __restrict__ hid,
                                               u16* __restrict__ h0s,
                                               u16* __restrict__ h1s) {
    int i = blockIdx.x * 256 + threadIdx.x;   // 0 .. 16383
    u16 v0 = f2bf(hid[i]), v1 = f2bf(hid[16384 + i]);
    h0s[i] = v0; h0s[16384 + i] = v0;
    h1s[i] = v1; h1s[16384 + i] = v1;
}

// ---------------------------------------------------------------------------
// pack W_in into MFMA B-fragment order (1024 rows x K 512). grid 256 x 256.
// ---------------------------------------------------------------------------
__global__ void __launch_bounds__(256) k_packIn(const float* __restrict__ Win,
                                                u16* __restrict__ Wp) {
    int g = blockIdx.x * 256 + threadIdx.x;   // 0 .. 65535
    int lane = g & 63, grp = g >> 6;
    int j16 = grp >> 4, ks = grp & 15;
    const float* src = &Win[((size_t)(j16 * 16 + (lane & 15))) * 512 + ks * 32 + (lane >> 4) * 8];
    u16* dst = &Wp[(size_t)g * 8];
    f4 v0 = *(const f4*)&src[0];
    f4 v1 = *(const f4*)&src[4];
    dst[0] = f2bf(v0[0]); dst[1] = f2bf(v0[1]); dst[2] = f2bf(v0[2]); dst[3] = f2bf(v0[3]);
    dst[4] = f2bf(v1[0]); dst[5] = f2bf(v1[1]); dst[6] = f2bf(v1[2]); dst[7] = f2bf(v1[3]);
}

// ---------------------------------------------------------------------------
// pack W_out into MFMA B-fragment order (512 rows x K 1536). grid 384 x 256.
// ---------------------------------------------------------------------------
__global__ void __launch_bounds__(256) k_packOut(const float* __restrict__ Wout,
                                                 u16* __restrict__ Wp) {
    int g = blockIdx.x * 256 + threadIdx.x;   // 0 .. 98303
    int lane = g & 63, grp = g >> 6;          // grp 0..1535
    int j16 = grp / 48, ks = grp % 48;
    const float* src = &Wout[((size_t)(j16 * 16 + (lane & 15))) * 1536 + ks * 32 + (lane >> 4) * 8];
    u16* dst = &Wp[(size_t)g * 8];
    f4 v0 = *(const f4*)&src[0];
    f4 v1 = *(const f4*)&src[4];
    dst[0] = f2bf(v0[0]); dst[1] = f2bf(v0[1]); dst[2] = f2bf(v0[2]); dst[3] = f2bf(v0[3]);
    dst[4] = f2bf(v1[0]); dst[5] = f2bf(v1[1]); dst[6] = f2bf(v1[2]); dst[7] = f2bf(v1[3]);
}

// ---------------------------------------------------------------------------
// pack W_ih0 into MFMA B-fragment order (R14-proven). grid 512 x 256.
// ---------------------------------------------------------------------------
__global__ void __launch_bounds__(256) k_packA(const float* __restrict__ Wih0,
                                               u16* __restrict__ Wp) {
    int g = blockIdx.x * 256 + threadIdx.x;   // 0 .. 131071
    int lane = g & 63, grp = g >> 6;
    int j16 = grp >> 4, ks = grp & 15;
    const float* src = &Wih0[((size_t)(j16 * 16 + (lane & 15))) * 512 + ks * 32 + (lane >> 4) * 8];
    u16* dst = &Wp[(size_t)g * 8];
    f4 v0 = *(const f4*)&src[0];
    f4 v1 = *(const f4*)&src[4];
    dst[0] = f2bf(v0[0]); dst[1] = f2bf(v0[1]); dst[2] = f2bf(v0[2]); dst[3] = f2bf(v0[3]);
    dst[4] = f2bf(v1[0]); dst[5] = f2bf(v1[1]); dst[6] = f2bf(v1[2]); dst[7] = f2bf(v1[3]);
}

// ---------------------------------------------------------------------------
// pack {Whh0, Wih1, Whh1} into MFMA B-fragment order, gate-strided tiles
// (R19-proven). grid 1536 x 256.
// ---------------------------------------------------------------------------
__global__ void __launch_bounds__(256) k_packPh(const float* __restrict__ Wih,
                                                const float* __restrict__ Whh,
                                                u16* __restrict__ php) {
    int gidx = blockIdx.x * 256 + threadIdx.x;   // 0 .. 393215
    int m = gidx >> 17;                           // 0..2
    int rem = gidx & 131071;
    int lane = rem & 63;
    int q = rem >> 6;                             // 0..2047
    int ks = q & 15, T = q >> 4;                  // T 0..127
    int g = T >> 5, d16 = T & 31;
    int j = g * 512 + d16 * 16 + (lane & 15);
    int kcol = ks * 32 + (lane >> 4) * 8;
    const float* src = (m == 0) ? Whh
                     : (m == 1) ? (Wih + 1048576)
                                : (Whh + 1048576);
    const float* sp = &src[(size_t)j * 512 + kcol];
    u16* dst = &php[((size_t)m << 20) + (size_t)rem * 8];
    f4 v0 = *(const f4*)&sp[0];
    f4 v1 = *(const f4*)&sp[4];
    dst[0] = f2bf(v0[0]); dst[1] = f2bf(v0[1]); dst[2] = f2bf(v0[2]); dst[3] = f2bf(v0[3]);
    dst[4] = f2bf(v1[0]); dst[5] = f2bf(v1[1]); dst[6] = f2bf(v1[2]); dst[7] = f2bf(v1[3]);
}

// ---------------------------------------------------------------------------
// gih0 via MFMA 16x16x32 bf16 (R14-proven, untouched).
// ---------------------------------------------------------------------------
__global__ void __launch_bounds__(256) k_gih0_mfma(const int* __restrict__ tokens,
                                                   const float* __restrict__ embed,
                                                   const u16* __restrict__ Wp,
                                                   const float* __restrict__ bih,
                                                   const float* __restrict__ bhh,
                                                   float* __restrict__ gih0) {
    const int tid = threadIdx.x;
    const int lane = tid & 63, w = tid >> 6;
    const int t = blockIdx.y;
    const int jw = blockIdx.x * 256 + w * 64;
    __shared__ u16 xs[32][520];
    __shared__ int toks[32];
    if (tid < 32) toks[tid] = tokens[tid * TT + t];
    __syncthreads();
    for (int i = tid; i < 32 * 128; i += 256) {
        int b = i >> 7, k4 = i & 127;
        f4 v = *(const f4*)&embed[(size_t)toks[b] * 512 + k4 * 4];
        u16* dst = &xs[b][k4 * 4];
        dst[0] = f2bf(v[0]); dst[1] = f2bf(v[1]); dst[2] = f2bf(v[2]); dst[3] = f2bf(v[3]);
    }
    __syncthreads();

    const int l15 = lane & 15, l4 = lane >> 4;
    f32x4 acc[2][4];
#pragma unroll
    for (int mi = 0; mi < 2; mi++)
#pragma unroll
        for (int ni = 0; ni < 4; ni++) acc[mi][ni] = (f32x4){0.f, 0.f, 0.f, 0.f};

    for (int ks = 0; ks < 16; ks++) {
        bfrag a0 = *(const bfrag*)&xs[l15][ks * 32 + l4 * 8];
        bfrag a1 = *(const bfrag*)&xs[16 + l15][ks * 32 + l4 * 8];
#pragma unroll
        for (int ni = 0; ni < 4; ni++) {
            int j16 = (jw + ni * 16) >> 4;
            bfrag bf = *(const bfrag*)&Wp[(((size_t)j16 * 16 + ks) * 64 + lane) * 8];
            acc[0][ni] = __builtin_amdgcn_mfma_f32_16x16x32_bf16(a0, bf, acc[0][ni], 0, 0, 0);
            acc[1][ni] = __builtin_amdgcn_mfma_f32_16x16x32_bf16(a1, bf, acc[1][ni], 0, 0, 0);
        }
    }

#pragma unroll
    for (int ni = 0; ni < 4; ni++) {
        int j = jw + ni * 16 + l15;
        float bv = bih[j] + bhh[j];
#pragma unroll
        for (int mi = 0; mi < 2; mi++) {
#pragma unroll
            for (int r = 0; r < 4; r++) {
                int b = mi * 16 + l4 * 4 + r;
                gih0[((size_t)(t * 32 + b)) * 2048 + j] = acc[mi][ni][r] + bv;
            }
        }
    }
}

// ---------------------------------------------------------------------------
// MFMA phase kernel, bf16 h-state (pure-copy staging). 16 blocks x 256 thr.
// blocks 0..7 : stepA(t=k); blocks 8..15: stepB(t=k-1).
// Epilogues write f2bf(value) — bit-identical to staging-time conversion.
// ---------------------------------------------------------------------------
__global__ void __launch_bounds__(256) k_phaseM(
    const int k,
    const float* __restrict__ gih0,
    const u16* __restrict__ whh0p,
    const u16* __restrict__ wih1p,
    const u16* __restrict__ whh1p,
    const float* __restrict__ bih1,
    const float* __restrict__ bhh1,
    const float* __restrict__ cells,
    const u16* __restrict__ h0r, u16* __restrict__ h0w,
    const u16* __restrict__ h20r, u16* __restrict__ h20w,
    const u16* __restrict__ h1r, u16* __restrict__ h1w,
    u16* __restrict__ H2)
{
    const int tid = threadIdx.x;
    const int lane = tid & 63, w = tid >> 6;
    const int l15 = lane & 15, l4 = lane >> 4;
    __shared__ u16 xsA[32][520];
    __shared__ u16 xsB[32][520];

    if (blockIdx.x < 8) {                       // ======== stepA (t = k)
        if (k >= 64) return;
        for (int i = tid; i < 2048; i += 256) { // 32 rows x 512 u16 / 8-wide
            int b = i >> 6, k8 = i & 63;
            *(us8*)&xsA[b][k8 * 8] = *(const us8*)&h0r[b * 512 + k8 * 8];
        }
        __syncthreads();
        const int d16 = blockIdx.x * 4 + w;     // 0..31
        const int d = d16 * 16 + l15;
        f32x4 acc[2][4];
#pragma unroll
        for (int mi = 0; mi < 2; mi++)
#pragma unroll
            for (int g = 0; g < 4; g++) acc[mi][g] = (f32x4){0.f, 0.f, 0.f, 0.f};
        for (int ks = 0; ks < 16; ks++) {
            bfrag a0 = *(const bfrag*)&xsA[l15][ks * 32 + l4 * 8];
            bfrag a1 = *(const bfrag*)&xsA[16 + l15][ks * 32 + l4 * 8];
#pragma unroll
            for (int g = 0; g < 4; g++) {
                int T = g * 32 + d16;
                bfrag bf = *(const bfrag*)&whh0p[(((size_t)T * 16 + ks) * 64 + lane) * 8];
                acc[0][g] = __builtin_amdgcn_mfma_f32_16x16x32_bf16(a0, bf, acc[0][g], 0, 0, 0);
                acc[1][g] = __builtin_amdgcn_mfma_f32_16x16x32_bf16(a1, bf, acc[1][g], 0, 0, 0);
            }
        }
#pragma unroll
        for (int mi = 0; mi < 2; mi++) {
#pragma unroll
            for (int r = 0; r < 4; r++) {
                int b = mi * 16 + l4 * 4 + r;
                const float* grow = &gih0[(size_t)k * 65536 + (size_t)b * 2048];
                float gi = acc[mi][0][r] + grow[0 * 512 + d];
                float gf = acc[mi][1][r] + grow[1 * 512 + d];
                float gg = acc[mi][2][r] + grow[2 * 512 + d];
                float go = acc[mi][3][r] + grow[3 * 512 + d];
                float cell = cells[b * 512 + d];
                float c2 = sigf(gf) * cell + sigf(gi) * tanhf(gg);
                float h2 = sigf(go) * tanhf(c2);
                h0w[b * 512 + d] = f2bf(c2);    // faithful bug: carry = cell
                h20w[b * 512 + d] = f2bf(h2);
            }
        }
    } else {                                    // ======== stepB (t = k-1)
        if (k < 1) return;
        for (int i = tid; i < 2048; i += 256) {
            int b = i >> 6, k8 = i & 63;
            *(us8*)&xsA[b][k8 * 8] = *(const us8*)&h20r[b * 512 + k8 * 8];
            *(us8*)&xsB[b][k8 * 8] = *(const us8*)&h1r[b * 512 + k8 * 8];
        }
        __syncthreads();
        const int d16 = (blockIdx.x - 8) * 4 + w;   // 0..31
        const int d = d16 * 16 + l15;
        f32x4 acc[2][4];
#pragma unroll
        for (int mi = 0; mi < 2; mi++)
#pragma unroll
            for (int g = 0; g < 4; g++) acc[mi][g] = (f32x4){0.f, 0.f, 0.f, 0.f};
        for (int ks = 0; ks < 16; ks++) {
            bfrag a0 = *(const bfrag*)&xsA[l15][ks * 32 + l4 * 8];
            bfrag a1 = *(const bfrag*)&xsA[16 + l15][ks * 32 + l4 * 8];
#pragma unroll
            for (int g = 0; g < 4; g++) {
                int T = g * 32 + d16;
                bfrag bf = *(const bfrag*)&wih1p[(((size_t)T * 16 + ks) * 64 + lane) * 8];
                acc[0][g] = __builtin_amdgcn_mfma_f32_16x16x32_bf16(a0, bf, acc[0][g], 0, 0, 0);
                acc[1][g] = __builtin_amdgcn_mfma_f32_16x16x32_bf16(a1, bf, acc[1][g], 0, 0, 0);
            }
        }
        for (int ks = 0; ks < 16; ks++) {
            bfrag a0 = *(const bfrag*)&xsB[l15][ks * 32 + l4 * 8];
            bfrag a1 = *(const bfrag*)&xsB[16 + l15][ks * 32 + l4 * 8];
#pragma unroll
            for (int g = 0; g < 4; g++) {
                int T = g * 32 + d16;
                bfrag bf = *(const bfrag*)&whh1p[(((size_t)T * 16 + ks) * 64 + lane) * 8];
                acc[0][g] = __builtin_amdgcn_mfma_f32_16x16x32_bf16(a0, bf, acc[0][g], 0, 0, 0);
                acc[1][g] = __builtin_amdgcn_mfma_f32_16x16x32_bf16(a1, bf, acc[1][g], 0, 0, 0);
            }
        }
        float bb0 = bih1[0 * 512 + d] + bhh1[0 * 512 + d];
        float bb1v = bih1[1 * 512 + d] + bhh1[1 * 512 + d];
        float bb2 = bih1[2 * 512 + d] + bhh1[2 * 512 + d];
        float bb3 = bih1[3 * 512 + d] + bhh1[3 * 512 + d];
#pragma unroll
        for (int mi = 0; mi < 2; mi++) {
#pragma unroll
            for (int r = 0; r < 4; r++) {
                int b = mi * 16 + l4 * 4 + r;
                float gi = acc[mi][0][r] + bb0;
                float gf = acc[mi][1][r] + bb1v;
                float gg = acc[mi][2][r] + bb2;
                float go = acc[mi][3][r] + bb3;
                float cell = cells[16384 + b * 512 + d];
                float c2 = sigf(gf) * cell + sigf(gi) * tanhf(gg);
                float h2 = sigf(go) * tanhf(c2);
                h1w[b * 512 + d] = f2bf(c2);    // faithful bug
                H2[(size_t)(k - 1) * 16384 + b * 512 + d] = f2bf(h2);
            }
        }
    }
}

// ---------------------------------------------------------------------------
// XQ via MFMA: H2 already bf16 -> pure-copy staging. grid (4 j-tiles, 64 t).
// ---------------------------------------------------------------------------
__global__ void __launch_bounds__(256) k_x_mfma(const u16* __restrict__ H2,
                                                const u16* __restrict__ Wpin,
                                                const float* __restrict__ bin,
                                                float* __restrict__ XQ) {
    const int tid = threadIdx.x;
    const int lane = tid & 63, w = tid >> 6;
    const int t = blockIdx.y;
    const int jw = blockIdx.x * 256 + w * 64;
    __shared__ u16 xs[32][520];
    for (int i = tid; i < 2048; i += 256) {
        int b = i >> 6, k8 = i & 63;
        *(us8*)&xs[b][k8 * 8] = *(const us8*)&H2[(size_t)t * 16384 + b * 512 + k8 * 8];
    }
    __syncthreads();
    const int l15 = lane & 15, l4 = lane >> 4;
    f32x4 acc[2][4];
#pragma unroll
    for (int mi = 0; mi < 2; mi++)
#pragma unroll
        for (int ni = 0; ni < 4; ni++) acc[mi][ni] = (f32x4){0.f, 0.f, 0.f, 0.f};
    for (int ks = 0; ks < 16; ks++) {
        bfrag a0 = *(const bfrag*)&xs[l15][ks * 32 + l4 * 8];
        bfrag a1 = *(const bfrag*)&xs[16 + l15][ks * 32 + l4 * 8];
#pragma unroll
        for (int ni = 0; ni < 4; ni++) {
            int j16 = (jw + ni * 16) >> 4;
            bfrag bf = *(const bfrag*)&Wpin[(((size_t)j16 * 16 + ks) * 64 + lane) * 8];
            acc[0][ni] = __builtin_amdgcn_mfma_f32_16x16x32_bf16(a0, bf, acc[0][ni], 0, 0, 0);
            acc[1][ni] = __builtin_amdgcn_mfma_f32_16x16x32_bf16(a1, bf, acc[1][ni], 0, 0, 0);
        }
    }
#pragma unroll
    for (int ni = 0; ni < 4; ni++) {
        int j = jw + ni * 16 + l15;
        float bv = bin[j];
#pragma unroll
        for (int mi = 0; mi < 2; mi++) {
#pragma unroll
            for (int r = 0; r < 4; r++) {
                int b = mi * 16 + l4 * 4 + r;
                XQ[((size_t)(t * 32 + b)) * 1024 + j] = acc[mi][ni][r] + bv;
            }
        }
    }
}

// ---------------------------------------------------------------------------
// out via MFMA: K=1536 in 3 chunks {CTX f32 x2, H2 bf16}. grid (2, 64).
// ---------------------------------------------------------------------------
__global__ void __launch_bounds__(256) k_out_mfma(const float* __restrict__ CTX,
                                                  const u16* __restrict__ H2,
                                                  const u16* __restrict__ Wpout,
                                                  const float* __restrict__ bout,
                                                  float* __restrict__ out) {
    const int tid = threadIdx.x;
    const int lane = tid & 63, w = tid >> 6;
    const int t = blockIdx.y;
    const int jw = blockIdx.x * 256 + w * 64;
    __shared__ u16 xs[32][520];
    const int l15 = lane & 15, l4 = lane >> 4;
    f32x4 acc[2][4];
#pragma unroll
    for (int mi = 0; mi < 2; mi++)
#pragma unroll
        for (int ni = 0; ni < 4; ni++) acc[mi][ni] = (f32x4){0.f, 0.f, 0.f, 0.f};
    for (int c = 0; c < 3; c++) {
        if (c) __syncthreads();                 // xs reuse guard
        if (c < 2) {
            for (int i = tid; i < 32 * 128; i += 256) {
                int b = i >> 7, k4 = i & 127;
                f4 v = *(const f4*)&CTX[((size_t)(t * 32 + b)) * 1024 + c * 512 + k4 * 4];
                u16* dst = &xs[b][k4 * 4];
                dst[0] = f2bf(v[0]); dst[1] = f2bf(v[1]); dst[2] = f2bf(v[2]); dst[3] = f2bf(v[3]);
            }
        } else {
            for (int i = tid; i < 2048; i += 256) {
                int b = i >> 6, k8 = i & 63;
                *(us8*)&xs[b][k8 * 8] = *(const us8*)&H2[(size_t)t * 16384 + b * 512 + k8 * 8];
            }
        }
        __syncthreads();
        for (int ks = 0; ks < 16; ks++) {
            bfrag a0 = *(const bfrag*)&xs[l15][ks * 32 + l4 * 8];
            bfrag a1 = *(const bfrag*)&xs[16 + l15][ks * 32 + l4 * 8];
#pragma unroll
            for (int ni = 0; ni < 4; ni++) {
                int j16 = (jw + ni * 16) >> 4;
                bfrag bf = *(const bfrag*)&Wpout[(((size_t)j16 * 48 + c * 16 + ks) * 64 + lane) * 8];
                acc[0][ni] = __builtin_amdgcn_mfma_f32_16x16x32_bf16(a0, bf, acc[0][ni], 0, 0, 0);
                acc[1][ni] = __builtin_amdgcn_mfma_f32_16x16x32_bf16(a1, bf, acc[1][ni], 0, 0, 0);
            }
        }
    }
#pragma unroll
    for (int ni = 0; ni < 4; ni++) {
        int j = jw + ni * 16 + l15;
        float bv = bout[j];
#pragma unroll
        for (int mi = 0; mi < 2; mi++) {
#pragma unroll
            for (int r = 0; r < 4; r++) {
                int b = mi * 16 + l4 * 4 + r;
                out[((size_t)(t * 32 + b)) * 512 + j] = tanhf(acc[mi][ni][r] + bv);
            }
        }
    }
}

// ---------------------------------------------------------------------------
// attention, FOUR time-steps per block: all t's share every enc read.
// grid (32 b, 16 t-quads), 256 thr. Per-t reduction order unchanged.
// ---------------------------------------------------------------------------
__global__ void __launch_bounds__(256) k_att4(const float* __restrict__ XQ,
                                              const float* __restrict__ enc,
                                              const unsigned char* __restrict__ mask,
                                              const int* __restrict__ flag,
                                              float* __restrict__ CTX) {
    const int tid = threadIdx.x;
    const int b = blockIdx.x, t0 = blockIdx.y * 4;
    __shared__ float xq[4][1024];
    __shared__ float ered[4][256];
    __shared__ float attn[4][128];
    __shared__ float red2[4][8];
#pragma unroll
    for (int tg = 0; tg < 4; tg++) {
        f4 v = *(const f4*)&XQ[((size_t)((t0 + tg) * 32 + b)) * 1024 + tid * 4];
        float* dst = &xq[tg][tid * 4];
        dst[0] = v[0]; dst[1] = v[1]; dst[2] = v[2]; dst[3] = v[3];
    }
    __syncthreads();
    const int s = tid >> 1, hh = tid & 1;
    float p[4] = {0.f, 0.f, 0.f, 0.f};
    const float* erow = enc + ((size_t)(b * 128 + s)) * 1024 + hh * 512;
    for (int k4 = 0; k4 < 128; k4++) {
        f4 u = *(const f4*)&erow[k4 * 4];
#pragma unroll
        for (int kk = 0; kk < 4; kk++) {
#pragma unroll
            for (int tg = 0; tg < 4; tg++)
                p[tg] += u[kk] * xq[tg][hh * 512 + k4 * 4 + kk];
        }
    }
#pragma unroll
    for (int tg = 0; tg < 4; tg++) ered[tg][tid] = p[tg];
    __syncthreads();
    bool msk = false;
    if (tid < 128) {
        int f = *flag;
        if (f == 0)      msk = mask[b * 128 + tid] != 0;
        else if (f == 1) msk = ((const int*)mask)[b * 128 + tid] != 0;
        else if (f == 2) msk = ((const u16*)mask)[b * 128 + tid] != 0;
        else             msk = ((const unsigned int*)mask)[b * 128 + tid] != 0;
    }
    const int wave = tid >> 6;
    float e[4];
#pragma unroll
    for (int tg = 0; tg < 4; tg++) {
        e[tg] = -INFINITY;
        if (tid < 128) {
            e[tg] = ered[tg][2 * tid] + ered[tg][2 * tid + 1];
            if (msk) e[tg] = -1e9f;
        }
        float v = e[tg];
#pragma unroll
        for (int off = 32; off >= 1; off >>= 1) v = fmaxf(v, __shfl_xor(v, off));
        if ((tid & 63) == 0) red2[tg][wave] = v;
    }
    __syncthreads();
#pragma unroll
    for (int tg = 0; tg < 4; tg++) {
        float mx = fmaxf(fmaxf(red2[tg][0], red2[tg][1]), fmaxf(red2[tg][2], red2[tg][3]));
        float pp = (tid < 128) ? expf(e[tg] - mx) : 0.f;
        float su = pp;
#pragma unroll
        for (int off = 32; off >= 1; off >>= 1) su += __shfl_xor(su, off);
        if ((tid & 63) == 0) red2[tg][4 + wave] = su;
        __syncthreads();
        float S = (red2[tg][4] + red2[tg][5]) + (red2[tg][6] + red2[tg][7]);
        if (tid < 128) attn[tg][tid] = pp / S;
        __syncthreads();
    }
    float c0[4] = {0, 0, 0, 0}, c1[4] = {0, 0, 0, 0};
    float c2v[4] = {0, 0, 0, 0}, c3[4] = {0, 0, 0, 0};
    const float* eb = enc + ((size_t)b * 128) * 1024 + tid * 4;
    for (int s2 = 0; s2 < 128; s2++) {
        f4 u = *(const f4*)&eb[(size_t)s2 * 1024];
#pragma unroll
        for (int tg = 0; tg < 4; tg++) {
            float a = attn[tg][s2];
            c0[tg] += a * u[0]; c1[tg] += a * u[1]; c2v[tg] += a * u[2]; c3[tg] += a * u[3];
        }
    }
#pragma unroll
    for (int tg = 0; tg < 4; tg++) {
        float* crow = CTX + ((size_t)((t0 + tg) * 32 + b)) * 1024 + tid * 4;
        crow[0] = c0[tg]; crow[1] = c1[tg]; crow[2] = c2v[tg]; crow[3] = c3[tg];
    }
}

// ---------------------------------------------------------------------------
extern "C" void kernel_launch(void* const* d_in, const int* in_sizes, int n_in,
                              void* d_out, int out_size, void* d_ws, size_t ws_size,
                              hipStream_t stream) {
    const int* tokens   = (const int*)d_in[0];
    const float* enc    = (const float*)d_in[1];
    const float* hidden = (const float*)d_in[2];
    const float* cells  = (const float*)d_in[3];
    const unsigned char* mask = (const unsigned char*)d_in[4];
    const float* embed  = (const float*)d_in[5];
    const float* W_ih   = (const float*)d_in[6];
    const float* W_hh   = (const float*)d_in[7];
    const float* b_ih   = (const float*)d_in[8];
    const float* b_hh   = (const float*)d_in[9];
    const float* W_in   = (const float*)d_in[10];
    const float* b_in   = (const float*)d_in[11];
    const float* W_out  = (const float*)d_in[12];
    const float* b_out  = (const float*)d_in[13];
    float* out = (float*)d_out;

    float* ws = (float*)d_ws;
    // Phase-time layout (f-slot offsets):
    float* gih0 = ws;                              // [0, 4194304) — dead after phases
    u16*   h0s  = (u16*)(ws + 4194304);            // 2x16384 u16 -> 16384 f
    u16*   h20s = (u16*)(ws + 4210688);            // 16384 f
    u16*   h1s  = (u16*)(ws + 4227072);            // 16384 f
    u16*   H2   = (u16*)(ws + 4243456);            // 64x16384 u16 = 524288 f
    u16*   php  = (u16*)(ws + 4767744);            // 3x1048576 u16 = 1572864 f
    u16*   whh0p = php;
    u16*   wih1p = php + 1048576;
    u16*   whh1p = php + 2097152;
    u16*   wpin  = (u16*)(ws + 6340608);           // 524288 u16 = 262144 f
    u16*   wpout = (u16*)(ws + 6602752);           // 786432 u16 = 393216 f
    u16*   wih0p = (u16*)(ws + 6995968);           // 1048576 u16 = 524288 f
    int*   flag  = (int*)(ws + 7520256);
    // Tail-time layout (gih0 region reused):
    float* XQ   = ws;                              // [0, 2097152)
    float* CTX  = ws + 2097152;                    // [2097152, 4194304)

    const float* bih1 = b_ih + G4_;
    const float* bhh1 = b_hh + G4_;

    k_flag<<<1, 256, 0, stream>>>(mask, flag);
    k_init2<<<64, 256, 0, stream>>>(hidden, h0s, h1s);
    k_packIn<<<256, 256, 0, stream>>>(W_in, wpin);
    k_packOut<<<384, 256, 0, stream>>>(W_out, wpout);
    k_packA<<<512, 256, 0, stream>>>(W_ih, wih0p);
    k_packPh<<<1536, 256, 0, stream>>>(W_ih, W_hh, php);
    k_gih0_mfma<<<dim3(8, 64), 256, 0, stream>>>(tokens, embed, wih0p, b_ih, b_hh, gih0);

    for (int k = 0; k <= 64; k++) {
        const int r = k & 1, w = r ^ 1;
        k_phaseM<<<16, 256, 0, stream>>>(k, gih0, whh0p, wih1p, whh1p, bih1, bhh1, cells,
                                         h0s + r * 16384, h0s + w * 16384,
                                         h20s + r * 16384, h20s + w * 16384,
                                         h1s + r * 16384, h1s + w * 16384, H2);
    }

    k_x_mfma<<<dim3(4, 64), 256, 0, stream>>>(H2, wpin, b_in, XQ);
    k_att4<<<dim3(32, 16), 256, 0, stream>>>(XQ, enc, mask, flag, CTX);
    k_out_mfma<<<dim3(2, 64), 256, 0, stream>>>(CTX, H2, wpout, b_out, out);
}

// Round 22
// 936.208 us; speedup vs baseline: 1.8021x; 1.0126x over previous
//
#include <hip/hip_runtime.h>
#include <math.h>

typedef unsigned short u16;
typedef __attribute__((ext_vector_type(4))) float f4;
typedef __attribute__((ext_vector_type(8))) unsigned short us8;
typedef __attribute__((ext_vector_type(8))) short bfrag;
typedef __attribute__((ext_vector_type(4))) float f32x4;

#define BB 32
#define TT 64
#define DD 512
#define G4_ 2048

__device__ __forceinline__ float sigf(float x) { return 1.0f / (1.0f + expf(-x)); }
__device__ __forceinline__ float bf2f(u16 u) {
    union { unsigned int i; float f; } v; v.i = ((unsigned int)u) << 16; return v.f;
}
__device__ __forceinline__ u16 f2bf(float f) {
    union { float f; unsigned int i; } v; v.f = f;
    unsigned int r = v.i + 0x7fffu + ((v.i >> 16) & 1u);
    return (u16)(r >> 16);
}

// ---------------------------------------------------------------------------
// mask dtype classifier: 0=u8(bool), 1=i32, 2=bf16, 3=f32. Deterministic.
// ---------------------------------------------------------------------------
__global__ void k_flag(const unsigned char* __restrict__ m, int* __restrict__ flag) {
    int tid = threadIdx.x;
    int badbyte = 0, nonz_off = 0, evenu16_nz = 0;
    for (int i = tid * 16; i < tid * 16 + 16; i++) {
        unsigned char c = m[i];
        if (c > 1) badbyte = 1;
        if ((i & 3) != 0 && c != 0) nonz_off = 1;
    }
    const u16* mu = (const u16*)m;
    for (int i = tid * 8; i < tid * 8 + 8; i++) {
        if ((i & 1) == 0 && mu[i] != 0) evenu16_nz = 1;
    }
    __shared__ int s_bad, s_noff, s_env;
    if (tid == 0) { s_bad = 0; s_noff = 0; s_env = 0; }
    __syncthreads();
    if (badbyte) atomicOr(&s_bad, 1);
    if (nonz_off) atomicOr(&s_noff, 1);
    if (evenu16_nz) atomicOr(&s_env, 1);
    __syncthreads();
    if (tid == 0) {
        int f;
        if (s_bad) f = s_env ? 2 : 3;
        else       f = s_noff ? 0 : 1;
        *flag = f;
    }
}

// ---------------------------------------------------------------------------
// init: h-states to bf16 parity buffers.
// ---------------------------------------------------------------------------
__global__ void __launch_bounds__(256) k_init2(const float* __restrict__ hid,
                                               u16* __restrict__ h0s,
                                               u16* __restrict__ h1s) {
    int i = blockIdx.x * 256 + threadIdx.x;   // 0 .. 16383
    u16 v0 = f2bf(hid[i]), v1 = f2bf(hid[16384 + i]);
    h0s[i] = v0; h0s[16384 + i] = v0;
    h1s[i] = v1; h1s[16384 + i] = v1;
}

// ---------------------------------------------------------------------------
// pack W_in into MFMA B-fragment order (1024 rows x K 512). grid 256 x 256.
// ---------------------------------------------------------------------------
__global__ void __launch_bounds__(256) k_packIn(const float* __restrict__ Win,
                                                u16* __restrict__ Wp) {
    int g = blockIdx.x * 256 + threadIdx.x;   // 0 .. 65535
    int lane = g & 63, grp = g >> 6;
    int j16 = grp >> 4, ks = grp & 15;
    const float* src = &Win[((size_t)(j16 * 16 + (lane & 15))) * 512 + ks * 32 + (lane >> 4) * 8];
    u16* dst = &Wp[(size_t)g * 8];
    f4 v0 = *(const f4*)&src[0];
    f4 v1 = *(const f4*)&src[4];
    dst[0] = f2bf(v0[0]); dst[1] = f2bf(v0[1]); dst[2] = f2bf(v0[2]); dst[3] = f2bf(v0[3]);
    dst[4] = f2bf(v1[0]); dst[5] = f2bf(v1[1]); dst[6] = f2bf(v1[2]); dst[7] = f2bf(v1[3]);
}

// ---------------------------------------------------------------------------
// pack W_out into MFMA B-fragment order (512 rows x K 1536). grid 384 x 256.
// ---------------------------------------------------------------------------
__global__ void __launch_bounds__(256) k_packOut(const float* __restrict__ Wout,
                                                 u16* __restrict__ Wp) {
    int g = blockIdx.x * 256 + threadIdx.x;   // 0 .. 98303
    int lane = g & 63, grp = g >> 6;          // grp 0..1535
    int j16 = grp / 48, ks = grp % 48;
    const float* src = &Wout[((size_t)(j16 * 16 + (lane & 15))) * 1536 + ks * 32 + (lane >> 4) * 8];
    u16* dst = &Wp[(size_t)g * 8];
    f4 v0 = *(const f4*)&src[0];
    f4 v1 = *(const f4*)&src[4];
    dst[0] = f2bf(v0[0]); dst[1] = f2bf(v0[1]); dst[2] = f2bf(v0[2]); dst[3] = f2bf(v0[3]);
    dst[4] = f2bf(v1[0]); dst[5] = f2bf(v1[1]); dst[6] = f2bf(v1[2]); dst[7] = f2bf(v1[3]);
}

// ---------------------------------------------------------------------------
// pack W_ih0 into MFMA B-fragment order (R14-proven). grid 512 x 256.
// ---------------------------------------------------------------------------
__global__ void __launch_bounds__(256) k_packA(const float* __restrict__ Wih0,
                                               u16* __restrict__ Wp) {
    int g = blockIdx.x * 256 + threadIdx.x;   // 0 .. 131071
    int lane = g & 63, grp = g >> 6;
    int j16 = grp >> 4, ks = grp & 15;
    const float* src = &Wih0[((size_t)(j16 * 16 + (lane & 15))) * 512 + ks * 32 + (lane >> 4) * 8];
    u16* dst = &Wp[(size_t)g * 8];
    f4 v0 = *(const f4*)&src[0];
    f4 v1 = *(const f4*)&src[4];
    dst[0] = f2bf(v0[0]); dst[1] = f2bf(v0[1]); dst[2] = f2bf(v0[2]); dst[3] = f2bf(v0[3]);
    dst[4] = f2bf(v1[0]); dst[5] = f2bf(v1[1]); dst[6] = f2bf(v1[2]); dst[7] = f2bf(v1[3]);
}

// ---------------------------------------------------------------------------
// pack {Whh0, Wih1, Whh1} into MFMA B-fragment order, gate-strided tiles
// (R19-proven). grid 1536 x 256.
// ---------------------------------------------------------------------------
__global__ void __launch_bounds__(256) k_packPh(const float* __restrict__ Wih,
                                                const float* __restrict__ Whh,
                                                u16* __restrict__ php) {
    int gidx = blockIdx.x * 256 + threadIdx.x;   // 0 .. 393215
    int m = gidx >> 17;                           // 0..2
    int rem = gidx & 131071;
    int lane = rem & 63;
    int q = rem >> 6;                             // 0..2047
    int ks = q & 15, T = q >> 4;                  // T 0..127
    int g = T >> 5, d16 = T & 31;
    int j = g * 512 + d16 * 16 + (lane & 15);
    int kcol = ks * 32 + (lane >> 4) * 8;
    const float* src = (m == 0) ? Whh
                     : (m == 1) ? (Wih + 1048576)
                                : (Whh + 1048576);
    const float* sp = &src[(size_t)j * 512 + kcol];
    u16* dst = &php[((size_t)m << 20) + (size_t)rem * 8];
    f4 v0 = *(const f4*)&sp[0];
    f4 v1 = *(const f4*)&sp[4];
    dst[0] = f2bf(v0[0]); dst[1] = f2bf(v0[1]); dst[2] = f2bf(v0[2]); dst[3] = f2bf(v0[3]);
    dst[4] = f2bf(v1[0]); dst[5] = f2bf(v1[1]); dst[6] = f2bf(v1[2]); dst[7] = f2bf(v1[3]);
}

// ---------------------------------------------------------------------------
// gih0 via MFMA, output in ACCUMULATOR-FRAGMENT layout (bias pre-added):
// gih0p[((((t*32 + d16)*4 + g)*2 + mi)*64 + lane)*4 + r] = acc[mi][ni][r] + bias
// where j16 = jw/16 + ni, g = j16>>5, d16 = j16&31. Coalesced f32x4 stores;
// stepA loads these directly as its MFMA C-init.
// ---------------------------------------------------------------------------
__global__ void __launch_bounds__(256) k_gih0_mfma(const int* __restrict__ tokens,
                                                   const float* __restrict__ embed,
                                                   const u16* __restrict__ Wp,
                                                   const float* __restrict__ bih,
                                                   const float* __restrict__ bhh,
                                                   float* __restrict__ gih0p) {
    const int tid = threadIdx.x;
    const int lane = tid & 63, w = tid >> 6;
    const int t = blockIdx.y;
    const int jw = blockIdx.x * 256 + w * 64;
    __shared__ u16 xs[32][520];
    __shared__ int toks[32];
    if (tid < 32) toks[tid] = tokens[tid * TT + t];
    __syncthreads();
    for (int i = tid; i < 32 * 128; i += 256) {
        int b = i >> 7, k4 = i & 127;
        f4 v = *(const f4*)&embed[(size_t)toks[b] * 512 + k4 * 4];
        u16* dst = &xs[b][k4 * 4];
        dst[0] = f2bf(v[0]); dst[1] = f2bf(v[1]); dst[2] = f2bf(v[2]); dst[3] = f2bf(v[3]);
    }
    __syncthreads();

    const int l15 = lane & 15, l4 = lane >> 4;
    f32x4 acc[2][4];
#pragma unroll
    for (int mi = 0; mi < 2; mi++)
#pragma unroll
        for (int ni = 0; ni < 4; ni++) acc[mi][ni] = (f32x4){0.f, 0.f, 0.f, 0.f};

    for (int ks = 0; ks < 16; ks++) {
        bfrag a0 = *(const bfrag*)&xs[l15][ks * 32 + l4 * 8];
        bfrag a1 = *(const bfrag*)&xs[16 + l15][ks * 32 + l4 * 8];
#pragma unroll
        for (int ni = 0; ni < 4; ni++) {
            int j16 = (jw + ni * 16) >> 4;
            bfrag bf = *(const bfrag*)&Wp[(((size_t)j16 * 16 + ks) * 64 + lane) * 8];
            acc[0][ni] = __builtin_amdgcn_mfma_f32_16x16x32_bf16(a0, bf, acc[0][ni], 0, 0, 0);
            acc[1][ni] = __builtin_amdgcn_mfma_f32_16x16x32_bf16(a1, bf, acc[1][ni], 0, 0, 0);
        }
    }

#pragma unroll
    for (int ni = 0; ni < 4; ni++) {
        int j16 = (jw >> 4) + ni;
        int g = j16 >> 5, d16 = j16 & 31;
        int j = j16 * 16 + l15;
        float bv = bih[j] + bhh[j];
#pragma unroll
        for (int mi = 0; mi < 2; mi++) {
            f32x4 sv = acc[mi][ni];
            sv[0] += bv; sv[1] += bv; sv[2] += bv; sv[3] += bv;
            *(f32x4*)&gih0p[(((((size_t)t * 32 + d16) * 4 + g) * 2 + mi) * 64 + lane) * 4] = sv;
        }
    }
}

// ---------------------------------------------------------------------------
// MFMA phase kernel, bf16 h-state; stepA inits acc from fragment-layout gih0p
// (coalesced f32x4 loads, no scattered epilogue reads). 16 blocks x 256 thr.
// ---------------------------------------------------------------------------
__global__ void __launch_bounds__(256) k_phaseM(
    const int k,
    const float* __restrict__ gih0p,
    const u16* __restrict__ whh0p,
    const u16* __restrict__ wih1p,
    const u16* __restrict__ whh1p,
    const float* __restrict__ bih1,
    const float* __restrict__ bhh1,
    const float* __restrict__ cells,
    const u16* __restrict__ h0r, u16* __restrict__ h0w,
    const u16* __restrict__ h20r, u16* __restrict__ h20w,
    const u16* __restrict__ h1r, u16* __restrict__ h1w,
    u16* __restrict__ H2)
{
    const int tid = threadIdx.x;
    const int lane = tid & 63, w = tid >> 6;
    const int l15 = lane & 15, l4 = lane >> 4;
    __shared__ u16 xsA[32][520];
    __shared__ u16 xsB[32][520];

    if (blockIdx.x < 8) {                       // ======== stepA (t = k)
        if (k >= 64) return;
        const int d16 = blockIdx.x * 4 + w;     // 0..31
        const int d = d16 * 16 + l15;
        f32x4 acc[2][4];
#pragma unroll
        for (int mi = 0; mi < 2; mi++)
#pragma unroll
            for (int g = 0; g < 4; g++)
                acc[mi][g] = *(const f32x4*)&gih0p[(((((size_t)k * 32 + d16) * 4 + g) * 2 + mi) * 64 + lane) * 4];
        for (int i = tid; i < 2048; i += 256) { // 32 rows x 512 u16 / 8-wide
            int b = i >> 6, k8 = i & 63;
            *(us8*)&xsA[b][k8 * 8] = *(const us8*)&h0r[b * 512 + k8 * 8];
        }
        __syncthreads();
        for (int ks = 0; ks < 16; ks++) {
            bfrag a0 = *(const bfrag*)&xsA[l15][ks * 32 + l4 * 8];
            bfrag a1 = *(const bfrag*)&xsA[16 + l15][ks * 32 + l4 * 8];
#pragma unroll
            for (int g = 0; g < 4; g++) {
                int T = g * 32 + d16;
                bfrag bf = *(const bfrag*)&whh0p[(((size_t)T * 16 + ks) * 64 + lane) * 8];
                acc[0][g] = __builtin_amdgcn_mfma_f32_16x16x32_bf16(a0, bf, acc[0][g], 0, 0, 0);
                acc[1][g] = __builtin_amdgcn_mfma_f32_16x16x32_bf16(a1, bf, acc[1][g], 0, 0, 0);
            }
        }
#pragma unroll
        for (int mi = 0; mi < 2; mi++) {
#pragma unroll
            for (int r = 0; r < 4; r++) {
                int b = mi * 16 + l4 * 4 + r;
                float gi = acc[mi][0][r];
                float gf = acc[mi][1][r];
                float gg = acc[mi][2][r];
                float go = acc[mi][3][r];
                float cell = cells[b * 512 + d];
                float c2 = sigf(gf) * cell + sigf(gi) * tanhf(gg);
                float h2 = sigf(go) * tanhf(c2);
                h0w[b * 512 + d] = f2bf(c2);    // faithful bug: carry = cell
                h20w[b * 512 + d] = f2bf(h2);
            }
        }
    } else {                                    // ======== stepB (t = k-1)
        if (k < 1) return;
        for (int i = tid; i < 2048; i += 256) {
            int b = i >> 6, k8 = i & 63;
            *(us8*)&xsA[b][k8 * 8] = *(const us8*)&h20r[b * 512 + k8 * 8];
            *(us8*)&xsB[b][k8 * 8] = *(const us8*)&h1r[b * 512 + k8 * 8];
        }
        __syncthreads();
        const int d16 = (blockIdx.x - 8) * 4 + w;   // 0..31
        const int d = d16 * 16 + l15;
        f32x4 acc[2][4];
#pragma unroll
        for (int mi = 0; mi < 2; mi++)
#pragma unroll
            for (int g = 0; g < 4; g++) acc[mi][g] = (f32x4){0.f, 0.f, 0.f, 0.f};
        for (int ks = 0; ks < 16; ks++) {
            bfrag a0 = *(const bfrag*)&xsA[l15][ks * 32 + l4 * 8];
            bfrag a1 = *(const bfrag*)&xsA[16 + l15][ks * 32 + l4 * 8];
#pragma unroll
            for (int g = 0; g < 4; g++) {
                int T = g * 32 + d16;
                bfrag bf = *(const bfrag*)&wih1p[(((size_t)T * 16 + ks) * 64 + lane) * 8];
                acc[0][g] = __builtin_amdgcn_mfma_f32_16x16x32_bf16(a0, bf, acc[0][g], 0, 0, 0);
                acc[1][g] = __builtin_amdgcn_mfma_f32_16x16x32_bf16(a1, bf, acc[1][g], 0, 0, 0);
            }
        }
        for (int ks = 0; ks < 16; ks++) {
            bfrag a0 = *(const bfrag*)&xsB[l15][ks * 32 + l4 * 8];
            bfrag a1 = *(const bfrag*)&xsB[16 + l15][ks * 32 + l4 * 8];
#pragma unroll
            for (int g = 0; g < 4; g++) {
                int T = g * 32 + d16;
                bfrag bf = *(const bfrag*)&whh1p[(((size_t)T * 16 + ks) * 64 + lane) * 8];
                acc[0][g] = __builtin_amdgcn_mfma_f32_16x16x32_bf16(a0, bf, acc[0][g], 0, 0, 0);
                acc[1][g] = __builtin_amdgcn_mfma_f32_16x16x32_bf16(a1, bf, acc[1][g], 0, 0, 0);
            }
        }
        float bb0 = bih1[0 * 512 + d] + bhh1[0 * 512 + d];
        float bb1v = bih1[1 * 512 + d] + bhh1[1 * 512 + d];
        float bb2 = bih1[2 * 512 + d] + bhh1[2 * 512 + d];
        float bb3 = bih1[3 * 512 + d] + bhh1[3 * 512 + d];
#pragma unroll
        for (int mi = 0; mi < 2; mi++) {
#pragma unroll
            for (int r = 0; r < 4; r++) {
                int b = mi * 16 + l4 * 4 + r;
                float gi = acc[mi][0][r] + bb0;
                float gf = acc[mi][1][r] + bb1v;
                float gg = acc[mi][2][r] + bb2;
                float go = acc[mi][3][r] + bb3;
                float cell = cells[16384 + b * 512 + d];
                float c2 = sigf(gf) * cell + sigf(gi) * tanhf(gg);
                float h2 = sigf(go) * tanhf(c2);
                h1w[b * 512 + d] = f2bf(c2);    // faithful bug
                H2[(size_t)(k - 1) * 16384 + b * 512 + d] = f2bf(h2);
            }
        }
    }
}

// ---------------------------------------------------------------------------
// XQ via MFMA: H2 bf16, pure-copy staging. grid (4 j-tiles, 64 t).
// ---------------------------------------------------------------------------
__global__ void __launch_bounds__(256) k_x_mfma(const u16* __restrict__ H2,
                                                const u16* __restrict__ Wpin,
                                                const float* __restrict__ bin,
                                                float* __restrict__ XQ) {
    const int tid = threadIdx.x;
    const int lane = tid & 63, w = tid >> 6;
    const int t = blockIdx.y;
    const int jw = blockIdx.x * 256 + w * 64;
    __shared__ u16 xs[32][520];
    for (int i = tid; i < 2048; i += 256) {
        int b = i >> 6, k8 = i & 63;
        *(us8*)&xs[b][k8 * 8] = *(const us8*)&H2[(size_t)t * 16384 + b * 512 + k8 * 8];
    }
    __syncthreads();
    const int l15 = lane & 15, l4 = lane >> 4;
    f32x4 acc[2][4];
#pragma unroll
    for (int mi = 0; mi < 2; mi++)
#pragma unroll
        for (int ni = 0; ni < 4; ni++) acc[mi][ni] = (f32x4){0.f, 0.f, 0.f, 0.f};
    for (int ks = 0; ks < 16; ks++) {
        bfrag a0 = *(const bfrag*)&xs[l15][ks * 32 + l4 * 8];
        bfrag a1 = *(const bfrag*)&xs[16 + l15][ks * 32 + l4 * 8];
#pragma unroll
        for (int ni = 0; ni < 4; ni++) {
            int j16 = (jw + ni * 16) >> 4;
            bfrag bf = *(const bfrag*)&Wpin[(((size_t)j16 * 16 + ks) * 64 + lane) * 8];
            acc[0][ni] = __builtin_amdgcn_mfma_f32_16x16x32_bf16(a0, bf, acc[0][ni], 0, 0, 0);
            acc[1][ni] = __builtin_amdgcn_mfma_f32_16x16x32_bf16(a1, bf, acc[1][ni], 0, 0, 0);
        }
    }
#pragma unroll
    for (int ni = 0; ni < 4; ni++) {
        int j = jw + ni * 16 + l15;
        float bv = bin[j];
#pragma unroll
        for (int mi = 0; mi < 2; mi++) {
#pragma unroll
            for (int r = 0; r < 4; r++) {
                int b = mi * 16 + l4 * 4 + r;
                XQ[((size_t)(t * 32 + b)) * 1024 + j] = acc[mi][ni][r] + bv;
            }
        }
    }
}

// ---------------------------------------------------------------------------
// out via MFMA: K=1536 in 3 chunks {CTX f32 x2, H2 bf16}. grid (2, 64).
// ---------------------------------------------------------------------------
__global__ void __launch_bounds__(256) k_out_mfma(const float* __restrict__ CTX,
                                                  const u16* __restrict__ H2,
                                                  const u16* __restrict__ Wpout,
                                                  const float* __restrict__ bout,
                                                  float* __restrict__ out) {
    const int tid = threadIdx.x;
    const int lane = tid & 63, w = tid >> 6;
    const int t = blockIdx.y;
    const int jw = blockIdx.x * 256 + w * 64;
    __shared__ u16 xs[32][520];
    const int l15 = lane & 15, l4 = lane >> 4;
    f32x4 acc[2][4];
#pragma unroll
    for (int mi = 0; mi < 2; mi++)
#pragma unroll
        for (int ni = 0; ni < 4; ni++) acc[mi][ni] = (f32x4){0.f, 0.f, 0.f, 0.f};
    for (int c = 0; c < 3; c++) {
        if (c) __syncthreads();                 // xs reuse guard
        if (c < 2) {
            for (int i = tid; i < 32 * 128; i += 256) {
                int b = i >> 7, k4 = i & 127;
                f4 v = *(const f4*)&CTX[((size_t)(t * 32 + b)) * 1024 + c * 512 + k4 * 4];
                u16* dst = &xs[b][k4 * 4];
                dst[0] = f2bf(v[0]); dst[1] = f2bf(v[1]); dst[2] = f2bf(v[2]); dst[3] = f2bf(v[3]);
            }
        } else {
            for (int i = tid; i < 2048; i += 256) {
                int b = i >> 6, k8 = i & 63;
                *(us8*)&xs[b][k8 * 8] = *(const us8*)&H2[(size_t)t * 16384 + b * 512 + k8 * 8];
            }
        }
        __syncthreads();
        for (int ks = 0; ks < 16; ks++) {
            bfrag a0 = *(const bfrag*)&xs[l15][ks * 32 + l4 * 8];
            bfrag a1 = *(const bfrag*)&xs[16 + l15][ks * 32 + l4 * 8];
#pragma unroll
            for (int ni = 0; ni < 4; ni++) {
                int j16 = (jw + ni * 16) >> 4;
                bfrag bf = *(const bfrag*)&Wpout[(((size_t)j16 * 48 + c * 16 + ks) * 64 + lane) * 8];
                acc[0][ni] = __builtin_amdgcn_mfma_f32_16x16x32_bf16(a0, bf, acc[0][ni], 0, 0, 0);
                acc[1][ni] = __builtin_amdgcn_mfma_f32_16x16x32_bf16(a1, bf, acc[1][ni], 0, 0, 0);
            }
        }
    }
#pragma unroll
    for (int ni = 0; ni < 4; ni++) {
        int j = jw + ni * 16 + l15;
        float bv = bout[j];
#pragma unroll
        for (int mi = 0; mi < 2; mi++) {
#pragma unroll
            for (int r = 0; r < 4; r++) {
                int b = mi * 16 + l4 * 4 + r;
                out[((size_t)(t * 32 + b)) * 512 + j] = tanhf(acc[mi][ni][r] + bv);
            }
        }
    }
}

// ---------------------------------------------------------------------------
// attention, FOUR time-steps per block (R21-proven, untouched).
// ---------------------------------------------------------------------------
__global__ void __launch_bounds__(256) k_att4(const float* __restrict__ XQ,
                                              const float* __restrict__ enc,
                                              const unsigned char* __restrict__ mask,
                                              const int* __restrict__ flag,
                                              float* __restrict__ CTX) {
    const int tid = threadIdx.x;
    const int b = blockIdx.x, t0 = blockIdx.y * 4;
    __shared__ float xq[4][1024];
    __shared__ float ered[4][256];
    __shared__ float attn[4][128];
    __shared__ float red2[4][8];
#pragma unroll
    for (int tg = 0; tg < 4; tg++) {
        f4 v = *(const f4*)&XQ[((size_t)((t0 + tg) * 32 + b)) * 1024 + tid * 4];
        float* dst = &xq[tg][tid * 4];
        dst[0] = v[0]; dst[1] = v[1]; dst[2] = v[2]; dst[3] = v[3];
    }
    __syncthreads();
    const int s = tid >> 1, hh = tid & 1;
    float p[4] = {0.f, 0.f, 0.f, 0.f};
    const float* erow = enc + ((size_t)(b * 128 + s)) * 1024 + hh * 512;
    for (int k4 = 0; k4 < 128; k4++) {
        f4 u = *(const f4*)&erow[k4 * 4];
#pragma unroll
        for (int kk = 0; kk < 4; kk++) {
#pragma unroll
            for (int tg = 0; tg < 4; tg++)
                p[tg] += u[kk] * xq[tg][hh * 512 + k4 * 4 + kk];
        }
    }
#pragma unroll
    for (int tg = 0; tg < 4; tg++) ered[tg][tid] = p[tg];
    __syncthreads();
    bool msk = false;
    if (tid < 128) {
        int f = *flag;
        if (f == 0)      msk = mask[b * 128 + tid] != 0;
        else if (f == 1) msk = ((const int*)mask)[b * 128 + tid] != 0;
        else if (f == 2) msk = ((const u16*)mask)[b * 128 + tid] != 0;
        else             msk = ((const unsigned int*)mask)[b * 128 + tid] != 0;
    }
    const int wave = tid >> 6;
    float e[4];
#pragma unroll
    for (int tg = 0; tg < 4; tg++) {
        e[tg] = -INFINITY;
        if (tid < 128) {
            e[tg] = ered[tg][2 * tid] + ered[tg][2 * tid + 1];
            if (msk) e[tg] = -1e9f;
        }
        float v = e[tg];
#pragma unroll
        for (int off = 32; off >= 1; off >>= 1) v = fmaxf(v, __shfl_xor(v, off));
        if ((tid & 63) == 0) red2[tg][wave] = v;
    }
    __syncthreads();
#pragma unroll
    for (int tg = 0; tg < 4; tg++) {
        float mx = fmaxf(fmaxf(red2[tg][0], red2[tg][1]), fmaxf(red2[tg][2], red2[tg][3]));
        float pp = (tid < 128) ? expf(e[tg] - mx) : 0.f;
        float su = pp;
#pragma unroll
        for (int off = 32; off >= 1; off >>= 1) su += __shfl_xor(su, off);
        if ((tid & 63) == 0) red2[tg][4 + wave] = su;
        __syncthreads();
        float S = (red2[tg][4] + red2[tg][5]) + (red2[tg][6] + red2[tg][7]);
        if (tid < 128) attn[tg][tid] = pp / S;
        __syncthreads();
    }
    float c0[4] = {0, 0, 0, 0}, c1[4] = {0, 0, 0, 0};
    float c2v[4] = {0, 0, 0, 0}, c3[4] = {0, 0, 0, 0};
    const float* eb = enc + ((size_t)b * 128) * 1024 + tid * 4;
    for (int s2 = 0; s2 < 128; s2++) {
        f4 u = *(const f4*)&eb[(size_t)s2 * 1024];
#pragma unroll
        for (int tg = 0; tg < 4; tg++) {
            float a = attn[tg][s2];
            c0[tg] += a * u[0]; c1[tg] += a * u[1]; c2v[tg] += a * u[2]; c3[tg] += a * u[3];
        }
    }
#pragma unroll
    for (int tg = 0; tg < 4; tg++) {
        float* crow = CTX + ((size_t)((t0 + tg) * 32 + b)) * 1024 + tid * 4;
        crow[0] = c0[tg]; crow[1] = c1[tg]; crow[2] = c2v[tg]; crow[3] = c3[tg];
    }
}

// ---------------------------------------------------------------------------
extern "C" void kernel_launch(void* const* d_in, const int* in_sizes, int n_in,
                              void* d_out, int out_size, void* d_ws, size_t ws_size,
                              hipStream_t stream) {
    const int* tokens   = (const int*)d_in[0];
    const float* enc    = (const float*)d_in[1];
    const float* hidden = (const float*)d_in[2];
    const float* cells  = (const float*)d_in[3];
    const unsigned char* mask = (const unsigned char*)d_in[4];
    const float* embed  = (const float*)d_in[5];
    const float* W_ih   = (const float*)d_in[6];
    const float* W_hh   = (const float*)d_in[7];
    const float* b_ih   = (const float*)d_in[8];
    const float* b_hh   = (const float*)d_in[9];
    const float* W_in   = (const float*)d_in[10];
    const float* b_in   = (const float*)d_in[11];
    const float* W_out  = (const float*)d_in[12];
    const float* b_out  = (const float*)d_in[13];
    float* out = (float*)d_out;

    float* ws = (float*)d_ws;
    // Phase-time layout (f-slot offsets):
    float* gih0p = ws;                             // [0, 4194304) — dead after phases
    u16*   h0s  = (u16*)(ws + 4194304);            // 2x16384 u16 -> 16384 f
    u16*   h20s = (u16*)(ws + 4210688);            // 16384 f
    u16*   h1s  = (u16*)(ws + 4227072);            // 16384 f
    u16*   H2   = (u16*)(ws + 4243456);            // 64x16384 u16 = 524288 f
    u16*   php  = (u16*)(ws + 4767744);            // 3x1048576 u16 = 1572864 f
    u16*   whh0p = php;
    u16*   wih1p = php + 1048576;
    u16*   whh1p = php + 2097152;
    u16*   wpin  = (u16*)(ws + 6340608);           // 524288 u16 = 262144 f
    u16*   wpout = (u16*)(ws + 6602752);           // 786432 u16 = 393216 f
    u16*   wih0p = (u16*)(ws + 6995968);           // 1048576 u16 = 524288 f
    int*   flag  = (int*)(ws + 7520256);
    // Tail-time layout (gih0p region reused):
    float* XQ   = ws;                              // [0, 2097152)
    float* CTX  = ws + 2097152;                    // [2097152, 4194304)

    const float* bih1 = b_ih + G4_;
    const float* bhh1 = b_hh + G4_;

    k_flag<<<1, 256, 0, stream>>>(mask, flag);
    k_init2<<<64, 256, 0, stream>>>(hidden, h0s, h1s);
    k_packIn<<<256, 256, 0, stream>>>(W_in, wpin);
    k_packOut<<<384, 256, 0, stream>>>(W_out, wpout);
    k_packA<<<512, 256, 0, stream>>>(W_ih, wih0p);
    k_packPh<<<1536, 256, 0, stream>>>(W_ih, W_hh, php);
    k_gih0_mfma<<<dim3(8, 64), 256, 0, stream>>>(tokens, embed, wih0p, b_ih, b_hh, gih0p);

    for (int k = 0; k <= 64; k++) {
        const int r = k & 1, w = r ^ 1;
        k_phaseM<<<16, 256, 0, stream>>>(k, gih0p, whh0p, wih1p, whh1p, bih1, bhh1, cells,
                                         h0s + r * 16384, h0s + w * 16384,
                                         h20s + r * 16384, h20s + w * 16384,
                                         h1s + r * 16384, h1s + w * 16384, H2);
    }

    k_x_mfma<<<dim3(4, 64), 256, 0, stream>>>(H2, wpin, b_in, XQ);
    k_att4<<<dim3(32, 16), 256, 0, stream>>>(XQ, enc, mask, flag, CTX);
    k_out_mfma<<<dim3(2, 64), 256, 0, stream>>>(CTX, H2, wpout, b_out, out);
}

// Round 23
// 676.397 us; speedup vs baseline: 2.4944x; 1.3841x over previous
//
#include <hip/hip_runtime.h>
#include <math.h>

typedef unsigned short u16;
typedef __attribute__((ext_vector_type(4))) float f4;
typedef __attribute__((ext_vector_type(8))) unsigned short us8;
typedef __attribute__((ext_vector_type(8))) short bfrag;
typedef __attribute__((ext_vector_type(4))) float f32x4;

#define BB 32
#define TT 64
#define DD 512
#define G4_ 2048

__device__ __forceinline__ float sigf(float x) { return 1.0f / (1.0f + expf(-x)); }
__device__ __forceinline__ float bf2f(u16 u) {
    union { unsigned int i; float f; } v; v.i = ((unsigned int)u) << 16; return v.f;
}
__device__ __forceinline__ u16 f2bf(float f) {
    union { float f; unsigned int i; } v; v.f = f;
    unsigned int r = v.i + 0x7fffu + ((v.i >> 16) & 1u);
    return (u16)(r >> 16);
}

// ---------------------------------------------------------------------------
// mask dtype classifier: 0=u8(bool), 1=i32, 2=bf16, 3=f32. Deterministic.
// ---------------------------------------------------------------------------
__global__ void k_flag(const unsigned char* __restrict__ m, int* __restrict__ flag) {
    int tid = threadIdx.x;
    int badbyte = 0, nonz_off = 0, evenu16_nz = 0;
    for (int i = tid * 16; i < tid * 16 + 16; i++) {
        unsigned char c = m[i];
        if (c > 1) badbyte = 1;
        if ((i & 3) != 0 && c != 0) nonz_off = 1;
    }
    const u16* mu = (const u16*)m;
    for (int i = tid * 8; i < tid * 8 + 8; i++) {
        if ((i & 1) == 0 && mu[i] != 0) evenu16_nz = 1;
    }
    __shared__ int s_bad, s_noff, s_env;
    if (tid == 0) { s_bad = 0; s_noff = 0; s_env = 0; }
    __syncthreads();
    if (badbyte) atomicOr(&s_bad, 1);
    if (nonz_off) atomicOr(&s_noff, 1);
    if (evenu16_nz) atomicOr(&s_env, 1);
    __syncthreads();
    if (tid == 0) {
        int f;
        if (s_bad) f = s_env ? 2 : 3;
        else       f = s_noff ? 0 : 1;
        *flag = f;
    }
}

// ---------------------------------------------------------------------------
// init: h-states to bf16 parity buffers.
// ---------------------------------------------------------------------------
__global__ void __launch_bounds__(256) k_init2(const float* __restrict__ hid,
                                               u16* __restrict__ h0s,
                                               u16* __restrict__ h1s) {
    int i = blockIdx.x * 256 + threadIdx.x;   // 0 .. 16383
    u16 v0 = f2bf(hid[i]), v1 = f2bf(hid[16384 + i]);
    h0s[i] = v0; h0s[16384 + i] = v0;
    h1s[i] = v1; h1s[16384 + i] = v1;
}

// ---------------------------------------------------------------------------
// pack W_in into MFMA B-fragment order (1024 rows x K 512). grid 256 x 256.
// ---------------------------------------------------------------------------
__global__ void __launch_bounds__(256) k_packIn(const float* __restrict__ Win,
                                                u16* __restrict__ Wp) {
    int g = blockIdx.x * 256 + threadIdx.x;   // 0 .. 65535
    int lane = g & 63, grp = g >> 6;
    int j16 = grp >> 4, ks = grp & 15;
    const float* src = &Win[((size_t)(j16 * 16 + (lane & 15))) * 512 + ks * 32 + (lane >> 4) * 8];
    u16* dst = &Wp[(size_t)g * 8];
    f4 v0 = *(const f4*)&src[0];
    f4 v1 = *(const f4*)&src[4];
    dst[0] = f2bf(v0[0]); dst[1] = f2bf(v0[1]); dst[2] = f2bf(v0[2]); dst[3] = f2bf(v0[3]);
    dst[4] = f2bf(v1[0]); dst[5] = f2bf(v1[1]); dst[6] = f2bf(v1[2]); dst[7] = f2bf(v1[3]);
}

// ---------------------------------------------------------------------------
// pack W_out into MFMA B-fragment order (512 rows x K 1536). grid 384 x 256.
// ---------------------------------------------------------------------------
__global__ void __launch_bounds__(256) k_packOut(const float* __restrict__ Wout,
                                                 u16* __restrict__ Wp) {
    int g = blockIdx.x * 256 + threadIdx.x;   // 0 .. 98303
    int lane = g & 63, grp = g >> 6;          // grp 0..1535
    int j16 = grp / 48, ks = grp % 48;
    const float* src = &Wout[((size_t)(j16 * 16 + (lane & 15))) * 1536 + ks * 32 + (lane >> 4) * 8];
    u16* dst = &Wp[(size_t)g * 8];
    f4 v0 = *(const f4*)&src[0];
    f4 v1 = *(const f4*)&src[4];
    dst[0] = f2bf(v0[0]); dst[1] = f2bf(v0[1]); dst[2] = f2bf(v0[2]); dst[3] = f2bf(v0[3]);
    dst[4] = f2bf(v1[0]); dst[5] = f2bf(v1[1]); dst[6] = f2bf(v1[2]); dst[7] = f2bf(v1[3]);
}

// ---------------------------------------------------------------------------
// pack W_ih0 into MFMA B-fragment order (R14-proven). grid 512 x 256.
// ---------------------------------------------------------------------------
__global__ void __launch_bounds__(256) k_packA(const float* __restrict__ Wih0,
                                               u16* __restrict__ Wp) {
    int g = blockIdx.x * 256 + threadIdx.x;   // 0 .. 131071
    int lane = g & 63, grp = g >> 6;
    int j16 = grp >> 4, ks = grp & 15;
    const float* src = &Wih0[((size_t)(j16 * 16 + (lane & 15))) * 512 + ks * 32 + (lane >> 4) * 8];
    u16* dst = &Wp[(size_t)g * 8];
    f4 v0 = *(const f4*)&src[0];
    f4 v1 = *(const f4*)&src[4];
    dst[0] = f2bf(v0[0]); dst[1] = f2bf(v0[1]); dst[2] = f2bf(v0[2]); dst[3] = f2bf(v0[3]);
    dst[4] = f2bf(v1[0]); dst[5] = f2bf(v1[1]); dst[6] = f2bf(v1[2]); dst[7] = f2bf(v1[3]);
}

// ---------------------------------------------------------------------------
// pack {Whh0, Wih1, Whh1} into MFMA B-fragment order, gate-strided tiles
// (R19-proven). grid 1536 x 256.
// ---------------------------------------------------------------------------
__global__ void __launch_bounds__(256) k_packPh(const float* __restrict__ Wih,
                                                const float* __restrict__ Whh,
                                                u16* __restrict__ php) {
    int gidx = blockIdx.x * 256 + threadIdx.x;   // 0 .. 393215
    int m = gidx >> 17;                           // 0..2
    int rem = gidx & 131071;
    int lane = rem & 63;
    int q = rem >> 6;                             // 0..2047
    int ks = q & 15, T = q >> 4;                  // T 0..127
    int g = T >> 5, d16 = T & 31;
    int j = g * 512 + d16 * 16 + (lane & 15);
    int kcol = ks * 32 + (lane >> 4) * 8;
    const float* src = (m == 0) ? Whh
                     : (m == 1) ? (Wih + 1048576)
                                : (Whh + 1048576);
    const float* sp = &src[(size_t)j * 512 + kcol];
    u16* dst = &php[((size_t)m << 20) + (size_t)rem * 8];
    f4 v0 = *(const f4*)&sp[0];
    f4 v1 = *(const f4*)&sp[4];
    dst[0] = f2bf(v0[0]); dst[1] = f2bf(v0[1]); dst[2] = f2bf(v0[2]); dst[3] = f2bf(v0[3]);
    dst[4] = f2bf(v1[0]); dst[5] = f2bf(v1[1]); dst[6] = f2bf(v1[2]); dst[7] = f2bf(v1[3]);
}

// ---------------------------------------------------------------------------
// gih0 via MFMA, output in accumulator-fragment layout (R22-proven).
// ---------------------------------------------------------------------------
__global__ void __launch_bounds__(256) k_gih0_mfma(const int* __restrict__ tokens,
                                                   const float* __restrict__ embed,
                                                   const u16* __restrict__ Wp,
                                                   const float* __restrict__ bih,
                                                   const float* __restrict__ bhh,
                                                   float* __restrict__ gih0p) {
    const int tid = threadIdx.x;
    const int lane = tid & 63, w = tid >> 6;
    const int t = blockIdx.y;
    const int jw = blockIdx.x * 256 + w * 64;
    __shared__ u16 xs[32][520];
    __shared__ int toks[32];
    if (tid < 32) toks[tid] = tokens[tid * TT + t];
    __syncthreads();
    for (int i = tid; i < 32 * 128; i += 256) {
        int b = i >> 7, k4 = i & 127;
        f4 v = *(const f4*)&embed[(size_t)toks[b] * 512 + k4 * 4];
        u16* dst = &xs[b][k4 * 4];
        dst[0] = f2bf(v[0]); dst[1] = f2bf(v[1]); dst[2] = f2bf(v[2]); dst[3] = f2bf(v[3]);
    }
    __syncthreads();

    const int l15 = lane & 15, l4 = lane >> 4;
    f32x4 acc[2][4];
#pragma unroll
    for (int mi = 0; mi < 2; mi++)
#pragma unroll
        for (int ni = 0; ni < 4; ni++) acc[mi][ni] = (f32x4){0.f, 0.f, 0.f, 0.f};

    for (int ks = 0; ks < 16; ks++) {
        bfrag a0 = *(const bfrag*)&xs[l15][ks * 32 + l4 * 8];
        bfrag a1 = *(const bfrag*)&xs[16 + l15][ks * 32 + l4 * 8];
#pragma unroll
        for (int ni = 0; ni < 4; ni++) {
            int j16 = (jw + ni * 16) >> 4;
            bfrag bf = *(const bfrag*)&Wp[(((size_t)j16 * 16 + ks) * 64 + lane) * 8];
            acc[0][ni] = __builtin_amdgcn_mfma_f32_16x16x32_bf16(a0, bf, acc[0][ni], 0, 0, 0);
            acc[1][ni] = __builtin_amdgcn_mfma_f32_16x16x32_bf16(a1, bf, acc[1][ni], 0, 0, 0);
        }
    }

#pragma unroll
    for (int ni = 0; ni < 4; ni++) {
        int j16 = (jw >> 4) + ni;
        int g = j16 >> 5, d16 = j16 & 31;
        int j = j16 * 16 + l15;
        float bv = bih[j] + bhh[j];
#pragma unroll
        for (int mi = 0; mi < 2; mi++) {
            f32x4 sv = acc[mi][ni];
            sv[0] += bv; sv[1] += bv; sv[2] += bv; sv[3] += bv;
            *(f32x4*)&gih0p[(((((size_t)t * 32 + d16) * 4 + g) * 2 + mi) * 64 + lane) * 4] = sv;
        }
    }
}

// ---------------------------------------------------------------------------
// MFMA phase kernel, 32 blocks x 256 thr: wave = (d16, mi) split — 2x the CUs
// of R22 for the same total wave count (2x aggregate L2 weight BW + pipes).
//  blocks  0..15: stepA(t=k)   wid = blk*4+w in [0,64): d16 = wid>>1, mi = wid&1
//  blocks 16..31: stepB(t=k-1) same mapping.
// Per-output arithmetic identical to R22 (same C-init, same k-order) -> bit-exact.
// ---------------------------------------------------------------------------
__global__ void __launch_bounds__(256) k_phaseM(
    const int k,
    const float* __restrict__ gih0p,
    const u16* __restrict__ whh0p,
    const u16* __restrict__ wih1p,
    const u16* __restrict__ whh1p,
    const float* __restrict__ bih1,
    const float* __restrict__ bhh1,
    const float* __restrict__ cells,
    const u16* __restrict__ h0r, u16* __restrict__ h0w,
    const u16* __restrict__ h20r, u16* __restrict__ h20w,
    const u16* __restrict__ h1r, u16* __restrict__ h1w,
    u16* __restrict__ H2)
{
    const int tid = threadIdx.x;
    const int lane = tid & 63, w = tid >> 6;
    const int l15 = lane & 15, l4 = lane >> 4;
    __shared__ u16 xsA[32][520];
    __shared__ u16 xsB[32][520];

    if (blockIdx.x < 16) {                      // ======== stepA (t = k)
        if (k >= 64) return;
        const int wid = blockIdx.x * 4 + w;     // 0..63
        const int d16 = wid >> 1, mi = wid & 1;
        const int d = d16 * 16 + l15;
        f32x4 acc[4];
#pragma unroll
        for (int g = 0; g < 4; g++)
            acc[g] = *(const f32x4*)&gih0p[(((((size_t)k * 32 + d16) * 4 + g) * 2 + mi) * 64 + lane) * 4];
        for (int i = tid; i < 2048; i += 256) { // 32 rows x 512 u16 / 8-wide
            int b = i >> 6, k8 = i & 63;
            *(us8*)&xsA[b][k8 * 8] = *(const us8*)&h0r[b * 512 + k8 * 8];
        }
        __syncthreads();
        const int arow = mi * 16 + l15;
        for (int ks = 0; ks < 16; ks++) {
            bfrag a = *(const bfrag*)&xsA[arow][ks * 32 + l4 * 8];
#pragma unroll
            for (int g = 0; g < 4; g++) {
                int T = g * 32 + d16;
                bfrag bf = *(const bfrag*)&whh0p[(((size_t)T * 16 + ks) * 64 + lane) * 8];
                acc[g] = __builtin_amdgcn_mfma_f32_16x16x32_bf16(a, bf, acc[g], 0, 0, 0);
            }
        }
#pragma unroll
        for (int r = 0; r < 4; r++) {
            int b = mi * 16 + l4 * 4 + r;
            float gi = acc[0][r];
            float gf = acc[1][r];
            float gg = acc[2][r];
            float go = acc[3][r];
            float cell = cells[b * 512 + d];
            float c2 = sigf(gf) * cell + sigf(gi) * tanhf(gg);
            float h2 = sigf(go) * tanhf(c2);
            h0w[b * 512 + d] = f2bf(c2);        // faithful bug: carry = cell
            h20w[b * 512 + d] = f2bf(h2);
        }
    } else {                                    // ======== stepB (t = k-1)
        if (k < 1) return;
        for (int i = tid; i < 2048; i += 256) {
            int b = i >> 6, k8 = i & 63;
            *(us8*)&xsA[b][k8 * 8] = *(const us8*)&h20r[b * 512 + k8 * 8];
            *(us8*)&xsB[b][k8 * 8] = *(const us8*)&h1r[b * 512 + k8 * 8];
        }
        __syncthreads();
        const int wid = (blockIdx.x - 16) * 4 + w;  // 0..63
        const int d16 = wid >> 1, mi = wid & 1;
        const int d = d16 * 16 + l15;
        const int arow = mi * 16 + l15;
        f32x4 acc[4];
#pragma unroll
        for (int g = 0; g < 4; g++) acc[g] = (f32x4){0.f, 0.f, 0.f, 0.f};
        for (int ks = 0; ks < 16; ks++) {
            bfrag a = *(const bfrag*)&xsA[arow][ks * 32 + l4 * 8];
#pragma unroll
            for (int g = 0; g < 4; g++) {
                int T = g * 32 + d16;
                bfrag bf = *(const bfrag*)&wih1p[(((size_t)T * 16 + ks) * 64 + lane) * 8];
                acc[g] = __builtin_amdgcn_mfma_f32_16x16x32_bf16(a, bf, acc[g], 0, 0, 0);
            }
        }
        for (int ks = 0; ks < 16; ks++) {
            bfrag a = *(const bfrag*)&xsB[arow][ks * 32 + l4 * 8];
#pragma unroll
            for (int g = 0; g < 4; g++) {
                int T = g * 32 + d16;
                bfrag bf = *(const bfrag*)&whh1p[(((size_t)T * 16 + ks) * 64 + lane) * 8];
                acc[g] = __builtin_amdgcn_mfma_f32_16x16x32_bf16(a, bf, acc[g], 0, 0, 0);
            }
        }
        float bb0 = bih1[0 * 512 + d] + bhh1[0 * 512 + d];
        float bb1v = bih1[1 * 512 + d] + bhh1[1 * 512 + d];
        float bb2 = bih1[2 * 512 + d] + bhh1[2 * 512 + d];
        float bb3 = bih1[3 * 512 + d] + bhh1[3 * 512 + d];
#pragma unroll
        for (int r = 0; r < 4; r++) {
            int b = mi * 16 + l4 * 4 + r;
            float gi = acc[0][r] + bb0;
            float gf = acc[1][r] + bb1v;
            float gg = acc[2][r] + bb2;
            float go = acc[3][r] + bb3;
            float cell = cells[16384 + b * 512 + d];
            float c2 = sigf(gf) * cell + sigf(gi) * tanhf(gg);
            float h2 = sigf(go) * tanhf(c2);
            h1w[b * 512 + d] = f2bf(c2);        // faithful bug
            H2[(size_t)(k - 1) * 16384 + b * 512 + d] = f2bf(h2);
        }
    }
}

// ---------------------------------------------------------------------------
// XQ via MFMA: H2 bf16, pure-copy staging. grid (4 j-tiles, 64 t).
// ---------------------------------------------------------------------------
__global__ void __launch_bounds__(256) k_x_mfma(const u16* __restrict__ H2,
                                                const u16* __restrict__ Wpin,
                                                const float* __restrict__ bin,
                                                float* __restrict__ XQ) {
    const int tid = threadIdx.x;
    const int lane = tid & 63, w = tid >> 6;
    const int t = blockIdx.y;
    const int jw = blockIdx.x * 256 + w * 64;
    __shared__ u16 xs[32][520];
    for (int i = tid; i < 2048; i += 256) {
        int b = i >> 6, k8 = i & 63;
        *(us8*)&xs[b][k8 * 8] = *(const us8*)&H2[(size_t)t * 16384 + b * 512 + k8 * 8];
    }
    __syncthreads();
    const int l15 = lane & 15, l4 = lane >> 4;
    f32x4 acc[2][4];
#pragma unroll
    for (int mi = 0; mi < 2; mi++)
#pragma unroll
        for (int ni = 0; ni < 4; ni++) acc[mi][ni] = (f32x4){0.f, 0.f, 0.f, 0.f};
    for (int ks = 0; ks < 16; ks++) {
        bfrag a0 = *(const bfrag*)&xs[l15][ks * 32 + l4 * 8];
        bfrag a1 = *(const bfrag*)&xs[16 + l15][ks * 32 + l4 * 8];
#pragma unroll
        for (int ni = 0; ni < 4; ni++) {
            int j16 = (jw + ni * 16) >> 4;
            bfrag bf = *(const bfrag*)&Wpin[(((size_t)j16 * 16 + ks) * 64 + lane) * 8];
            acc[0][ni] = __builtin_amdgcn_mfma_f32_16x16x32_bf16(a0, bf, acc[0][ni], 0, 0, 0);
            acc[1][ni] = __builtin_amdgcn_mfma_f32_16x16x32_bf16(a1, bf, acc[1][ni], 0, 0, 0);
        }
    }
#pragma unroll
    for (int ni = 0; ni < 4; ni++) {
        int j = jw + ni * 16 + l15;
        float bv = bin[j];
#pragma unroll
        for (int mi = 0; mi < 2; mi++) {
#pragma unroll
            for (int r = 0; r < 4; r++) {
                int b = mi * 16 + l4 * 4 + r;
                XQ[((size_t)(t * 32 + b)) * 1024 + j] = acc[mi][ni][r] + bv;
            }
        }
    }
}

// ---------------------------------------------------------------------------
// out via MFMA: K=1536 in 3 chunks {CTX f32 x2, H2 bf16}. grid (2, 64).
// ---------------------------------------------------------------------------
__global__ void __launch_bounds__(256) k_out_mfma(const float* __restrict__ CTX,
                                                  const u16* __restrict__ H2,
                                                  const u16* __restrict__ Wpout,
                                                  const float* __restrict__ bout,
                                                  float* __restrict__ out) {
    const int tid = threadIdx.x;
    const int lane = tid & 63, w = tid >> 6;
    const int t = blockIdx.y;
    const int jw = blockIdx.x * 256 + w * 64;
    __shared__ u16 xs[32][520];
    const int l15 = lane & 15, l4 = lane >> 4;
    f32x4 acc[2][4];
#pragma unroll
    for (int mi = 0; mi < 2; mi++)
#pragma unroll
        for (int ni = 0; ni < 4; ni++) acc[mi][ni] = (f32x4){0.f, 0.f, 0.f, 0.f};
    for (int c = 0; c < 3; c++) {
        if (c) __syncthreads();                 // xs reuse guard
        if (c < 2) {
            for (int i = tid; i < 32 * 128; i += 256) {
                int b = i >> 7, k4 = i & 127;
                f4 v = *(const f4*)&CTX[((size_t)(t * 32 + b)) * 1024 + c * 512 + k4 * 4];
                u16* dst = &xs[b][k4 * 4];
                dst[0] = f2bf(v[0]); dst[1] = f2bf(v[1]); dst[2] = f2bf(v[2]); dst[3] = f2bf(v[3]);
            }
        } else {
            for (int i = tid; i < 2048; i += 256) {
                int b = i >> 6, k8 = i & 63;
                *(us8*)&xs[b][k8 * 8] = *(const us8*)&H2[(size_t)t * 16384 + b * 512 + k8 * 8];
            }
        }
        __syncthreads();
        for (int ks = 0; ks < 16; ks++) {
            bfrag a0 = *(const bfrag*)&xs[l15][ks * 32 + l4 * 8];
            bfrag a1 = *(const bfrag*)&xs[16 + l15][ks * 32 + l4 * 8];
#pragma unroll
            for (int ni = 0; ni < 4; ni++) {
                int j16 = (jw + ni * 16) >> 4;
                bfrag bf = *(const bfrag*)&Wpout[(((size_t)j16 * 48 + c * 16 + ks) * 64 + lane) * 8];
                acc[0][ni] = __builtin_amdgcn_mfma_f32_16x16x32_bf16(a0, bf, acc[0][ni], 0, 0, 0);
                acc[1][ni] = __builtin_amdgcn_mfma_f32_16x16x32_bf16(a1, bf, acc[1][ni], 0, 0, 0);
            }
        }
    }
#pragma unroll
    for (int ni = 0; ni < 4; ni++) {
        int j = jw + ni * 16 + l15;
        float bv = bout[j];
#pragma unroll
        for (int mi = 0; mi < 2; mi++) {
#pragma unroll
            for (int r = 0; r < 4; r++) {
                int b = mi * 16 + l4 * 4 + r;
                out[((size_t)(t * 32 + b)) * 512 + j] = tanhf(acc[mi][ni][r] + bv);
            }
        }
    }
}

// ---------------------------------------------------------------------------
// attention, FOUR time-steps per block (R21-proven, untouched).
// ---------------------------------------------------------------------------
__global__ void __launch_bounds__(256) k_att4(const float* __restrict__ XQ,
                                              const float* __restrict__ enc,
                                              const unsigned char* __restrict__ mask,
                                              const int* __restrict__ flag,
                                              float* __restrict__ CTX) {
    const int tid = threadIdx.x;
    const int b = blockIdx.x, t0 = blockIdx.y * 4;
    __shared__ float xq[4][1024];
    __shared__ float ered[4][256];
    __shared__ float attn[4][128];
    __shared__ float red2[4][8];
#pragma unroll
    for (int tg = 0; tg < 4; tg++) {
        f4 v = *(const f4*)&XQ[((size_t)((t0 + tg) * 32 + b)) * 1024 + tid * 4];
        float* dst = &xq[tg][tid * 4];
        dst[0] = v[0]; dst[1] = v[1]; dst[2] = v[2]; dst[3] = v[3];
    }
    __syncthreads();
    const int s = tid >> 1, hh = tid & 1;
    float p[4] = {0.f, 0.f, 0.f, 0.f};
    const float* erow = enc + ((size_t)(b * 128 + s)) * 1024 + hh * 512;
    for (int k4 = 0; k4 < 128; k4++) {
        f4 u = *(const f4*)&erow[k4 * 4];
#pragma unroll
        for (int kk = 0; kk < 4; kk++) {
#pragma unroll
            for (int tg = 0; tg < 4; tg++)
                p[tg] += u[kk] * xq[tg][hh * 512 + k4 * 4 + kk];
        }
    }
#pragma unroll
    for (int tg = 0; tg < 4; tg++) ered[tg][tid] = p[tg];
    __syncthreads();
    bool msk = false;
    if (tid < 128) {
        int f = *flag;
        if (f == 0)      msk = mask[b * 128 + tid] != 0;
        else if (f == 1) msk = ((const int*)mask)[b * 128 + tid] != 0;
        else if (f == 2) msk = ((const u16*)mask)[b * 128 + tid] != 0;
        else             msk = ((const unsigned int*)mask)[b * 128 + tid] != 0;
    }
    const int wave = tid >> 6;
    float e[4];
#pragma unroll
    for (int tg = 0; tg < 4; tg++) {
        e[tg] = -INFINITY;
        if (tid < 128) {
            e[tg] = ered[tg][2 * tid] + ered[tg][2 * tid + 1];
            if (msk) e[tg] = -1e9f;
        }
        float v = e[tg];
#pragma unroll
        for (int off = 32; off >= 1; off >>= 1) v = fmaxf(v, __shfl_xor(v, off));
        if ((tid & 63) == 0) red2[tg][wave] = v;
    }
    __syncthreads();
#pragma unroll
    for (int tg = 0; tg < 4; tg++) {
        float mx = fmaxf(fmaxf(red2[tg][0], red2[tg][1]), fmaxf(red2[tg][2], red2[tg][3]));
        float pp = (tid < 128) ? expf(e[tg] - mx) : 0.f;
        float su = pp;
#pragma unroll
        for (int off = 32; off >= 1; off >>= 1) su += __shfl_xor(su, off);
        if ((tid & 63) == 0) red2[tg][4 + wave] = su;
        __syncthreads();
        float S = (red2[tg][4] + red2[tg][5]) + (red2[tg][6] + red2[tg][7]);
        if (tid < 128) attn[tg][tid] = pp / S;
        __syncthreads();
    }
    float c0[4] = {0, 0, 0, 0}, c1[4] = {0, 0, 0, 0};
    float c2v[4] = {0, 0, 0, 0}, c3[4] = {0, 0, 0, 0};
    const float* eb = enc + ((size_t)b * 128) * 1024 + tid * 4;
    for (int s2 = 0; s2 < 128; s2++) {
        f4 u = *(const f4*)&eb[(size_t)s2 * 1024];
#pragma unroll
        for (int tg = 0; tg < 4; tg++) {
            float a = attn[tg][s2];
            c0[tg] += a * u[0]; c1[tg] += a * u[1]; c2v[tg] += a * u[2]; c3[tg] += a * u[3];
        }
    }
#pragma unroll
    for (int tg = 0; tg < 4; tg++) {
        float* crow = CTX + ((size_t)((t0 + tg) * 32 + b)) * 1024 + tid * 4;
        crow[0] = c0[tg]; crow[1] = c1[tg]; crow[2] = c2v[tg]; crow[3] = c3[tg];
    }
}

// ---------------------------------------------------------------------------
extern "C" void kernel_launch(void* const* d_in, const int* in_sizes, int n_in,
                              void* d_out, int out_size, void* d_ws, size_t ws_size,
                              hipStream_t stream) {
    const int* tokens   = (const int*)d_in[0];
    const float* enc    = (const float*)d_in[1];
    const float* hidden = (const float*)d_in[2];
    const float* cells  = (const float*)d_in[3];
    const unsigned char* mask = (const unsigned char*)d_in[4];
    const float* embed  = (const float*)d_in[5];
    const float* W_ih   = (const float*)d_in[6];
    const float* W_hh   = (const float*)d_in[7];
    const float* b_ih   = (const float*)d_in[8];
    const float* b_hh   = (const float*)d_in[9];
    const float* W_in   = (const float*)d_in[10];
    const float* b_in   = (const float*)d_in[11];
    const float* W_out  = (const float*)d_in[12];
    const float* b_out  = (const float*)d_in[13];
    float* out = (float*)d_out;

    float* ws = (float*)d_ws;
    // Phase-time layout (f-slot offsets):
    float* gih0p = ws;                             // [0, 4194304) — dead after phases
    u16*   h0s  = (u16*)(ws + 4194304);            // 2x16384 u16 -> 16384 f
    u16*   h20s = (u16*)(ws + 4210688);            // 16384 f
    u16*   h1s  = (u16*)(ws + 4227072);            // 16384 f
    u16*   H2   = (u16*)(ws + 4243456);            // 64x16384 u16 = 524288 f
    u16*   php  = (u16*)(ws + 4767744);            // 3x1048576 u16 = 1572864 f
    u16*   whh0p = php;
    u16*   wih1p = php + 1048576;
    u16*   whh1p = php + 2097152;
    u16*   wpin  = (u16*)(ws + 6340608);           // 524288 u16 = 262144 f
    u16*   wpout = (u16*)(ws + 6602752);           // 786432 u16 = 393216 f
    u16*   wih0p = (u16*)(ws + 6995968);           // 1048576 u16 = 524288 f
    int*   flag  = (int*)(ws + 7520256);
    // Tail-time layout (gih0p region reused):
    float* XQ   = ws;                              // [0, 2097152)
    float* CTX  = ws + 2097152;                    // [2097152, 4194304)

    const float* bih1 = b_ih + G4_;
    const float* bhh1 = b_hh + G4_;

    k_flag<<<1, 256, 0, stream>>>(mask, flag);
    k_init2<<<64, 256, 0, stream>>>(hidden, h0s, h1s);
    k_packIn<<<256, 256, 0, stream>>>(W_in, wpin);
    k_packOut<<<384, 256, 0, stream>>>(W_out, wpout);
    k_packA<<<512, 256, 0, stream>>>(W_ih, wih0p);
    k_packPh<<<1536, 256, 0, stream>>>(W_ih, W_hh, php);
    k_gih0_mfma<<<dim3(8, 64), 256, 0, stream>>>(tokens, embed, wih0p, b_ih, b_hh, gih0p);

    for (int k = 0; k <= 64; k++) {
        const int r = k & 1, w = r ^ 1;
        k_phaseM<<<32, 256, 0, stream>>>(k, gih0p, whh0p, wih1p, whh1p, bih1, bhh1, cells,
                                         h0s + r * 16384, h0s + w * 16384,
                                         h20s + r * 16384, h20s + w * 16384,
                                         h1s + r * 16384, h1s + w * 16384, H2);
    }

    k_x_mfma<<<dim3(4, 64), 256, 0, stream>>>(H2, wpin, b_in, XQ);
    k_att4<<<dim3(32, 16), 256, 0, stream>>>(XQ, enc, mask, flag, CTX);
    k_out_mfma<<<dim3(2, 64), 256, 0, stream>>>(CTX, H2, wpout, b_out, out);
}

// Round 24
// 608.509 us; speedup vs baseline: 2.7727x; 1.1116x over previous
//
#include <hip/hip_runtime.h>
#include <math.h>

typedef unsigned short u16;
typedef __attribute__((ext_vector_type(4))) float f4;
typedef __attribute__((ext_vector_type(8))) unsigned short us8;
typedef __attribute__((ext_vector_type(8))) short bfrag;
typedef __attribute__((ext_vector_type(4))) float f32x4;

#define BB 32
#define TT 64
#define DD 512
#define G4_ 2048

__device__ __forceinline__ float sigf(float x) { return 1.0f / (1.0f + expf(-x)); }
__device__ __forceinline__ float bf2f(u16 u) {
    union { unsigned int i; float f; } v; v.i = ((unsigned int)u) << 16; return v.f;
}
__device__ __forceinline__ u16 f2bf(float f) {
    union { float f; unsigned int i; } v; v.f = f;
    unsigned int r = v.i + 0x7fffu + ((v.i >> 16) & 1u);
    return (u16)(r >> 16);
}

// ---------------------------------------------------------------------------
// mask dtype classifier: 0=u8(bool), 1=i32, 2=bf16, 3=f32. Deterministic.
// ---------------------------------------------------------------------------
__global__ void k_flag(const unsigned char* __restrict__ m, int* __restrict__ flag) {
    int tid = threadIdx.x;
    int badbyte = 0, nonz_off = 0, evenu16_nz = 0;
    for (int i = tid * 16; i < tid * 16 + 16; i++) {
        unsigned char c = m[i];
        if (c > 1) badbyte = 1;
        if ((i & 3) != 0 && c != 0) nonz_off = 1;
    }
    const u16* mu = (const u16*)m;
    for (int i = tid * 8; i < tid * 8 + 8; i++) {
        if ((i & 1) == 0 && mu[i] != 0) evenu16_nz = 1;
    }
    __shared__ int s_bad, s_noff, s_env;
    if (tid == 0) { s_bad = 0; s_noff = 0; s_env = 0; }
    __syncthreads();
    if (badbyte) atomicOr(&s_bad, 1);
    if (nonz_off) atomicOr(&s_noff, 1);
    if (evenu16_nz) atomicOr(&s_env, 1);
    __syncthreads();
    if (tid == 0) {
        int f;
        if (s_bad) f = s_env ? 2 : 3;
        else       f = s_noff ? 0 : 1;
        *flag = f;
    }
}

// ---------------------------------------------------------------------------
// init: h-states to bf16 parity buffers.
// ---------------------------------------------------------------------------
__global__ void __launch_bounds__(256) k_init2(const float* __restrict__ hid,
                                               u16* __restrict__ h0s,
                                               u16* __restrict__ h1s) {
    int i = blockIdx.x * 256 + threadIdx.x;   // 0 .. 16383
    u16 v0 = f2bf(hid[i]), v1 = f2bf(hid[16384 + i]);
    h0s[i] = v0; h0s[16384 + i] = v0;
    h1s[i] = v1; h1s[16384 + i] = v1;
}

// ---------------------------------------------------------------------------
// pack W_in into MFMA B-fragment order (1024 rows x K 512). grid 256 x 256.
// ---------------------------------------------------------------------------
__global__ void __launch_bounds__(256) k_packIn(const float* __restrict__ Win,
                                                u16* __restrict__ Wp) {
    int g = blockIdx.x * 256 + threadIdx.x;   // 0 .. 65535
    int lane = g & 63, grp = g >> 6;
    int j16 = grp >> 4, ks = grp & 15;
    const float* src = &Win[((size_t)(j16 * 16 + (lane & 15))) * 512 + ks * 32 + (lane >> 4) * 8];
    u16* dst = &Wp[(size_t)g * 8];
    f4 v0 = *(const f4*)&src[0];
    f4 v1 = *(const f4*)&src[4];
    dst[0] = f2bf(v0[0]); dst[1] = f2bf(v0[1]); dst[2] = f2bf(v0[2]); dst[3] = f2bf(v0[3]);
    dst[4] = f2bf(v1[0]); dst[5] = f2bf(v1[1]); dst[6] = f2bf(v1[2]); dst[7] = f2bf(v1[3]);
}

// ---------------------------------------------------------------------------
// pack W_out into MFMA B-fragment order (512 rows x K 1536). grid 384 x 256.
// ---------------------------------------------------------------------------
__global__ void __launch_bounds__(256) k_packOut(const float* __restrict__ Wout,
                                                 u16* __restrict__ Wp) {
    int g = blockIdx.x * 256 + threadIdx.x;   // 0 .. 98303
    int lane = g & 63, grp = g >> 6;          // grp 0..1535
    int j16 = grp / 48, ks = grp % 48;
    const float* src = &Wout[((size_t)(j16 * 16 + (lane & 15))) * 1536 + ks * 32 + (lane >> 4) * 8];
    u16* dst = &Wp[(size_t)g * 8];
    f4 v0 = *(const f4*)&src[0];
    f4 v1 = *(const f4*)&src[4];
    dst[0] = f2bf(v0[0]); dst[1] = f2bf(v0[1]); dst[2] = f2bf(v0[2]); dst[3] = f2bf(v0[3]);
    dst[4] = f2bf(v1[0]); dst[5] = f2bf(v1[1]); dst[6] = f2bf(v1[2]); dst[7] = f2bf(v1[3]);
}

// ---------------------------------------------------------------------------
// pack W_ih0 into MFMA B-fragment order (R14-proven). grid 512 x 256.
// ---------------------------------------------------------------------------
__global__ void __launch_bounds__(256) k_packA(const float* __restrict__ Wih0,
                                               u16* __restrict__ Wp) {
    int g = blockIdx.x * 256 + threadIdx.x;   // 0 .. 131071
    int lane = g & 63, grp = g >> 6;
    int j16 = grp >> 4, ks = grp & 15;
    const float* src = &Wih0[((size_t)(j16 * 16 + (lane & 15))) * 512 + ks * 32 + (lane >> 4) * 8];
    u16* dst = &Wp[(size_t)g * 8];
    f4 v0 = *(const f4*)&src[0];
    f4 v1 = *(const f4*)&src[4];
    dst[0] = f2bf(v0[0]); dst[1] = f2bf(v0[1]); dst[2] = f2bf(v0[2]); dst[3] = f2bf(v0[3]);
    dst[4] = f2bf(v1[0]); dst[5] = f2bf(v1[1]); dst[6] = f2bf(v1[2]); dst[7] = f2bf(v1[3]);
}

// ---------------------------------------------------------------------------
// pack {Whh0, Wih1, Whh1} into MFMA B-fragment order, gate-strided tiles
// (R19-proven). grid 1536 x 256.
// ---------------------------------------------------------------------------
__global__ void __launch_bounds__(256) k_packPh(const float* __restrict__ Wih,
                                                const float* __restrict__ Whh,
                                                u16* __restrict__ php) {
    int gidx = blockIdx.x * 256 + threadIdx.x;   // 0 .. 393215
    int m = gidx >> 17;                           // 0..2
    int rem = gidx & 131071;
    int lane = rem & 63;
    int q = rem >> 6;                             // 0..2047
    int ks = q & 15, T = q >> 4;                  // T 0..127
    int g = T >> 5, d16 = T & 31;
    int j = g * 512 + d16 * 16 + (lane & 15);
    int kcol = ks * 32 + (lane >> 4) * 8;
    const float* src = (m == 0) ? Whh
                     : (m == 1) ? (Wih + 1048576)
                                : (Whh + 1048576);
    const float* sp = &src[(size_t)j * 512 + kcol];
    u16* dst = &php[((size_t)m << 20) + (size_t)rem * 8];
    f4 v0 = *(const f4*)&sp[0];
    f4 v1 = *(const f4*)&sp[4];
    dst[0] = f2bf(v0[0]); dst[1] = f2bf(v0[1]); dst[2] = f2bf(v0[2]); dst[3] = f2bf(v0[3]);
    dst[4] = f2bf(v1[0]); dst[5] = f2bf(v1[1]); dst[6] = f2bf(v1[2]); dst[7] = f2bf(v1[3]);
}

// ---------------------------------------------------------------------------
// gih0 via MFMA, output in accumulator-fragment layout (R22-proven).
// ---------------------------------------------------------------------------
__global__ void __launch_bounds__(256) k_gih0_mfma(const int* __restrict__ tokens,
                                                   const float* __restrict__ embed,
                                                   const u16* __restrict__ Wp,
                                                   const float* __restrict__ bih,
                                                   const float* __restrict__ bhh,
                                                   float* __restrict__ gih0p) {
    const int tid = threadIdx.x;
    const int lane = tid & 63, w = tid >> 6;
    const int t = blockIdx.y;
    const int jw = blockIdx.x * 256 + w * 64;
    __shared__ u16 xs[32][520];
    __shared__ int toks[32];
    if (tid < 32) toks[tid] = tokens[tid * TT + t];
    __syncthreads();
    for (int i = tid; i < 32 * 128; i += 256) {
        int b = i >> 7, k4 = i & 127;
        f4 v = *(const f4*)&embed[(size_t)toks[b] * 512 + k4 * 4];
        u16* dst = &xs[b][k4 * 4];
        dst[0] = f2bf(v[0]); dst[1] = f2bf(v[1]); dst[2] = f2bf(v[2]); dst[3] = f2bf(v[3]);
    }
    __syncthreads();

    const int l15 = lane & 15, l4 = lane >> 4;
    f32x4 acc[2][4];
#pragma unroll
    for (int mi = 0; mi < 2; mi++)
#pragma unroll
        for (int ni = 0; ni < 4; ni++) acc[mi][ni] = (f32x4){0.f, 0.f, 0.f, 0.f};

    for (int ks = 0; ks < 16; ks++) {
        bfrag a0 = *(const bfrag*)&xs[l15][ks * 32 + l4 * 8];
        bfrag a1 = *(const bfrag*)&xs[16 + l15][ks * 32 + l4 * 8];
#pragma unroll
        for (int ni = 0; ni < 4; ni++) {
            int j16 = (jw + ni * 16) >> 4;
            bfrag bf = *(const bfrag*)&Wp[(((size_t)j16 * 16 + ks) * 64 + lane) * 8];
            acc[0][ni] = __builtin_amdgcn_mfma_f32_16x16x32_bf16(a0, bf, acc[0][ni], 0, 0, 0);
            acc[1][ni] = __builtin_amdgcn_mfma_f32_16x16x32_bf16(a1, bf, acc[1][ni], 0, 0, 0);
        }
    }

#pragma unroll
    for (int ni = 0; ni < 4; ni++) {
        int j16 = (jw >> 4) + ni;
        int g = j16 >> 5, d16 = j16 & 31;
        int j = j16 * 16 + l15;
        float bv = bih[j] + bhh[j];
#pragma unroll
        for (int mi = 0; mi < 2; mi++) {
            f32x4 sv = acc[mi][ni];
            sv[0] += bv; sv[1] += bv; sv[2] += bv; sv[3] += bv;
            *(f32x4*)&gih0p[(((((size_t)t * 32 + d16) * 4 + g) * 2 + mi) * 64 + lane) * 4] = sv;
        }
    }
}

// ---------------------------------------------------------------------------
// MFMA phase kernel, 64 blocks x 256 thr: intra-block K-split.
// Each block hosts 2 output units (d16,mi), each unit = 2 waves computing
// K-partials; LDS f32x4 reduce, even wave does the epilogue.
//  blocks  0..31: stepA(t=k)  unit d16mi = blk*2 + (w>>1); kh = w&1 (ks half)
//  blocks 32..63: stepB(t=k-1) unit d16mi = (blk-32)*2 + (w>>1); src = w&1
// Partial-sum reduction reorders f32 adds (absmax may move ±1 ulp; ok).
// ---------------------------------------------------------------------------
__global__ void __launch_bounds__(256) k_phaseM(
    const int k,
    const float* __restrict__ gih0p,
    const u16* __restrict__ whh0p,
    const u16* __restrict__ wih1p,
    const u16* __restrict__ whh1p,
    const float* __restrict__ bih1,
    const float* __restrict__ bhh1,
    const float* __restrict__ cells,
    const u16* __restrict__ h0r, u16* __restrict__ h0w,
    const u16* __restrict__ h20r, u16* __restrict__ h20w,
    const u16* __restrict__ h1r, u16* __restrict__ h1w,
    u16* __restrict__ H2)
{
    const int tid = threadIdx.x;
    const int lane = tid & 63, w = tid >> 6;
    const int l15 = lane & 15, l4 = lane >> 4;
    const int unitL = w >> 1, sub = w & 1;      // unit-local index, K-sub index
    __shared__ u16 xsA[32][520];
    __shared__ u16 xsB[32][520];
    __shared__ float red[2][4][64][4];          // [unitL][g][lane][r]

    if (blockIdx.x < 32) {                      // ======== stepA (t = k)
        if (k >= 64) return;
        const int d16mi = blockIdx.x * 2 + unitL;   // 0..63
        const int d16 = d16mi >> 1, mi = d16mi & 1;
        const int d = d16 * 16 + l15;
        f32x4 acc[4];
#pragma unroll
        for (int g = 0; g < 4; g++) {
            if (sub == 0)
                acc[g] = *(const f32x4*)&gih0p[(((((size_t)k * 32 + d16) * 4 + g) * 2 + mi) * 64 + lane) * 4];
            else
                acc[g] = (f32x4){0.f, 0.f, 0.f, 0.f};
        }
        for (int i = tid; i < 2048; i += 256) { // 32 rows x 512 u16 / 8-wide
            int b = i >> 6, k8 = i & 63;
            *(us8*)&xsA[b][k8 * 8] = *(const us8*)&h0r[b * 512 + k8 * 8];
        }
        __syncthreads();
        const int arow = mi * 16 + l15;
        const int ks0 = sub * 8;
        for (int ks = ks0; ks < ks0 + 8; ks++) {
            bfrag a = *(const bfrag*)&xsA[arow][ks * 32 + l4 * 8];
#pragma unroll
            for (int g = 0; g < 4; g++) {
                int T = g * 32 + d16;
                bfrag bf = *(const bfrag*)&whh0p[(((size_t)T * 16 + ks) * 64 + lane) * 8];
                acc[g] = __builtin_amdgcn_mfma_f32_16x16x32_bf16(a, bf, acc[g], 0, 0, 0);
            }
        }
        if (sub == 1) {
#pragma unroll
            for (int g = 0; g < 4; g++)
                *(f32x4*)&red[unitL][g][lane][0] = acc[g];
        }
        __syncthreads();
        if (sub == 0) {
#pragma unroll
            for (int g = 0; g < 4; g++) {
                f32x4 pv = *(const f32x4*)&red[unitL][g][lane][0];
                acc[g][0] += pv[0]; acc[g][1] += pv[1]; acc[g][2] += pv[2]; acc[g][3] += pv[3];
            }
#pragma unroll
            for (int r = 0; r < 4; r++) {
                int b = mi * 16 + l4 * 4 + r;
                float gi = acc[0][r];
                float gf = acc[1][r];
                float gg = acc[2][r];
                float go = acc[3][r];
                float cell = cells[b * 512 + d];
                float c2 = sigf(gf) * cell + sigf(gi) * tanhf(gg);
                float h2 = sigf(go) * tanhf(c2);
                h0w[b * 512 + d] = f2bf(c2);    // faithful bug: carry = cell
                h20w[b * 512 + d] = f2bf(h2);
            }
        }
    } else {                                    // ======== stepB (t = k-1)
        if (k < 1) return;
        for (int i = tid; i < 2048; i += 256) {
            int b = i >> 6, k8 = i & 63;
            *(us8*)&xsA[b][k8 * 8] = *(const us8*)&h20r[b * 512 + k8 * 8];
            *(us8*)&xsB[b][k8 * 8] = *(const us8*)&h1r[b * 512 + k8 * 8];
        }
        __syncthreads();
        const int d16mi = (blockIdx.x - 32) * 2 + unitL;    // 0..63
        const int d16 = d16mi >> 1, mi = d16mi & 1;
        const int d = d16 * 16 + l15;
        const int arow = mi * 16 + l15;
        const u16 (* __restrict__ xsrc)[520] = sub ? xsB : xsA;
        const u16* wsrc = sub ? whh1p : wih1p;
        f32x4 acc[4];
#pragma unroll
        for (int g = 0; g < 4; g++) acc[g] = (f32x4){0.f, 0.f, 0.f, 0.f};
        for (int ks = 0; ks < 16; ks++) {
            bfrag a = *(const bfrag*)&xsrc[arow][ks * 32 + l4 * 8];
#pragma unroll
            for (int g = 0; g < 4; g++) {
                int T = g * 32 + d16;
                bfrag bf = *(const bfrag*)&wsrc[(((size_t)T * 16 + ks) * 64 + lane) * 8];
                acc[g] = __builtin_amdgcn_mfma_f32_16x16x32_bf16(a, bf, acc[g], 0, 0, 0);
            }
        }
        if (sub == 1) {
#pragma unroll
            for (int g = 0; g < 4; g++)
                *(f32x4*)&red[unitL][g][lane][0] = acc[g];
        }
        __syncthreads();
        if (sub == 0) {
#pragma unroll
            for (int g = 0; g < 4; g++) {
                f32x4 pv = *(const f32x4*)&red[unitL][g][lane][0];
                acc[g][0] += pv[0]; acc[g][1] += pv[1]; acc[g][2] += pv[2]; acc[g][3] += pv[3];
            }
            float bb0 = bih1[0 * 512 + d] + bhh1[0 * 512 + d];
            float bb1v = bih1[1 * 512 + d] + bhh1[1 * 512 + d];
            float bb2 = bih1[2 * 512 + d] + bhh1[2 * 512 + d];
            float bb3 = bih1[3 * 512 + d] + bhh1[3 * 512 + d];
#pragma unroll
            for (int r = 0; r < 4; r++) {
                int b = mi * 16 + l4 * 4 + r;
                float gi = acc[0][r] + bb0;
                float gf = acc[1][r] + bb1v;
                float gg = acc[2][r] + bb2;
                float go = acc[3][r] + bb3;
                float cell = cells[16384 + b * 512 + d];
                float c2 = sigf(gf) * cell + sigf(gi) * tanhf(gg);
                float h2 = sigf(go) * tanhf(c2);
                h1w[b * 512 + d] = f2bf(c2);    // faithful bug
                H2[(size_t)(k - 1) * 16384 + b * 512 + d] = f2bf(h2);
            }
        }
    }
}

// ---------------------------------------------------------------------------
// XQ via MFMA: H2 bf16, pure-copy staging. grid (4 j-tiles, 64 t).
// ---------------------------------------------------------------------------
__global__ void __launch_bounds__(256) k_x_mfma(const u16* __restrict__ H2,
                                                const u16* __restrict__ Wpin,
                                                const float* __restrict__ bin,
                                                float* __restrict__ XQ) {
    const int tid = threadIdx.x;
    const int lane = tid & 63, w = tid >> 6;
    const int t = blockIdx.y;
    const int jw = blockIdx.x * 256 + w * 64;
    __shared__ u16 xs[32][520];
    for (int i = tid; i < 2048; i += 256) {
        int b = i >> 6, k8 = i & 63;
        *(us8*)&xs[b][k8 * 8] = *(const us8*)&H2[(size_t)t * 16384 + b * 512 + k8 * 8];
    }
    __syncthreads();
    const int l15 = lane & 15, l4 = lane >> 4;
    f32x4 acc[2][4];
#pragma unroll
    for (int mi = 0; mi < 2; mi++)
#pragma unroll
        for (int ni = 0; ni < 4; ni++) acc[mi][ni] = (f32x4){0.f, 0.f, 0.f, 0.f};
    for (int ks = 0; ks < 16; ks++) {
        bfrag a0 = *(const bfrag*)&xs[l15][ks * 32 + l4 * 8];
        bfrag a1 = *(const bfrag*)&xs[16 + l15][ks * 32 + l4 * 8];
#pragma unroll
        for (int ni = 0; ni < 4; ni++) {
            int j16 = (jw + ni * 16) >> 4;
            bfrag bf = *(const bfrag*)&Wpin[(((size_t)j16 * 16 + ks) * 64 + lane) * 8];
            acc[0][ni] = __builtin_amdgcn_mfma_f32_16x16x32_bf16(a0, bf, acc[0][ni], 0, 0, 0);
            acc[1][ni] = __builtin_amdgcn_mfma_f32_16x16x32_bf16(a1, bf, acc[1][ni], 0, 0, 0);
        }
    }
#pragma unroll
    for (int ni = 0; ni < 4; ni++) {
        int j = jw + ni * 16 + l15;
        float bv = bin[j];
#pragma unroll
        for (int mi = 0; mi < 2; mi++) {
#pragma unroll
            for (int r = 0; r < 4; r++) {
                int b = mi * 16 + l4 * 4 + r;
                XQ[((size_t)(t * 32 + b)) * 1024 + j] = acc[mi][ni][r] + bv;
            }
        }
    }
}

// ---------------------------------------------------------------------------
// out via MFMA: K=1536 in 3 chunks {CTX f32 x2, H2 bf16}. grid (2, 64).
// ---------------------------------------------------------------------------
__global__ void __launch_bounds__(256) k_out_mfma(const float* __restrict__ CTX,
                                                  const u16* __restrict__ H2,
                                                  const u16* __restrict__ Wpout,
                                                  const float* __restrict__ bout,
                                                  float* __restrict__ out) {
    const int tid = threadIdx.x;
    const int lane = tid & 63, w = tid >> 6;
    const int t = blockIdx.y;
    const int jw = blockIdx.x * 256 + w * 64;
    __shared__ u16 xs[32][520];
    const int l15 = lane & 15, l4 = lane >> 4;
    f32x4 acc[2][4];
#pragma unroll
    for (int mi = 0; mi < 2; mi++)
#pragma unroll
        for (int ni = 0; ni < 4; ni++) acc[mi][ni] = (f32x4){0.f, 0.f, 0.f, 0.f};
    for (int c = 0; c < 3; c++) {
        if (c) __syncthreads();                 // xs reuse guard
        if (c < 2) {
            for (int i = tid; i < 32 * 128; i += 256) {
                int b = i >> 7, k4 = i & 127;
                f4 v = *(const f4*)&CTX[((size_t)(t * 32 + b)) * 1024 + c * 512 + k4 * 4];
                u16* dst = &xs[b][k4 * 4];
                dst[0] = f2bf(v[0]); dst[1] = f2bf(v[1]); dst[2] = f2bf(v[2]); dst[3] = f2bf(v[3]);
            }
        } else {
            for (int i = tid; i < 2048; i += 256) {
                int b = i >> 6, k8 = i & 63;
                *(us8*)&xs[b][k8 * 8] = *(const us8*)&H2[(size_t)t * 16384 + b * 512 + k8 * 8];
            }
        }
        __syncthreads();
        for (int ks = 0; ks < 16; ks++) {
            bfrag a0 = *(const bfrag*)&xs[l15][ks * 32 + l4 * 8];
            bfrag a1 = *(const bfrag*)&xs[16 + l15][ks * 32 + l4 * 8];
#pragma unroll
            for (int ni = 0; ni < 4; ni++) {
                int j16 = (jw + ni * 16) >> 4;
                bfrag bf = *(const bfrag*)&Wpout[(((size_t)j16 * 48 + c * 16 + ks) * 64 + lane) * 8];
                acc[0][ni] = __builtin_amdgcn_mfma_f32_16x16x32_bf16(a0, bf, acc[0][ni], 0, 0, 0);
                acc[1][ni] = __builtin_amdgcn_mfma_f32_16x16x32_bf16(a1, bf, acc[1][ni], 0, 0, 0);
            }
        }
    }
#pragma unroll
    for (int ni = 0; ni < 4; ni++) {
        int j = jw + ni * 16 + l15;
        float bv = bout[j];
#pragma unroll
        for (int mi = 0; mi < 2; mi++) {
#pragma unroll
            for (int r = 0; r < 4; r++) {
                int b = mi * 16 + l4 * 4 + r;
                out[((size_t)(t * 32 + b)) * 512 + j] = tanhf(acc[mi][ni][r] + bv);
            }
        }
    }
}

// ---------------------------------------------------------------------------
// attention, FOUR time-steps per block (R21-proven, untouched).
// ---------------------------------------------------------------------------
__global__ void __launch_bounds__(256) k_att4(const float* __restrict__ XQ,
                                              const float* __restrict__ enc,
                                              const unsigned char* __restrict__ mask,
                                              const int* __restrict__ flag,
                                              float* __restrict__ CTX) {
    const int tid = threadIdx.x;
    const int b = blockIdx.x, t0 = blockIdx.y * 4;
    __shared__ float xq[4][1024];
    __shared__ float ered[4][256];
    __shared__ float attn[4][128];
    __shared__ float red2[4][8];
#pragma unroll
    for (int tg = 0; tg < 4; tg++) {
        f4 v = *(const f4*)&XQ[((size_t)((t0 + tg) * 32 + b)) * 1024 + tid * 4];
        float* dst = &xq[tg][tid * 4];
        dst[0] = v[0]; dst[1] = v[1]; dst[2] = v[2]; dst[3] = v[3];
    }
    __syncthreads();
    const int s = tid >> 1, hh = tid & 1;
    float p[4] = {0.f, 0.f, 0.f, 0.f};
    const float* erow = enc + ((size_t)(b * 128 + s)) * 1024 + hh * 512;
    for (int k4 = 0; k4 < 128; k4++) {
        f4 u = *(const f4*)&erow[k4 * 4];
#pragma unroll
        for (int kk = 0; kk < 4; kk++) {
#pragma unroll
            for (int tg = 0; tg < 4; tg++)
                p[tg] += u[kk] * xq[tg][hh * 512 + k4 * 4 + kk];
        }
    }
#pragma unroll
    for (int tg = 0; tg < 4; tg++) ered[tg][tid] = p[tg];
    __syncthreads();
    bool msk = false;
    if (tid < 128) {
        int f = *flag;
        if (f == 0)      msk = mask[b * 128 + tid] != 0;
        else if (f == 1) msk = ((const int*)mask)[b * 128 + tid] != 0;
        else if (f == 2) msk = ((const u16*)mask)[b * 128 + tid] != 0;
        else             msk = ((const unsigned int*)mask)[b * 128 + tid] != 0;
    }
    const int wave = tid >> 6;
    float e[4];
#pragma unroll
    for (int tg = 0; tg < 4; tg++) {
        e[tg] = -INFINITY;
        if (tid < 128) {
            e[tg] = ered[tg][2 * tid] + ered[tg][2 * tid + 1];
            if (msk) e[tg] = -1e9f;
        }
        float v = e[tg];
#pragma unroll
        for (int off = 32; off >= 1; off >>= 1) v = fmaxf(v, __shfl_xor(v, off));
        if ((tid & 63) == 0) red2[tg][wave] = v;
    }
    __syncthreads();
#pragma unroll
    for (int tg = 0; tg < 4; tg++) {
        float mx = fmaxf(fmaxf(red2[tg][0], red2[tg][1]), fmaxf(red2[tg][2], red2[tg][3]));
        float pp = (tid < 128) ? expf(e[tg] - mx) : 0.f;
        float su = pp;
#pragma unroll
        for (int off = 32; off >= 1; off >>= 1) su += __shfl_xor(su, off);
        if ((tid & 63) == 0) red2[tg][4 + wave] = su;
        __syncthreads();
        float S = (red2[tg][4] + red2[tg][5]) + (red2[tg][6] + red2[tg][7]);
        if (tid < 128) attn[tg][tid] = pp / S;
        __syncthreads();
    }
    float c0[4] = {0, 0, 0, 0}, c1[4] = {0, 0, 0, 0};
    float c2v[4] = {0, 0, 0, 0}, c3[4] = {0, 0, 0, 0};
    const float* eb = enc + ((size_t)b * 128) * 1024 + tid * 4;
    for (int s2 = 0; s2 < 128; s2++) {
        f4 u = *(const f4*)&eb[(size_t)s2 * 1024];
#pragma unroll
        for (int tg = 0; tg < 4; tg++) {
            float a = attn[tg][s2];
            c0[tg] += a * u[0]; c1[tg] += a * u[1]; c2v[tg] += a * u[2]; c3[tg] += a * u[3];
        }
    }
#pragma unroll
    for (int tg = 0; tg < 4; tg++) {
        float* crow = CTX + ((size_t)((t0 + tg) * 32 + b)) * 1024 + tid * 4;
        crow[0] = c0[tg]; crow[1] = c1[tg]; crow[2] = c2v[tg]; crow[3] = c3[tg];
    }
}

// ---------------------------------------------------------------------------
extern "C" void kernel_launch(void* const* d_in, const int* in_sizes, int n_in,
                              void* d_out, int out_size, void* d_ws, size_t ws_size,
                              hipStream_t stream) {
    const int* tokens   = (const int*)d_in[0];
    const float* enc    = (const float*)d_in[1];
    const float* hidden = (const float*)d_in[2];
    const float* cells  = (const float*)d_in[3];
    const unsigned char* mask = (const unsigned char*)d_in[4];
    const float* embed  = (const float*)d_in[5];
    const float* W_ih   = (const float*)d_in[6];
    const float* W_hh   = (const float*)d_in[7];
    const float* b_ih   = (const float*)d_in[8];
    const float* b_hh   = (const float*)d_in[9];
    const float* W_in   = (const float*)d_in[10];
    const float* b_in   = (const float*)d_in[11];
    const float* W_out  = (const float*)d_in[12];
    const float* b_out  = (const float*)d_in[13];
    float* out = (float*)d_out;

    float* ws = (float*)d_ws;
    // Phase-time layout (f-slot offsets):
    float* gih0p = ws;                             // [0, 4194304) — dead after phases
    u16*   h0s  = (u16*)(ws + 4194304);            // 2x16384 u16 -> 16384 f
    u16*   h20s = (u16*)(ws + 4210688);            // 16384 f
    u16*   h1s  = (u16*)(ws + 4227072);            // 16384 f
    u16*   H2   = (u16*)(ws + 4243456);            // 64x16384 u16 = 524288 f
    u16*   php  = (u16*)(ws + 4767744);            // 3x1048576 u16 = 1572864 f
    u16*   whh0p = php;
    u16*   wih1p = php + 1048576;
    u16*   whh1p = php + 2097152;
    u16*   wpin  = (u16*)(ws + 6340608);           // 524288 u16 = 262144 f
    u16*   wpout = (u16*)(ws + 6602752);           // 786432 u16 = 393216 f
    u16*   wih0p = (u16*)(ws + 6995968);           // 1048576 u16 = 524288 f
    int*   flag  = (int*)(ws + 7520256);
    // Tail-time layout (gih0p region reused):
    float* XQ   = ws;                              // [0, 2097152)
    float* CTX  = ws + 2097152;                    // [2097152, 4194304)

    const float* bih1 = b_ih + G4_;
    const float* bhh1 = b_hh + G4_;

    k_flag<<<1, 256, 0, stream>>>(mask, flag);
    k_init2<<<64, 256, 0, stream>>>(hidden, h0s, h1s);
    k_packIn<<<256, 256, 0, stream>>>(W_in, wpin);
    k_packOut<<<384, 256, 0, stream>>>(W_out, wpout);
    k_packA<<<512, 256, 0, stream>>>(W_ih, wih0p);
    k_packPh<<<1536, 256, 0, stream>>>(W_ih, W_hh, php);
    k_gih0_mfma<<<dim3(8, 64), 256, 0, stream>>>(tokens, embed, wih0p, b_ih, b_hh, gih0p);

    for (int k = 0; k <= 64; k++) {
        const int r = k & 1, w = r ^ 1;
        k_phaseM<<<64, 256, 0, stream>>>(k, gih0p, whh0p, wih1p, whh1p, bih1, bhh1, cells,
                                         h0s + r * 16384, h0s + w * 16384,
                                         h20s + r * 16384, h20s + w * 16384,
                                         h1s + r * 16384, h1s + w * 16384, H2);
    }

    k_x_mfma<<<dim3(4, 64), 256, 0, stream>>>(H2, wpin, b_in, XQ);
    k_att4<<<dim3(32, 16), 256, 0, stream>>>(XQ, enc, mask, flag, CTX);
    k_out_mfma<<<dim3(2, 64), 256, 0, stream>>>(CTX, H2, wpout, b_out, out);
}

// Round 25
// 591.605 us; speedup vs baseline: 2.8519x; 1.0286x over previous
//
#include <hip/hip_runtime.h>
#include <math.h>

typedef unsigned short u16;
typedef __attribute__((ext_vector_type(4))) float f4;
typedef __attribute__((ext_vector_type(8))) unsigned short us8;
typedef __attribute__((ext_vector_type(8))) short bfrag;
typedef __attribute__((ext_vector_type(4))) float f32x4;

#define BB 32
#define TT 64
#define DD 512
#define G4_ 2048

__device__ __forceinline__ float sigf(float x) { return 1.0f / (1.0f + expf(-x)); }
__device__ __forceinline__ float bf2f(u16 u) {
    union { unsigned int i; float f; } v; v.i = ((unsigned int)u) << 16; return v.f;
}
__device__ __forceinline__ u16 f2bf(float f) {
    union { float f; unsigned int i; } v; v.f = f;
    unsigned int r = v.i + 0x7fffu + ((v.i >> 16) & 1u);
    return (u16)(r >> 16);
}

// ---------------------------------------------------------------------------
// mask dtype classifier: 0=u8(bool), 1=i32, 2=bf16, 3=f32. Deterministic.
// ---------------------------------------------------------------------------
__global__ void k_flag(const unsigned char* __restrict__ m, int* __restrict__ flag) {
    int tid = threadIdx.x;
    int badbyte = 0, nonz_off = 0, evenu16_nz = 0;
    for (int i = tid * 16; i < tid * 16 + 16; i++) {
        unsigned char c = m[i];
        if (c > 1) badbyte = 1;
        if ((i & 3) != 0 && c != 0) nonz_off = 1;
    }
    const u16* mu = (const u16*)m;
    for (int i = tid * 8; i < tid * 8 + 8; i++) {
        if ((i & 1) == 0 && mu[i] != 0) evenu16_nz = 1;
    }
    __shared__ int s_bad, s_noff, s_env;
    if (tid == 0) { s_bad = 0; s_noff = 0; s_env = 0; }
    __syncthreads();
    if (badbyte) atomicOr(&s_bad, 1);
    if (nonz_off) atomicOr(&s_noff, 1);
    if (evenu16_nz) atomicOr(&s_env, 1);
    __syncthreads();
    if (tid == 0) {
        int f;
        if (s_bad) f = s_env ? 2 : 3;
        else       f = s_noff ? 0 : 1;
        *flag = f;
    }
}

// ---------------------------------------------------------------------------
// init: h-states to bf16 parity buffers.
// ---------------------------------------------------------------------------
__global__ void __launch_bounds__(256) k_init2(const float* __restrict__ hid,
                                               u16* __restrict__ h0s,
                                               u16* __restrict__ h1s) {
    int i = blockIdx.x * 256 + threadIdx.x;   // 0 .. 16383
    u16 v0 = f2bf(hid[i]), v1 = f2bf(hid[16384 + i]);
    h0s[i] = v0; h0s[16384 + i] = v0;
    h1s[i] = v1; h1s[16384 + i] = v1;
}

// ---------------------------------------------------------------------------
// merged pack kernel: all 4 weight packs in one launch (block ranges).
//   blk [0,256):    W_in   (R21-proven packIn layout)
//   blk [256,640):  W_out  (packOut layout)
//   blk [640,1152): W_ih0  (packA layout)
//   blk [1152,2688): {Whh0,Wih1,Whh1} (packPh layout)
// ---------------------------------------------------------------------------
__global__ void __launch_bounds__(256) k_packAll(const float* __restrict__ Wih,
                                                 const float* __restrict__ Whh,
                                                 const float* __restrict__ Win,
                                                 const float* __restrict__ Wout,
                                                 u16* __restrict__ wpin,
                                                 u16* __restrict__ wpout,
                                                 u16* __restrict__ wih0p,
                                                 u16* __restrict__ php) {
    const int blk = blockIdx.x;
    const int tid = threadIdx.x;
    const float* sp;
    u16* dst;
    if (blk < 256) {                            // -------- W_in
        int g = blk * 256 + tid;                // 0 .. 65535
        int lane = g & 63, grp = g >> 6;
        int j16 = grp >> 4, ks = grp & 15;
        sp = &Win[((size_t)(j16 * 16 + (lane & 15))) * 512 + ks * 32 + (lane >> 4) * 8];
        dst = &wpin[(size_t)g * 8];
    } else if (blk < 640) {                     // -------- W_out
        int g = (blk - 256) * 256 + tid;        // 0 .. 98303
        int lane = g & 63, grp = g >> 6;        // grp 0..1535
        int j16 = grp / 48, ks = grp % 48;
        sp = &Wout[((size_t)(j16 * 16 + (lane & 15))) * 1536 + ks * 32 + (lane >> 4) * 8];
        dst = &wpout[(size_t)g * 8];
    } else if (blk < 1152) {                    // -------- W_ih0
        int g = (blk - 640) * 256 + tid;        // 0 .. 131071
        int lane = g & 63, grp = g >> 6;
        int j16 = grp >> 4, ks = grp & 15;
        sp = &Wih[((size_t)(j16 * 16 + (lane & 15))) * 512 + ks * 32 + (lane >> 4) * 8];
        dst = &wih0p[(size_t)g * 8];
    } else {                                    // -------- {Whh0, Wih1, Whh1}
        int gidx = (blk - 1152) * 256 + tid;    // 0 .. 393215
        int m = gidx >> 17;                     // 0..2
        int rem = gidx & 131071;
        int lane = rem & 63;
        int q = rem >> 6;
        int ks = q & 15, T = q >> 4;
        int g = T >> 5, d16 = T & 31;
        int j = g * 512 + d16 * 16 + (lane & 15);
        int kcol = ks * 32 + (lane >> 4) * 8;
        const float* src = (m == 0) ? Whh
                         : (m == 1) ? (Wih + 1048576)
                                    : (Whh + 1048576);
        sp = &src[(size_t)j * 512 + kcol];
        dst = &php[((size_t)m << 20) + (size_t)rem * 8];
    }
    f4 v0 = *(const f4*)&sp[0];
    f4 v1 = *(const f4*)&sp[4];
    dst[0] = f2bf(v0[0]); dst[1] = f2bf(v0[1]); dst[2] = f2bf(v0[2]); dst[3] = f2bf(v0[3]);
    dst[4] = f2bf(v1[0]); dst[5] = f2bf(v1[1]); dst[6] = f2bf(v1[2]); dst[7] = f2bf(v1[3]);
}

// ---------------------------------------------------------------------------
// gih0 via MFMA, output in accumulator-fragment layout (R22-proven).
// ---------------------------------------------------------------------------
__global__ void __launch_bounds__(256) k_gih0_mfma(const int* __restrict__ tokens,
                                                   const float* __restrict__ embed,
                                                   const u16* __restrict__ Wp,
                                                   const float* __restrict__ bih,
                                                   const float* __restrict__ bhh,
                                                   float* __restrict__ gih0p) {
    const int tid = threadIdx.x;
    const int lane = tid & 63, w = tid >> 6;
    const int t = blockIdx.y;
    const int jw = blockIdx.x * 256 + w * 64;
    __shared__ u16 xs[32][520];
    __shared__ int toks[32];
    if (tid < 32) toks[tid] = tokens[tid * TT + t];
    __syncthreads();
    for (int i = tid; i < 32 * 128; i += 256) {
        int b = i >> 7, k4 = i & 127;
        f4 v = *(const f4*)&embed[(size_t)toks[b] * 512 + k4 * 4];
        u16* dst = &xs[b][k4 * 4];
        dst[0] = f2bf(v[0]); dst[1] = f2bf(v[1]); dst[2] = f2bf(v[2]); dst[3] = f2bf(v[3]);
    }
    __syncthreads();

    const int l15 = lane & 15, l4 = lane >> 4;
    f32x4 acc[2][4];
#pragma unroll
    for (int mi = 0; mi < 2; mi++)
#pragma unroll
        for (int ni = 0; ni < 4; ni++) acc[mi][ni] = (f32x4){0.f, 0.f, 0.f, 0.f};

    for (int ks = 0; ks < 16; ks++) {
        bfrag a0 = *(const bfrag*)&xs[l15][ks * 32 + l4 * 8];
        bfrag a1 = *(const bfrag*)&xs[16 + l15][ks * 32 + l4 * 8];
#pragma unroll
        for (int ni = 0; ni < 4; ni++) {
            int j16 = (jw + ni * 16) >> 4;
            bfrag bf = *(const bfrag*)&Wp[(((size_t)j16 * 16 + ks) * 64 + lane) * 8];
            acc[0][ni] = __builtin_amdgcn_mfma_f32_16x16x32_bf16(a0, bf, acc[0][ni], 0, 0, 0);
            acc[1][ni] = __builtin_amdgcn_mfma_f32_16x16x32_bf16(a1, bf, acc[1][ni], 0, 0, 0);
        }
    }

#pragma unroll
    for (int ni = 0; ni < 4; ni++) {
        int j16 = (jw >> 4) + ni;
        int g = j16 >> 5, d16 = j16 & 31;
        int j = j16 * 16 + l15;
        float bv = bih[j] + bhh[j];
#pragma unroll
        for (int mi = 0; mi < 2; mi++) {
            f32x4 sv = acc[mi][ni];
            sv[0] += bv; sv[1] += bv; sv[2] += bv; sv[3] += bv;
            *(f32x4*)&gih0p[(((((size_t)t * 32 + d16) * 4 + g) * 2 + mi) * 64 + lane) * 4] = sv;
        }
    }
}

// ---------------------------------------------------------------------------
// MFMA phase kernel, 64 blocks x 256 thr, intra-block K-split (R24-proven).
// ---------------------------------------------------------------------------
__global__ void __launch_bounds__(256) k_phaseM(
    const int k,
    const float* __restrict__ gih0p,
    const u16* __restrict__ whh0p,
    const u16* __restrict__ wih1p,
    const u16* __restrict__ whh1p,
    const float* __restrict__ bih1,
    const float* __restrict__ bhh1,
    const float* __restrict__ cells,
    const u16* __restrict__ h0r, u16* __restrict__ h0w,
    const u16* __restrict__ h20r, u16* __restrict__ h20w,
    const u16* __restrict__ h1r, u16* __restrict__ h1w,
    u16* __restrict__ H2)
{
    const int tid = threadIdx.x;
    const int lane = tid & 63, w = tid >> 6;
    const int l15 = lane & 15, l4 = lane >> 4;
    const int unitL = w >> 1, sub = w & 1;      // unit-local index, K-sub index
    __shared__ u16 xsA[32][520];
    __shared__ u16 xsB[32][520];
    __shared__ float red[2][4][64][4];          // [unitL][g][lane][r]

    if (blockIdx.x < 32) {                      // ======== stepA (t = k)
        if (k >= 64) return;
        const int d16mi = blockIdx.x * 2 + unitL;   // 0..63
        const int d16 = d16mi >> 1, mi = d16mi & 1;
        const int d = d16 * 16 + l15;
        f32x4 acc[4];
#pragma unroll
        for (int g = 0; g < 4; g++) {
            if (sub == 0)
                acc[g] = *(const f32x4*)&gih0p[(((((size_t)k * 32 + d16) * 4 + g) * 2 + mi) * 64 + lane) * 4];
            else
                acc[g] = (f32x4){0.f, 0.f, 0.f, 0.f};
        }
        for (int i = tid; i < 2048; i += 256) { // 32 rows x 512 u16 / 8-wide
            int b = i >> 6, k8 = i & 63;
            *(us8*)&xsA[b][k8 * 8] = *(const us8*)&h0r[b * 512 + k8 * 8];
        }
        __syncthreads();
        const int arow = mi * 16 + l15;
        const int ks0 = sub * 8;
        for (int ks = ks0; ks < ks0 + 8; ks++) {
            bfrag a = *(const bfrag*)&xsA[arow][ks * 32 + l4 * 8];
#pragma unroll
            for (int g = 0; g < 4; g++) {
                int T = g * 32 + d16;
                bfrag bf = *(const bfrag*)&whh0p[(((size_t)T * 16 + ks) * 64 + lane) * 8];
                acc[g] = __builtin_amdgcn_mfma_f32_16x16x32_bf16(a, bf, acc[g], 0, 0, 0);
            }
        }
        if (sub == 1) {
#pragma unroll
            for (int g = 0; g < 4; g++)
                *(f32x4*)&red[unitL][g][lane][0] = acc[g];
        }
        __syncthreads();
        if (sub == 0) {
#pragma unroll
            for (int g = 0; g < 4; g++) {
                f32x4 pv = *(const f32x4*)&red[unitL][g][lane][0];
                acc[g][0] += pv[0]; acc[g][1] += pv[1]; acc[g][2] += pv[2]; acc[g][3] += pv[3];
            }
#pragma unroll
            for (int r = 0; r < 4; r++) {
                int b = mi * 16 + l4 * 4 + r;
                float gi = acc[0][r];
                float gf = acc[1][r];
                float gg = acc[2][r];
                float go = acc[3][r];
                float cell = cells[b * 512 + d];
                float c2 = sigf(gf) * cell + sigf(gi) * tanhf(gg);
                float h2 = sigf(go) * tanhf(c2);
                h0w[b * 512 + d] = f2bf(c2);    // faithful bug: carry = cell
                h20w[b * 512 + d] = f2bf(h2);
            }
        }
    } else {                                    // ======== stepB (t = k-1)
        if (k < 1) return;
        for (int i = tid; i < 2048; i += 256) {
            int b = i >> 6, k8 = i & 63;
            *(us8*)&xsA[b][k8 * 8] = *(const us8*)&h20r[b * 512 + k8 * 8];
            *(us8*)&xsB[b][k8 * 8] = *(const us8*)&h1r[b * 512 + k8 * 8];
        }
        __syncthreads();
        const int d16mi = (blockIdx.x - 32) * 2 + unitL;    // 0..63
        const int d16 = d16mi >> 1, mi = d16mi & 1;
        const int d = d16 * 16 + l15;
        const int arow = mi * 16 + l15;
        const u16 (* __restrict__ xsrc)[520] = sub ? xsB : xsA;
        const u16* wsrc = sub ? whh1p : wih1p;
        f32x4 acc[4];
#pragma unroll
        for (int g = 0; g < 4; g++) acc[g] = (f32x4){0.f, 0.f, 0.f, 0.f};
        for (int ks = 0; ks < 16; ks++) {
            bfrag a = *(const bfrag*)&xsrc[arow][ks * 32 + l4 * 8];
#pragma unroll
            for (int g = 0; g < 4; g++) {
                int T = g * 32 + d16;
                bfrag bf = *(const bfrag*)&wsrc[(((size_t)T * 16 + ks) * 64 + lane) * 8];
                acc[g] = __builtin_amdgcn_mfma_f32_16x16x32_bf16(a, bf, acc[g], 0, 0, 0);
            }
        }
        if (sub == 1) {
#pragma unroll
            for (int g = 0; g < 4; g++)
                *(f32x4*)&red[unitL][g][lane][0] = acc[g];
        }
        __syncthreads();
        if (sub == 0) {
#pragma unroll
            for (int g = 0; g < 4; g++) {
                f32x4 pv = *(const f32x4*)&red[unitL][g][lane][0];
                acc[g][0] += pv[0]; acc[g][1] += pv[1]; acc[g][2] += pv[2]; acc[g][3] += pv[3];
            }
            float bb0 = bih1[0 * 512 + d] + bhh1[0 * 512 + d];
            float bb1v = bih1[1 * 512 + d] + bhh1[1 * 512 + d];
            float bb2 = bih1[2 * 512 + d] + bhh1[2 * 512 + d];
            float bb3 = bih1[3 * 512 + d] + bhh1[3 * 512 + d];
#pragma unroll
            for (int r = 0; r < 4; r++) {
                int b = mi * 16 + l4 * 4 + r;
                float gi = acc[0][r] + bb0;
                float gf = acc[1][r] + bb1v;
                float gg = acc[2][r] + bb2;
                float go = acc[3][r] + bb3;
                float cell = cells[16384 + b * 512 + d];
                float c2 = sigf(gf) * cell + sigf(gi) * tanhf(gg);
                float h2 = sigf(go) * tanhf(c2);
                h1w[b * 512 + d] = f2bf(c2);    // faithful bug
                H2[(size_t)(k - 1) * 16384 + b * 512 + d] = f2bf(h2);
            }
        }
    }
}

// ---------------------------------------------------------------------------
// XQ via MFMA: H2 bf16, pure-copy staging. grid (4 j-tiles, 64 t).
// ---------------------------------------------------------------------------
__global__ void __launch_bounds__(256) k_x_mfma(const u16* __restrict__ H2,
                                                const u16* __restrict__ Wpin,
                                                const float* __restrict__ bin,
                                                float* __restrict__ XQ) {
    const int tid = threadIdx.x;
    const int lane = tid & 63, w = tid >> 6;
    const int t = blockIdx.y;
    const int jw = blockIdx.x * 256 + w * 64;
    __shared__ u16 xs[32][520];
    for (int i = tid; i < 2048; i += 256) {
        int b = i >> 6, k8 = i & 63;
        *(us8*)&xs[b][k8 * 8] = *(const us8*)&H2[(size_t)t * 16384 + b * 512 + k8 * 8];
    }
    __syncthreads();
    const int l15 = lane & 15, l4 = lane >> 4;
    f32x4 acc[2][4];
#pragma unroll
    for (int mi = 0; mi < 2; mi++)
#pragma unroll
        for (int ni = 0; ni < 4; ni++) acc[mi][ni] = (f32x4){0.f, 0.f, 0.f, 0.f};
    for (int ks = 0; ks < 16; ks++) {
        bfrag a0 = *(const bfrag*)&xs[l15][ks * 32 + l4 * 8];
        bfrag a1 = *(const bfrag*)&xs[16 + l15][ks * 32 + l4 * 8];
#pragma unroll
        for (int ni = 0; ni < 4; ni++) {
            int j16 = (jw + ni * 16) >> 4;
            bfrag bf = *(const bfrag*)&Wpin[(((size_t)j16 * 16 + ks) * 64 + lane) * 8];
            acc[0][ni] = __builtin_amdgcn_mfma_f32_16x16x32_bf16(a0, bf, acc[0][ni], 0, 0, 0);
            acc[1][ni] = __builtin_amdgcn_mfma_f32_16x16x32_bf16(a1, bf, acc[1][ni], 0, 0, 0);
        }
    }
#pragma unroll
    for (int ni = 0; ni < 4; ni++) {
        int j = jw + ni * 16 + l15;
        float bv = bin[j];
#pragma unroll
        for (int mi = 0; mi < 2; mi++) {
#pragma unroll
            for (int r = 0; r < 4; r++) {
                int b = mi * 16 + l4 * 4 + r;
                XQ[((size_t)(t * 32 + b)) * 1024 + j] = acc[mi][ni][r] + bv;
            }
        }
    }
}

// ---------------------------------------------------------------------------
// out via MFMA: K=1536 in 3 chunks {CTX f32 x2, H2 bf16}. grid (2, 64).
// ---------------------------------------------------------------------------
__global__ void __launch_bounds__(256) k_out_mfma(const float* __restrict__ CTX,
                                                  const u16* __restrict__ H2,
                                                  const u16* __restrict__ Wpout,
                                                  const float* __restrict__ bout,
                                                  float* __restrict__ out) {
    const int tid = threadIdx.x;
    const int lane = tid & 63, w = tid >> 6;
    const int t = blockIdx.y;
    const int jw = blockIdx.x * 256 + w * 64;
    __shared__ u16 xs[32][520];
    const int l15 = lane & 15, l4 = lane >> 4;
    f32x4 acc[2][4];
#pragma unroll
    for (int mi = 0; mi < 2; mi++)
#pragma unroll
        for (int ni = 0; ni < 4; ni++) acc[mi][ni] = (f32x4){0.f, 0.f, 0.f, 0.f};
    for (int c = 0; c < 3; c++) {
        if (c) __syncthreads();                 // xs reuse guard
        if (c < 2) {
            for (int i = tid; i < 32 * 128; i += 256) {
                int b = i >> 7, k4 = i & 127;
                f4 v = *(const f4*)&CTX[((size_t)(t * 32 + b)) * 1024 + c * 512 + k4 * 4];
                u16* dst = &xs[b][k4 * 4];
                dst[0] = f2bf(v[0]); dst[1] = f2bf(v[1]); dst[2] = f2bf(v[2]); dst[3] = f2bf(v[3]);
            }
        } else {
            for (int i = tid; i < 2048; i += 256) {
                int b = i >> 6, k8 = i & 63;
                *(us8*)&xs[b][k8 * 8] = *(const us8*)&H2[(size_t)t * 16384 + b * 512 + k8 * 8];
            }
        }
        __syncthreads();
        for (int ks = 0; ks < 16; ks++) {
            bfrag a0 = *(const bfrag*)&xs[l15][ks * 32 + l4 * 8];
            bfrag a1 = *(const bfrag*)&xs[16 + l15][ks * 32 + l4 * 8];
#pragma unroll
            for (int ni = 0; ni < 4; ni++) {
                int j16 = (jw + ni * 16) >> 4;
                bfrag bf = *(const bfrag*)&Wpout[(((size_t)j16 * 48 + c * 16 + ks) * 64 + lane) * 8];
                acc[0][ni] = __builtin_amdgcn_mfma_f32_16x16x32_bf16(a0, bf, acc[0][ni], 0, 0, 0);
                acc[1][ni] = __builtin_amdgcn_mfma_f32_16x16x32_bf16(a1, bf, acc[1][ni], 0, 0, 0);
            }
        }
    }
#pragma unroll
    for (int ni = 0; ni < 4; ni++) {
        int j = jw + ni * 16 + l15;
        float bv = bout[j];
#pragma unroll
        for (int mi = 0; mi < 2; mi++) {
#pragma unroll
            for (int r = 0; r < 4; r++) {
                int b = mi * 16 + l4 * 4 + r;
                out[((size_t)(t * 32 + b)) * 512 + j] = tanhf(acc[mi][ni][r] + bv);
            }
        }
    }
}

// ---------------------------------------------------------------------------
// attention, EIGHT time-steps per block: all t's share every enc read.
// grid (32 b, 8 t-octets), 256 thr. Per-t reduction order unchanged.
// ---------------------------------------------------------------------------
__global__ void __launch_bounds__(256) k_att8(const float* __restrict__ XQ,
                                              const float* __restrict__ enc,
                                              const unsigned char* __restrict__ mask,
                                              const int* __restrict__ flag,
                                              float* __restrict__ CTX) {
    const int tid = threadIdx.x;
    const int b = blockIdx.x, t0 = blockIdx.y * 8;
    __shared__ float xq[8][1024];
    __shared__ float ered[8][256];
    __shared__ float attn[8][128];
    __shared__ float red2[8][8];
#pragma unroll
    for (int tg = 0; tg < 8; tg++) {
        f4 v = *(const f4*)&XQ[((size_t)((t0 + tg) * 32 + b)) * 1024 + tid * 4];
        float* dst = &xq[tg][tid * 4];
        dst[0] = v[0]; dst[1] = v[1]; dst[2] = v[2]; dst[3] = v[3];
    }
    __syncthreads();
    const int s = tid >> 1, hh = tid & 1;
    float p[8] = {0.f, 0.f, 0.f, 0.f, 0.f, 0.f, 0.f, 0.f};
    const float* erow = enc + ((size_t)(b * 128 + s)) * 1024 + hh * 512;
    for (int k4 = 0; k4 < 128; k4++) {
        f4 u = *(const f4*)&erow[k4 * 4];
#pragma unroll
        for (int kk = 0; kk < 4; kk++) {
#pragma unroll
            for (int tg = 0; tg < 8; tg++)
                p[tg] += u[kk] * xq[tg][hh * 512 + k4 * 4 + kk];
        }
    }
#pragma unroll
    for (int tg = 0; tg < 8; tg++) ered[tg][tid] = p[tg];
    __syncthreads();
    bool msk = false;
    if (tid < 128) {
        int f = *flag;
        if (f == 0)      msk = mask[b * 128 + tid] != 0;
        else if (f == 1) msk = ((const int*)mask)[b * 128 + tid] != 0;
        else if (f == 2) msk = ((const u16*)mask)[b * 128 + tid] != 0;
        else             msk = ((const unsigned int*)mask)[b * 128 + tid] != 0;
    }
    const int wave = tid >> 6;
    float e[8];
#pragma unroll
    for (int tg = 0; tg < 8; tg++) {
        e[tg] = -INFINITY;
        if (tid < 128) {
            e[tg] = ered[tg][2 * tid] + ered[tg][2 * tid + 1];
            if (msk) e[tg] = -1e9f;
        }
        float v = e[tg];
#pragma unroll
        for (int off = 32; off >= 1; off >>= 1) v = fmaxf(v, __shfl_xor(v, off));
        if ((tid & 63) == 0) red2[tg][wave] = v;
    }
    __syncthreads();
#pragma unroll
    for (int tg = 0; tg < 8; tg++) {
        float mx = fmaxf(fmaxf(red2[tg][0], red2[tg][1]), fmaxf(red2[tg][2], red2[tg][3]));
        float pp = (tid < 128) ? expf(e[tg] - mx) : 0.f;
        float su = pp;
#pragma unroll
        for (int off = 32; off >= 1; off >>= 1) su += __shfl_xor(su, off);
        if ((tid & 63) == 0) red2[tg][4 + wave] = su;
        __syncthreads();
        float S = (red2[tg][4] + red2[tg][5]) + (red2[tg][6] + red2[tg][7]);
        if (tid < 128) attn[tg][tid] = pp / S;
        __syncthreads();
    }
    float c0[8] = {0}, c1[8] = {0}, c2v[8] = {0}, c3[8] = {0};
    const float* eb = enc + ((size_t)b * 128) * 1024 + tid * 4;
    for (int s2 = 0; s2 < 128; s2++) {
        f4 u = *(const f4*)&eb[(size_t)s2 * 1024];
#pragma unroll
        for (int tg = 0; tg < 8; tg++) {
            float a = attn[tg][s2];
            c0[tg] += a * u[0]; c1[tg] += a * u[1]; c2v[tg] += a * u[2]; c3[tg] += a * u[3];
        }
    }
#pragma unroll
    for (int tg = 0; tg < 8; tg++) {
        float* crow = CTX + ((size_t)((t0 + tg) * 32 + b)) * 1024 + tid * 4;
        crow[0] = c0[tg]; crow[1] = c1[tg]; crow[2] = c2v[tg]; crow[3] = c3[tg];
    }
}

// ---------------------------------------------------------------------------
extern "C" void kernel_launch(void* const* d_in, const int* in_sizes, int n_in,
                              void* d_out, int out_size, void* d_ws, size_t ws_size,
                              hipStream_t stream) {
    const int* tokens   = (const int*)d_in[0];
    const float* enc    = (const float*)d_in[1];
    const float* hidden = (const float*)d_in[2];
    const float* cells  = (const float*)d_in[3];
    const unsigned char* mask = (const unsigned char*)d_in[4];
    const float* embed  = (const float*)d_in[5];
    const float* W_ih   = (const float*)d_in[6];
    const float* W_hh   = (const float*)d_in[7];
    const float* b_ih   = (const float*)d_in[8];
    const float* b_hh   = (const float*)d_in[9];
    const float* W_in   = (const float*)d_in[10];
    const float* b_in   = (const float*)d_in[11];
    const float* W_out  = (const float*)d_in[12];
    const float* b_out  = (const float*)d_in[13];
    float* out = (float*)d_out;

    float* ws = (float*)d_ws;
    // Phase-time layout (f-slot offsets):
    float* gih0p = ws;                             // [0, 4194304) — dead after phases
    u16*   h0s  = (u16*)(ws + 4194304);            // 2x16384 u16 -> 16384 f
    u16*   h20s = (u16*)(ws + 4210688);            // 16384 f
    u16*   h1s  = (u16*)(ws + 4227072);            // 16384 f
    u16*   H2   = (u16*)(ws + 4243456);            // 64x16384 u16 = 524288 f
    u16*   php  = (u16*)(ws + 4767744);            // 3x1048576 u16 = 1572864 f
    u16*   whh0p = php;
    u16*   wih1p = php + 1048576;
    u16*   whh1p = php + 2097152;
    u16*   wpin  = (u16*)(ws + 6340608);           // 524288 u16 = 262144 f
    u16*   wpout = (u16*)(ws + 6602752);           // 786432 u16 = 393216 f
    u16*   wih0p = (u16*)(ws + 6995968);           // 1048576 u16 = 524288 f
    int*   flag  = (int*)(ws + 7520256);
    // Tail-time layout (gih0p region reused):
    float* XQ   = ws;                              // [0, 2097152)
    float* CTX  = ws + 2097152;                    // [2097152, 4194304)

    const float* bih1 = b_ih + G4_;
    const float* bhh1 = b_hh + G4_;

    k_flag<<<1, 256, 0, stream>>>(mask, flag);
    k_init2<<<64, 256, 0, stream>>>(hidden, h0s, h1s);
    k_packAll<<<2688, 256, 0, stream>>>(W_ih, W_hh, W_in, W_out, wpin, wpout, wih0p, php);
    k_gih0_mfma<<<dim3(8, 64), 256, 0, stream>>>(tokens, embed, wih0p, b_ih, b_hh, gih0p);

    for (int k = 0; k <= 64; k++) {
        const int r = k & 1, w = r ^ 1;
        k_phaseM<<<64, 256, 0, stream>>>(k, gih0p, whh0p, wih1p, whh1p, bih1, bhh1, cells,
                                         h0s + r * 16384, h0s + w * 16384,
                                         h20s + r * 16384, h20s + w * 16384,
                                         h1s + r * 16384, h1s + w * 16384, H2);
    }

    k_x_mfma<<<dim3(4, 64), 256, 0, stream>>>(H2, wpin, b_in, XQ);
    k_att8<<<dim3(32, 8), 256, 0, stream>>>(XQ, enc, mask, flag, CTX);
    k_out_mfma<<<dim3(2, 64), 256, 0, stream>>>(CTX, H2, wpout, b_out, out);
}